// Round 5
// baseline (208.735 us; speedup 1.0000x reference)
//
#include <hip/hip_runtime.h>
#include <hip/hip_bf16.h>
#include <stdint.h>
#include <math.h>

#define HIDDEN 1024
#define NHEADS 16
#define HDIM   64
#define BSZ    4
#define QLEN   1024
#define KVLEN  2048

typedef __bf16 bf16_t;
typedef __bf16 bf16x8 __attribute__((ext_vector_type(8)));
typedef __bf16 bf16x4 __attribute__((ext_vector_type(4)));
typedef float  f32x4  __attribute__((ext_vector_type(4)));

// fixed-max softmax: p = exp2( s_raw*C_SCALE + madd ).
// Fixed max makes split-KV partials ADDITIVE (no rescale needed).
#define C_SCALE 0.18033688f     /* 0.125 * log2(e) */
#define C_FMADD (-43.2808512f)  /* -30 * log2(e) */

#define GLOAD16(g, l) \
    __builtin_amdgcn_global_load_lds((const __attribute__((address_space(1))) void*)(g), \
                                     (__attribute__((address_space(3))) void*)(l), 16, 0, 0)

__device__ __forceinline__ float clamp50(float v) {
    return fminf(fmaxf(v, -50.f), 50.f);
}

// ---------------------------------------------------------------------------
// Mask prep, 16 blocks (redundant dtype detection per block).
// ---------------------------------------------------------------------------
__global__ void mask_prep_kernel(const void* __restrict__ raw, float* __restrict__ maskadd) {
    __shared__ int s_float, s_multi;
    const int t = threadIdx.x;
    if (t == 0) { s_float = 0; s_multi = 0; }
    __syncthreads();
    const uint32_t* w = (const uint32_t*)raw;
    int cf = 0, cm = 0;
    for (int i = t; i < 2048; i += blockDim.x) {
        uint32_t v = w[i];
        if (v == 0x3F800000u) cf++;
        else if (v & 0xFFFFFF00u) cm++;
    }
    if (cf) atomicAdd(&s_float, cf);
    if (cm) atomicAdd(&s_multi, cm);
    __syncthreads();
    const int mode = (s_float > 0) ? 2 : ((s_multi > 0) ? 0 : 1);
    const int base = blockIdx.x * 512;
    for (int i = base + t; i < base + 512; i += blockDim.x) {
        bool m;
        if (mode == 2)      m = ((const float*)raw)[i] != 0.0f;
        else if (mode == 1) m = ((const int*)raw)[i] != 0;
        else                m = ((const unsigned char*)raw)[i] != 0;
        maskadd[i] = m ? (-100000.0f + C_FMADD) : C_FMADD;
    }
}

// ---------------------------------------------------------------------------
// One launch converts q, kv, and all 4 weights fp32 -> bf16 with clamp50.
// ---------------------------------------------------------------------------
#define NQ4  ((BSZ * QLEN  * HIDDEN) / 4)   /* 1048576 */
#define NKV4 ((BSZ * KVLEN * HIDDEN) / 4)   /* 2097152 */
#define NW4  ((HIDDEN * HIDDEN) / 4)        /* 262144  */

__global__ void cvt_all_kernel(const float* __restrict__ q, const float* __restrict__ kv,
                               const float* __restrict__ W0, const float* __restrict__ W1,
                               const float* __restrict__ W2, const float* __restrict__ W3,
                               bf16_t* __restrict__ q_bf, bf16_t* __restrict__ kv_bf,
                               bf16_t* __restrict__ w_bf) {
    const int i = blockIdx.x * blockDim.x + threadIdx.x;
    const float4* src;
    bf16x4* dst;
    if (i < NQ4) {
        src = (const float4*)q + i;            dst = (bf16x4*)q_bf + i;
    } else if (i < NQ4 + NKV4) {
        const int j = i - NQ4;
        src = (const float4*)kv + j;           dst = (bf16x4*)kv_bf + j;
    } else {
        const int j = i - (NQ4 + NKV4);
        const int ws = j >> 18, off = j & (NW4 - 1);
        const float* W = (ws == 0) ? W0 : (ws == 1) ? W1 : (ws == 2) ? W2 : W3;
        src = (const float4*)W + off;          dst = (bf16x4*)w_bf + (size_t)ws * NW4 + off;
    }
    const float4 v = *src;
    bf16x4 o;
    o[0] = (bf16_t)clamp50(v.x); o[1] = (bf16_t)clamp50(v.y);
    o[2] = (bf16_t)clamp50(v.z); o[3] = (bf16_t)clamp50(v.w);
    *dst = o;
}

// ---------------------------------------------------------------------------
// Shared GEMM core: 128xNT tile, BK=64, 4 waves (2x2), glds staging with
// source-side swizzle so LDS[row][c] = G[row][c^(row&7)]. K = 1024.
// ---------------------------------------------------------------------------
template <int NT>
__device__ __forceinline__ void gemm_core(const char* __restrict__ Ab, const char* __restrict__ Bb,
                                          bf16_t* Als, bf16_t* Bls,
                                          f32x4 (&acc)[4][NT / 32],
                                          int wave, int lane, int wm, int wn)
{
    constexpr int NF = NT / 32;
    const int srcsw = ((lane & 7) ^ (lane >> 3)) << 4;
    const int rowl = lane >> 3;

    for (int kt = 0; kt < HIDDEN / 64; ++kt) {
#pragma unroll
        for (int i = 0; i < 4; ++i) {
            const int row = i * 32 + wave * 8 + rowl;
            GLOAD16(Ab + (size_t)row * (HIDDEN * 2) + kt * 128 + srcsw,
                    (char*)Als + i * 4096 + wave * 1024);
        }
#pragma unroll
        for (int i = 0; i < NF; ++i) {
            const int row = i * 32 + wave * 8 + rowl;
            GLOAD16(Bb + (size_t)row * (HIDDEN * 2) + kt * 128 + srcsw,
                    (char*)Bls + i * 4096 + wave * 1024);
        }
        __syncthreads();
#pragma unroll
        for (int kc = 0; kc < 2; ++kc) {
            const int kbyte = kc * 64 + ((lane >> 4) << 4);
            bf16x8 af[4], bfr[NF];
#pragma unroll
            for (int f2 = 0; f2 < 4; ++f2) {
                const int arow = wm * 64 + f2 * 16 + (lane & 15);
                af[f2] = *(const bf16x8*)((const char*)Als + arow * 128 + (kbyte ^ ((arow & 7) << 4)));
            }
#pragma unroll
            for (int f2 = 0; f2 < NF; ++f2) {
                const int brow = wn * (NT / 2) + f2 * 16 + (lane & 15);
                bfr[f2] = *(const bf16x8*)((const char*)Bls + brow * 128 + (kbyte ^ ((brow & 7) << 4)));
            }
#pragma unroll
            for (int mf = 0; mf < 4; ++mf)
#pragma unroll
                for (int nf = 0; nf < NF; ++nf)
                    acc[mf][nf] = __builtin_amdgcn_mfma_f32_16x16x32_bf16(af[mf], bfr[nf], acc[mf][nf], 0, 0, 0);
        }
        __syncthreads();
    }
}

// EPI 0 epilogue: bf16 out in per-head layout [(b*16+h)][s][d], seqlen 1<<slog
template <int NF>
__device__ __forceinline__ void epi_head(f32x4 (&acc)[4][NF], const float* bias,
                                         bf16_t* out, int m0, int n0, int slog,
                                         int wm, int wn, int lane)
{
#pragma unroll
    for (int mf = 0; mf < 4; ++mf) {
#pragma unroll
        for (int nf = 0; nf < NF; ++nf) {
            const int gn = n0 + wn * (NF * 16) + nf * 16 + (lane & 15);
            const float bv = bias[gn];
#pragma unroll
            for (int r = 0; r < 4; ++r) {
                const int gm = m0 + wm * 64 + mf * 16 + ((lane >> 4) << 2) + r;
                const float v = clamp50(acc[mf][nf][r] + bv);
                const int b = gm >> slog;
                const int s = gm & ((1 << slog) - 1);
                const int h = gn >> 6, d = gn & 63;
                out[((((size_t)(b * NHEADS + h)) << slog) + s) * HDIM + d] = (bf16_t)v;
            }
        }
    }
}

// ---------------------------------------------------------------------------
// Generic GEMM kernel. EPI 0: bf16 per-head. EPI 1: fp32 [M][1024].
// ---------------------------------------------------------------------------
template <int EPI, int NT>
__global__ __launch_bounds__(256)
void gemm_bt_kernel(const bf16_t* __restrict__ A, const bf16_t* __restrict__ B,
                    const float* __restrict__ bias, void* __restrict__ out, int slog)
{
    constexpr int NF = NT / 32;
    __shared__ __align__(16) bf16_t Smem[(128 + NT) * 64];
    bf16_t* Als = Smem;
    bf16_t* Bls = Smem + 128 * 64;

    const int m0 = blockIdx.y * 128;
    const int n0 = blockIdx.x * NT;
    const int t = threadIdx.x;
    const int wave = t >> 6, lane = t & 63;
    const int wm = wave >> 1, wn = wave & 1;

    f32x4 acc[4][NF] = {};
    gemm_core<NT>((const char*)A + (size_t)m0 * (HIDDEN * 2),
                  (const char*)B + (size_t)n0 * (HIDDEN * 2),
                  Als, Bls, acc, wave, lane, wm, wn);

    if (EPI == 0) {
        epi_head<NF>(acc, bias, (bf16_t*)out, m0, n0, slog, wm, wn, lane);
    } else {
#pragma unroll
        for (int mf = 0; mf < 4; ++mf) {
#pragma unroll
            for (int nf = 0; nf < NF; ++nf) {
                const int gn = n0 + wn * (NF * 16) + nf * 16 + (lane & 15);
                const float bv = bias[gn];
#pragma unroll
                for (int r = 0; r < 4; ++r) {
                    const int gm = m0 + wm * 64 + mf * 16 + ((lane >> 4) << 2) + r;
                    ((float*)out)[(size_t)gm * HIDDEN + gn] = clamp50(acc[mf][nf][r] + bv);
                }
            }
        }
    }
}

// ---------------------------------------------------------------------------
// Fused K/V projection GEMM. Grid (16, 64): bx<8 -> Wk -> kh (per-head),
// bx>=8 -> Wv -> vt (per-head TRANSPOSED [bh][d][s], s = KVLEN).
// ---------------------------------------------------------------------------
__global__ __launch_bounds__(256)
void gemm_kv_fused(const bf16_t* __restrict__ A, const bf16_t* __restrict__ Bk,
                   const bf16_t* __restrict__ Bv, const float* __restrict__ bk,
                   const float* __restrict__ bv, bf16_t* __restrict__ kh,
                   bf16_t* __restrict__ vt)
{
    __shared__ __align__(16) bf16_t Smem[2 * 128 * 64];
    bf16_t* Als = Smem;
    bf16_t* Bls = Smem + 128 * 64;

    const int isV = blockIdx.x >> 3;
    const int n0 = (blockIdx.x & 7) * 128;
    const int m0 = blockIdx.y * 128;
    const int t = threadIdx.x;
    const int wave = t >> 6, lane = t & 63;
    const int wm = wave >> 1, wn = wave & 1;
    const bf16_t* B = isV ? Bv : Bk;
    const float* bias = isV ? bv : bk;

    f32x4 acc[4][4] = {};
    gemm_core<128>((const char*)A + (size_t)m0 * (HIDDEN * 2),
                   (const char*)B + (size_t)n0 * (HIDDEN * 2),
                   Als, Bls, acc, wave, lane, wm, wn);

    if (!isV) {
        epi_head<4>(acc, bias, kh, m0, n0, 11, wm, wn, lane);
        return;
    }

    // transpose epilogue via LDS (reuse Smem), 2 phases of 64 s-rows.
    bf16_t* Cls = Smem;                  // [64][130]
    const int dl = t >> 1;               // 0..127
    const int sh = (t & 1) << 5;         // 0 or 32
    const int gn = n0 + dl;
    const int h = gn >> 6, d = gn & 63;
    const int bb = m0 >> 11;
    bf16_t* dst = vt + ((size_t)((bb * NHEADS + h) * HDIM + d)) * KVLEN
                + (m0 & (KVLEN - 1)) + sh;
#pragma unroll
    for (int ph = 0; ph < 2; ++ph) {
        if (wm == ph) {
#pragma unroll
            for (int mf = 0; mf < 4; ++mf) {
#pragma unroll
                for (int nf = 0; nf < 4; ++nf) {
                    const int dcol = wn * 64 + nf * 16 + (lane & 15);
                    const float bv2 = bias[n0 + dcol];
#pragma unroll
                    for (int r = 0; r < 4; ++r) {
                        const int srow = mf * 16 + ((lane >> 4) << 2) + r;
                        Cls[srow * 130 + dcol] = (bf16_t)clamp50(acc[mf][nf][r] + bv2);
                    }
                }
            }
        }
        __syncthreads();
#pragma unroll
        for (int j0 = 0; j0 < 32; j0 += 8) {
            bf16x8 v;
#pragma unroll
            for (int j = 0; j < 8; ++j) v[j] = Cls[(sh + j0 + j) * 130 + dl];
            *(bf16x8*)(dst + ph * 64 + j0) = v;
        }
        __syncthreads();
    }
}

// ---------------------------------------------------------------------------
// Flash attention, fixed-max softmax, KV-SPLIT x2 (additive partials).
// Grid 1024 = 8 XCD x (8 bh x 8 qt x 2 half). Each block: 128 q-rows,
// 16 KV-tiles of 64. Partial O/l accumulated via fp32 atomics.
// ---------------------------------------------------------------------------
__global__ __launch_bounds__(256)
void attn_fwd_kernel(const bf16_t* __restrict__ Qh, const bf16_t* __restrict__ Kh,
                     const bf16_t* __restrict__ Vt, const float* __restrict__ maskadd,
                     float* __restrict__ Obuf, float* __restrict__ Lbuf)
{
    __shared__ __align__(16) bf16_t Kls[2][64 * 64];
    __shared__ __align__(16) bf16_t Vls[2][64 * 64];
    __shared__ __align__(16) bf16_t Pls[4][32 * 64];

    // XCD-grouped swizzle: xcd c -> o in [128c, 128c+128) -> 8 bh per XCD
    const int f = blockIdx.x;
    const int o = (f & 7) * 128 + (f >> 3);
    const int bh = o >> 4;
    const int qt = (o >> 1) & 7;
    const int half = o & 1;
    const int b = bh >> 4, h = bh & 15;
    const int t = threadIdx.x, wave = t >> 6, lane = t & 63;

    const int qbase = qt * 128 + wave * 32;
    bf16x8 qf[2][2];
#pragma unroll
    for (int qq = 0; qq < 2; ++qq) {
        const bf16_t* qp = Qh + ((size_t)bh * QLEN + qbase + qq * 16 + (lane & 15)) * HDIM
                         + ((lane >> 4) << 3);
        qf[qq][0] = *(const bf16x8*)qp;
        qf[qq][1] = *(const bf16x8*)(qp + 32);
    }

    f32x4 oacc[2][4] = {};
    float lsum[2][4] = {};

    const int srcsw = ((lane & 7) ^ (lane >> 3)) << 4;
    const int rowl = lane >> 3;
    // bases offset to this block's KV half (1024 keys)
    const char* Kb = (const char*)(Kh + (size_t)bh * KVLEN * HDIM) + ((size_t)half << 17);
    const char* Vb = (const char*)(Vt + (size_t)bh * HDIM * KVLEN) + (half * 2048);
    const float* mrow = maskadd + b * KVLEN + half * 1024;
    char* Pb = (char*)(&Pls[wave][0]);
    const int rbase = (lane >> 4) << 2;
    const int kb0 = (lane >> 4) << 4;

    // prologue: stage local tile 0 into buf 0, preload mask tile 0
#pragma unroll
    for (int i = 0; i < 2; ++i) {
        const int row = i * 32 + wave * 8 + rowl;
        GLOAD16(Kb + (size_t)row * 128 + srcsw,
                (char*)&Kls[0][0] + i * 4096 + wave * 1024);
        GLOAD16(Vb + (size_t)row * (KVLEN * 2) + srcsw,
                (char*)&Vls[0][0] + i * 4096 + wave * 1024);
    }
    float madd_c[4], madd_n[4];
#pragma unroll
    for (int kb = 0; kb < 4; ++kb)
        madd_c[kb] = mrow[kb * 16 + (lane & 15)];
    __syncthreads();

    for (int kt = 0; kt < 16; ++kt) {
        const int cur = kt & 1;
        if (kt < 15) {
#pragma unroll
            for (int i = 0; i < 2; ++i) {
                const int row = i * 32 + wave * 8 + rowl;
                GLOAD16(Kb + (size_t)((kt + 1) * 64 + row) * 128 + srcsw,
                        (char*)&Kls[cur ^ 1][0] + i * 4096 + wave * 1024);
                GLOAD16(Vb + (size_t)row * (KVLEN * 2) + (size_t)(kt + 1) * 128 + srcsw,
                        (char*)&Vls[cur ^ 1][0] + i * 4096 + wave * 1024);
            }
#pragma unroll
            for (int kb = 0; kb < 4; ++kb)
                madd_n[kb] = mrow[(kt + 1) * 64 + kb * 16 + (lane & 15)];
        }
        const char* Kc = (const char*)&Kls[cur][0];
        const char* Vc = (const char*)&Vls[cur][0];

        // ---- S = Q K^T (per qq block)
        f32x4 sacc[2][4] = {};
#pragma unroll
        for (int kb = 0; kb < 4; ++kb) {
            const int key = kb * 16 + (lane & 15);
            const int rowoff = key * 128;
            const int sw = (key & 7) << 4;
            const bf16x8 kf0 = *(const bf16x8*)(Kc + rowoff + ((kb0)      ^ sw));
            const bf16x8 kf1 = *(const bf16x8*)(Kc + rowoff + ((kb0 + 64) ^ sw));
#pragma unroll
            for (int qq = 0; qq < 2; ++qq) {
                sacc[qq][kb] = __builtin_amdgcn_mfma_f32_16x16x32_bf16(qf[qq][0], kf0, sacc[qq][kb], 0, 0, 0);
                sacc[qq][kb] = __builtin_amdgcn_mfma_f32_16x16x32_bf16(qf[qq][1], kf1, sacc[qq][kb], 0, 0, 0);
            }
        }

        // ---- fixed-max softmax: fma + exp2
#pragma unroll
        for (int qq = 0; qq < 2; ++qq) {
#pragma unroll
            for (int r = 0; r < 4; ++r) {
                float p[4];
#pragma unroll
                for (int kb = 0; kb < 4; ++kb)
                    p[kb] = __builtin_amdgcn_exp2f(__builtin_fmaf(sacc[qq][kb][r], C_SCALE, madd_c[kb]));
                lsum[qq][r] += (p[0] + p[1]) + (p[2] + p[3]);
                const int prow = qq * 16 + rbase + r;
                const int sw2 = (prow & 7) << 4;
                const int rowoff2 = prow * 128;
#pragma unroll
                for (int kb = 0; kb < 4; ++kb) {
                    const int key = kb * 16 + (lane & 15);
                    *(bf16_t*)(Pb + rowoff2 + ((key * 2) ^ sw2)) = (bf16_t)p[kb];
                }
            }
        }

        // ---- O += P V
        {
            bf16x8 pf[2][2];
#pragma unroll
            for (int qq = 0; qq < 2; ++qq) {
                const int prow = qq * 16 + (lane & 15);
                const int psw = (prow & 7) << 4;
                pf[qq][0] = *(const bf16x8*)(Pb + prow * 128 + ((kb0)      ^ psw));
                pf[qq][1] = *(const bf16x8*)(Pb + prow * 128 + ((kb0 + 64) ^ psw));
            }
#pragma unroll
            for (int db = 0; db < 4; ++db) {
                const int vrow = db * 16 + (lane & 15);
                const int vsw = (vrow & 7) << 4;
                const bf16x8 vf0 = *(const bf16x8*)(Vc + vrow * 128 + ((kb0)      ^ vsw));
                const bf16x8 vf1 = *(const bf16x8*)(Vc + vrow * 128 + ((kb0 + 64) ^ vsw));
#pragma unroll
                for (int qq = 0; qq < 2; ++qq) {
                    oacc[qq][db] = __builtin_amdgcn_mfma_f32_16x16x32_bf16(pf[qq][0], vf0, oacc[qq][db], 0, 0, 0);
                    oacc[qq][db] = __builtin_amdgcn_mfma_f32_16x16x32_bf16(pf[qq][1], vf1, oacc[qq][db], 0, 0, 0);
                }
            }
        }

        __syncthreads();
#pragma unroll
        for (int kb = 0; kb < 4; ++kb) madd_c[kb] = madd_n[kb];
    }

    // ---- epilogue: additive partials -> fp32 atomics
#pragma unroll
    for (int qq = 0; qq < 2; ++qq) {
#pragma unroll
        for (int r = 0; r < 4; ++r) {
            float l = lsum[qq][r];
            l += __shfl_xor(l, 1);
            l += __shfl_xor(l, 2);
            l += __shfl_xor(l, 4);
            l += __shfl_xor(l, 8);
            if ((lane & 15) == 0) {
                const int qrow = qbase + qq * 16 + rbase + r;
                atomicAdd(&Lbuf[bh * QLEN + qrow], l);
            }
        }
    }
#pragma unroll
    for (int qq = 0; qq < 2; ++qq) {
#pragma unroll
        for (int db = 0; db < 4; ++db) {
            const int d = db * 16 + (lane & 15);
#pragma unroll
            for (int r = 0; r < 4; ++r) {
                const int qrow = qbase + qq * 16 + rbase + r;
                atomicAdd(&Obuf[((size_t)(bh * QLEN + qrow)) * HDIM + d], oacc[qq][db][r]);
            }
        }
    }
}

// ---------------------------------------------------------------------------
// Combine: aout[b][q][h*64+d] = Obuf[bh][q][d] / Lbuf[bh][q]   (bf16 out)
// ---------------------------------------------------------------------------
__global__ void combine_kernel(const float* __restrict__ Obuf, const float* __restrict__ Lbuf,
                               bf16_t* __restrict__ aout) {
    const int i = blockIdx.x * blockDim.x + threadIdx.x;   // 1M threads
    const int bhq = i >> 4, d4 = i & 15;
    const int bh = bhq >> 10, q = bhq & 1023;
    const int b = bh >> 4, h = bh & 15;
    const f32x4 o = *(const f32x4*)(Obuf + (size_t)i * 4);
    const float invl = 1.0f / Lbuf[bhq];
    bf16x4 r;
    r[0] = (bf16_t)(o[0] * invl); r[1] = (bf16_t)(o[1] * invl);
    r[2] = (bf16_t)(o[2] * invl); r[3] = (bf16_t)(o[3] * invl);
    *(bf16x4*)(aout + ((size_t)(b * QLEN + q)) * HIDDEN + h * HDIM + d4 * 4) = r;
}

// ---------------------------------------------------------------------------
extern "C" void kernel_launch(void* const* d_in, const int* in_sizes, int n_in,
                              void* d_out, int out_size, void* d_ws, size_t ws_size,
                              hipStream_t stream) {
    (void)in_sizes; (void)n_in; (void)out_size; (void)ws_size;
    const float* q   = (const float*)d_in[0];
    const float* kv  = (const float*)d_in[1];
    const void*  msk = d_in[2];
    const float* Wq  = (const float*)d_in[3];
    const float* bq  = (const float*)d_in[4];
    const float* Wk  = (const float*)d_in[5];
    const float* bk  = (const float*)d_in[6];
    const float* Wv  = (const float*)d_in[7];
    const float* bv  = (const float*)d_in[8];
    const float* Wo  = (const float*)d_in[9];
    const float* bo  = (const float*)d_in[10];

    char* ws = (char*)d_ws;
    const size_t MB = 1024 * 1024;
    float*  maskadd = (float*)ws;                              // 32 KB
    bf16_t* w_bf  = (bf16_t*)(ws + 32 * 1024);                 // 8 MB (4 weights)
    bf16_t* q_bf  = (bf16_t*)(ws + 32 * 1024 + 8  * MB);       // 8 MB (reused as aout)
    bf16_t* kv_bf = (bf16_t*)(ws + 32 * 1024 + 16 * MB);       // 16 MB (reused as Obuf)
    bf16_t* qh    = (bf16_t*)(ws + 32 * 1024 + 32 * MB);       // 8 MB
    bf16_t* kh    = (bf16_t*)(ws + 32 * 1024 + 40 * MB);       // 16 MB
    bf16_t* vt    = (bf16_t*)(ws + 32 * 1024 + 56 * MB);       // 16 MB -> end 72 MB
    bf16_t* aout  = q_bf;           // q_bf dead after q-GEMM
    float*  Obuf  = (float*)kv_bf;  // kv_bf dead after kv-GEMM (16 MB = 4M fp32)
    float*  Lbuf  = (float*)w_bf;   // wq region dead after q-GEMM (256 KB)

    bf16_t* wq_bf = w_bf;
    bf16_t* wk_bf = w_bf + (size_t)HIDDEN * HIDDEN;
    bf16_t* wv_bf = w_bf + (size_t)2 * HIDDEN * HIDDEN;
    bf16_t* wo_bf = w_bf + (size_t)3 * HIDDEN * HIDDEN;

    mask_prep_kernel<<<dim3(16), 256, 0, stream>>>(msk, maskadd);
    cvt_all_kernel<<<dim3((NQ4 + NKV4 + 4 * NW4) / 256), 256, 0, stream>>>(
        q, kv, Wq, Wk, Wv, Wo, q_bf, kv_bf, w_bf);

    gemm_bt_kernel<0, 64><<<dim3(16, 32), 256, 0, stream>>>(q_bf, wq_bf, bq, qh, 10);
    gemm_kv_fused<<<dim3(16, 64), 256, 0, stream>>>(kv_bf, wk_bf, wv_bf, bk, bv, kh, vt);

    hipMemsetAsync(Obuf, 0, (size_t)BSZ * NHEADS * QLEN * HDIM * 4, stream);
    hipMemsetAsync(Lbuf, 0, (size_t)BSZ * NHEADS * QLEN * 4, stream);

    attn_fwd_kernel<<<dim3(1024), 256, 0, stream>>>(qh, kh, vt, maskadd, Obuf, Lbuf);
    combine_kernel<<<dim3(4096), 256, 0, stream>>>(Obuf, Lbuf, aout);

    gemm_bt_kernel<1, 64><<<dim3(16, 32), 256, 0, stream>>>(aout, wo_bf, bo, d_out, 10);
}

// Round 6
// 166.987 us; speedup vs baseline: 1.2500x; 1.2500x over previous
//
#include <hip/hip_runtime.h>
#include <hip/hip_bf16.h>
#include <stdint.h>
#include <math.h>

#define HIDDEN 1024
#define NHEADS 16
#define HDIM   64
#define BSZ    4
#define QLEN   1024
#define KVLEN  2048

typedef __bf16 bf16_t;
typedef __bf16 bf16x8 __attribute__((ext_vector_type(8)));
typedef __bf16 bf16x4 __attribute__((ext_vector_type(4)));
typedef float  f32x4  __attribute__((ext_vector_type(4)));

// fixed-max softmax: p = exp2( s_raw*C_SCALE + madd ).
#define C_SCALE 0.18033688f     /* 0.125 * log2(e) */
#define C_FMADD (-43.2808512f)  /* -30 * log2(e) */

#define GLOAD16(g, l) \
    __builtin_amdgcn_global_load_lds((const __attribute__((address_space(1))) void*)(g), \
                                     (__attribute__((address_space(3))) void*)(l), 16, 0, 0)

__device__ __forceinline__ float clamp50(float v) {
    return fminf(fmaxf(v, -50.f), 50.f);
}

// ---------------------------------------------------------------------------
// Mask prep, 16 blocks (redundant dtype detection per block).
// ---------------------------------------------------------------------------
__global__ void mask_prep_kernel(const void* __restrict__ raw, float* __restrict__ maskadd) {
    __shared__ int s_float, s_multi;
    const int t = threadIdx.x;
    if (t == 0) { s_float = 0; s_multi = 0; }
    __syncthreads();
    const uint32_t* w = (const uint32_t*)raw;
    int cf = 0, cm = 0;
    for (int i = t; i < 2048; i += blockDim.x) {
        uint32_t v = w[i];
        if (v == 0x3F800000u) cf++;
        else if (v & 0xFFFFFF00u) cm++;
    }
    if (cf) atomicAdd(&s_float, cf);
    if (cm) atomicAdd(&s_multi, cm);
    __syncthreads();
    const int mode = (s_float > 0) ? 2 : ((s_multi > 0) ? 0 : 1);
    const int base = blockIdx.x * 512;
    for (int i = base + t; i < base + 512; i += blockDim.x) {
        bool m;
        if (mode == 2)      m = ((const float*)raw)[i] != 0.0f;
        else if (mode == 1) m = ((const int*)raw)[i] != 0;
        else                m = ((const unsigned char*)raw)[i] != 0;
        maskadd[i] = m ? (-100000.0f + C_FMADD) : C_FMADD;
    }
}

// ---------------------------------------------------------------------------
// One launch converts q, kv, and all 4 weights fp32 -> bf16 with clamp50.
// ---------------------------------------------------------------------------
#define NQ4  ((BSZ * QLEN  * HIDDEN) / 4)   /* 1048576 */
#define NKV4 ((BSZ * KVLEN * HIDDEN) / 4)   /* 2097152 */
#define NW4  ((HIDDEN * HIDDEN) / 4)        /* 262144  */

__global__ void cvt_all_kernel(const float* __restrict__ q, const float* __restrict__ kv,
                               const float* __restrict__ W0, const float* __restrict__ W1,
                               const float* __restrict__ W2, const float* __restrict__ W3,
                               bf16_t* __restrict__ q_bf, bf16_t* __restrict__ kv_bf,
                               bf16_t* __restrict__ w_bf) {
    const int i = blockIdx.x * blockDim.x + threadIdx.x;
    const float4* src;
    bf16x4* dst;
    if (i < NQ4) {
        src = (const float4*)q + i;            dst = (bf16x4*)q_bf + i;
    } else if (i < NQ4 + NKV4) {
        const int j = i - NQ4;
        src = (const float4*)kv + j;           dst = (bf16x4*)kv_bf + j;
    } else {
        const int j = i - (NQ4 + NKV4);
        const int ws = j >> 18, off = j & (NW4 - 1);
        const float* W = (ws == 0) ? W0 : (ws == 1) ? W1 : (ws == 2) ? W2 : W3;
        src = (const float4*)W + off;          dst = (bf16x4*)w_bf + (size_t)ws * NW4 + off;
    }
    const float4 v = *src;
    bf16x4 o;
    o[0] = (bf16_t)clamp50(v.x); o[1] = (bf16_t)clamp50(v.y);
    o[2] = (bf16_t)clamp50(v.z); o[3] = (bf16_t)clamp50(v.w);
    *dst = o;
}

// ---------------------------------------------------------------------------
// Shared GEMM core: 128xNT tile, BK=64, 4 waves (2x2), glds staging with
// source-side swizzle so LDS[row][c] = G[row][c^(row&7)]. K = 1024.
// ---------------------------------------------------------------------------
template <int NT>
__device__ __forceinline__ void gemm_core(const char* __restrict__ Ab, const char* __restrict__ Bb,
                                          bf16_t* Als, bf16_t* Bls,
                                          f32x4 (&acc)[4][NT / 32],
                                          int wave, int lane, int wm, int wn)
{
    constexpr int NF = NT / 32;
    const int srcsw = ((lane & 7) ^ (lane >> 3)) << 4;
    const int rowl = lane >> 3;

    for (int kt = 0; kt < HIDDEN / 64; ++kt) {
#pragma unroll
        for (int i = 0; i < 4; ++i) {
            const int row = i * 32 + wave * 8 + rowl;
            GLOAD16(Ab + (size_t)row * (HIDDEN * 2) + kt * 128 + srcsw,
                    (char*)Als + i * 4096 + wave * 1024);
        }
#pragma unroll
        for (int i = 0; i < NF; ++i) {
            const int row = i * 32 + wave * 8 + rowl;
            GLOAD16(Bb + (size_t)row * (HIDDEN * 2) + kt * 128 + srcsw,
                    (char*)Bls + i * 4096 + wave * 1024);
        }
        __syncthreads();
#pragma unroll
        for (int kc = 0; kc < 2; ++kc) {
            const int kbyte = kc * 64 + ((lane >> 4) << 4);
            bf16x8 af[4], bfr[NF];
#pragma unroll
            for (int f2 = 0; f2 < 4; ++f2) {
                const int arow = wm * 64 + f2 * 16 + (lane & 15);
                af[f2] = *(const bf16x8*)((const char*)Als + arow * 128 + (kbyte ^ ((arow & 7) << 4)));
            }
#pragma unroll
            for (int f2 = 0; f2 < NF; ++f2) {
                const int brow = wn * (NT / 2) + f2 * 16 + (lane & 15);
                bfr[f2] = *(const bf16x8*)((const char*)Bls + brow * 128 + (kbyte ^ ((brow & 7) << 4)));
            }
#pragma unroll
            for (int mf = 0; mf < 4; ++mf)
#pragma unroll
                for (int nf = 0; nf < NF; ++nf)
                    acc[mf][nf] = __builtin_amdgcn_mfma_f32_16x16x32_bf16(af[mf], bfr[nf], acc[mf][nf], 0, 0, 0);
        }
        __syncthreads();
    }
}

// EPI 0 epilogue: bf16 out in per-head layout [(b*16+h)][s][d], seqlen 1<<slog
template <int NF>
__device__ __forceinline__ void epi_head(f32x4 (&acc)[4][NF], const float* bias,
                                         bf16_t* out, int m0, int n0, int slog,
                                         int wm, int wn, int lane)
{
#pragma unroll
    for (int mf = 0; mf < 4; ++mf) {
#pragma unroll
        for (int nf = 0; nf < NF; ++nf) {
            const int gn = n0 + wn * (NF * 16) + nf * 16 + (lane & 15);
            const float bv = bias[gn];
#pragma unroll
            for (int r = 0; r < 4; ++r) {
                const int gm = m0 + wm * 64 + mf * 16 + ((lane >> 4) << 2) + r;
                const float v = clamp50(acc[mf][nf][r] + bv);
                const int b = gm >> slog;
                const int s = gm & ((1 << slog) - 1);
                const int h = gn >> 6, d = gn & 63;
                out[((((size_t)(b * NHEADS + h)) << slog) + s) * HDIM + d] = (bf16_t)v;
            }
        }
    }
}

// ---------------------------------------------------------------------------
// Generic GEMM kernel. EPI 0: bf16 per-head. EPI 1: fp32 [M][1024].
// ---------------------------------------------------------------------------
template <int EPI, int NT>
__global__ __launch_bounds__(256)
void gemm_bt_kernel(const bf16_t* __restrict__ A, const bf16_t* __restrict__ B,
                    const float* __restrict__ bias, void* __restrict__ out, int slog)
{
    constexpr int NF = NT / 32;
    __shared__ __align__(16) bf16_t Smem[(128 + NT) * 64];
    bf16_t* Als = Smem;
    bf16_t* Bls = Smem + 128 * 64;

    const int m0 = blockIdx.y * 128;
    const int n0 = blockIdx.x * NT;
    const int t = threadIdx.x;
    const int wave = t >> 6, lane = t & 63;
    const int wm = wave >> 1, wn = wave & 1;

    f32x4 acc[4][NF] = {};
    gemm_core<NT>((const char*)A + (size_t)m0 * (HIDDEN * 2),
                  (const char*)B + (size_t)n0 * (HIDDEN * 2),
                  Als, Bls, acc, wave, lane, wm, wn);

    if (EPI == 0) {
        epi_head<NF>(acc, bias, (bf16_t*)out, m0, n0, slog, wm, wn, lane);
    } else {
#pragma unroll
        for (int mf = 0; mf < 4; ++mf) {
#pragma unroll
            for (int nf = 0; nf < NF; ++nf) {
                const int gn = n0 + wn * (NF * 16) + nf * 16 + (lane & 15);
                const float bv = bias[gn];
#pragma unroll
                for (int r = 0; r < 4; ++r) {
                    const int gm = m0 + wm * 64 + mf * 16 + ((lane >> 4) << 2) + r;
                    ((float*)out)[(size_t)gm * HIDDEN + gn] = clamp50(acc[mf][nf][r] + bv);
                }
            }
        }
    }
}

// ---------------------------------------------------------------------------
// Fused K/V projection GEMM. Grid (16, 64): bx<8 -> Wk -> kh (per-head),
// bx>=8 -> Wv -> vt (per-head TRANSPOSED [bh][d][s], s = KVLEN).
// ---------------------------------------------------------------------------
__global__ __launch_bounds__(256)
void gemm_kv_fused(const bf16_t* __restrict__ A, const bf16_t* __restrict__ Bk,
                   const bf16_t* __restrict__ Bv, const float* __restrict__ bk,
                   const float* __restrict__ bv, bf16_t* __restrict__ kh,
                   bf16_t* __restrict__ vt)
{
    __shared__ __align__(16) bf16_t Smem[2 * 128 * 64];
    bf16_t* Als = Smem;
    bf16_t* Bls = Smem + 128 * 64;

    const int isV = blockIdx.x >> 3;
    const int n0 = (blockIdx.x & 7) * 128;
    const int m0 = blockIdx.y * 128;
    const int t = threadIdx.x;
    const int wave = t >> 6, lane = t & 63;
    const int wm = wave >> 1, wn = wave & 1;
    const bf16_t* B = isV ? Bv : Bk;
    const float* bias = isV ? bv : bk;

    f32x4 acc[4][4] = {};
    gemm_core<128>((const char*)A + (size_t)m0 * (HIDDEN * 2),
                   (const char*)B + (size_t)n0 * (HIDDEN * 2),
                   Als, Bls, acc, wave, lane, wm, wn);

    if (!isV) {
        epi_head<4>(acc, bias, kh, m0, n0, 11, wm, wn, lane);
        return;
    }

    // transpose epilogue via LDS (reuse Smem), 2 phases of 64 s-rows.
    bf16_t* Cls = Smem;                  // [64][130]
    const int dl = t >> 1;               // 0..127
    const int sh = (t & 1) << 5;         // 0 or 32
    const int gn = n0 + dl;
    const int h = gn >> 6, d = gn & 63;
    const int bb = m0 >> 11;
    bf16_t* dst = vt + ((size_t)((bb * NHEADS + h) * HDIM + d)) * KVLEN
                + (m0 & (KVLEN - 1)) + sh;
#pragma unroll
    for (int ph = 0; ph < 2; ++ph) {
        if (wm == ph) {
#pragma unroll
            for (int mf = 0; mf < 4; ++mf) {
#pragma unroll
                for (int nf = 0; nf < 4; ++nf) {
                    const int dcol = wn * 64 + nf * 16 + (lane & 15);
                    const float bv2 = bias[n0 + dcol];
#pragma unroll
                    for (int r = 0; r < 4; ++r) {
                        const int srow = mf * 16 + ((lane >> 4) << 2) + r;
                        Cls[srow * 130 + dcol] = (bf16_t)clamp50(acc[mf][nf][r] + bv2);
                    }
                }
            }
        }
        __syncthreads();
#pragma unroll
        for (int j0 = 0; j0 < 32; j0 += 8) {
            bf16x8 v;
#pragma unroll
            for (int j = 0; j < 8; ++j) v[j] = Cls[(sh + j0 + j) * 130 + dl];
            *(bf16x8*)(dst + ph * 64 + j0) = v;
        }
        __syncthreads();
    }
}

// ---------------------------------------------------------------------------
// Flash attention, fixed-max softmax, SWAPPED QK^T + permuted-K staging:
// P never touches LDS. Grid 512 (XCD-grouped), 4 waves x 32 q-rows.
//
// K LDS row i holds global key kap(i) = 32*(i>>5) + 8*((i>>2)&3)
//   + 4*((i>>4)&1) + (i&3). With S^T = mfma(K,Q), lane (g = lane>>4,
//   q = lane&15) then holds P[q][key] for keys {8g..8g+7} (regs p[0..1])
//   and {32+8g..+7} (regs p[2..3]) -- exactly the PV A-fragment layout.
// ---------------------------------------------------------------------------
__global__ __launch_bounds__(256)
void attn_fwd_kernel(const bf16_t* __restrict__ Qh, const bf16_t* __restrict__ Kh,
                     const bf16_t* __restrict__ Vt, const float* __restrict__ maskadd,
                     bf16_t* __restrict__ aout)
{
    __shared__ __align__(16) bf16_t Kls[2][64 * 64];
    __shared__ __align__(16) bf16_t Vls[2][64 * 64];

    // XCD-grouped swizzle (512 = 8 XCDs x 64): xcd c -> bh in [8c, 8c+8)
    const int f = blockIdx.x;
    const int o = (f & 7) * 64 + (f >> 3);
    const int qt = o & 7;          // 8 q-tiles of 128
    const int bh = o >> 3;
    const int b = bh >> 4, h = bh & 15;
    const int t = threadIdx.x, wave = t >> 6, lane = t & 63;
    const int g = lane >> 4;       // lane group 0..3
    const int ql = lane & 15;      // q within 16-block

    const int qbase = qt * 128 + wave * 32;
    bf16x8 qf[2][2];
#pragma unroll
    for (int qq = 0; qq < 2; ++qq) {
        const bf16_t* qp = Qh + ((size_t)bh * QLEN + qbase + qq * 16 + ql) * HDIM + (g << 3);
        qf[qq][0] = *(const bf16x8*)qp;
        qf[qq][1] = *(const bf16x8*)(qp + 32);
    }

    f32x4 oacc[2][4] = {};
    float lsum[2] = {0.f, 0.f};

    const int srcsw = ((lane & 7) ^ (lane >> 3)) << 4;
    const int R0 = wave * 8 + (lane >> 3);    // LDS row this lane stages (i=0)
    const int R1 = R0 + 32;
    const int kap0 = 32 * (R0 >> 5) + 8 * ((R0 >> 2) & 3) + 4 * ((R0 >> 4) & 1) + (R0 & 3);
    const int kap1 = 32 * (R1 >> 5) + 8 * ((R1 >> 2) & 3) + 4 * ((R1 >> 4) & 1) + (R1 & 3);

    const char* Kb = (const char*)(Kh + (size_t)bh * KVLEN * HDIM);
    const char* Vb = (const char*)(Vt + (size_t)bh * HDIM * KVLEN);
    const float* mrow = maskadd + b * KVLEN;
    const int m8g = g * 8;   // mask offsets per kb: m8g + {0,4,32,36}

    // prologue: stage tile 0 into buf 0 (K rows permuted), preload mask
    GLOAD16(Kb + (size_t)kap0 * 128 + srcsw, (char*)&Kls[0][0] + wave * 1024);
    GLOAD16(Kb + (size_t)kap1 * 128 + srcsw, (char*)&Kls[0][0] + 4096 + wave * 1024);
    GLOAD16(Vb + (size_t)R0 * (KVLEN * 2) + srcsw, (char*)&Vls[0][0] + wave * 1024);
    GLOAD16(Vb + (size_t)R1 * (KVLEN * 2) + srcsw, (char*)&Vls[0][0] + 4096 + wave * 1024);

    f32x4 madd_c[4], madd_n[4];
    madd_c[0] = *(const f32x4*)(mrow + m8g);
    madd_c[1] = *(const f32x4*)(mrow + m8g + 4);
    madd_c[2] = *(const f32x4*)(mrow + m8g + 32);
    madd_c[3] = *(const f32x4*)(mrow + m8g + 36);
    __syncthreads();

    for (int kt = 0; kt < KVLEN / 64; ++kt) {
        const int cur = kt & 1;
        if (kt < KVLEN / 64 - 1) {
            const size_t ko = (size_t)(kt + 1) * 8192;
            GLOAD16(Kb + ko + (size_t)kap0 * 128 + srcsw,
                    (char*)&Kls[cur ^ 1][0] + wave * 1024);
            GLOAD16(Kb + ko + (size_t)kap1 * 128 + srcsw,
                    (char*)&Kls[cur ^ 1][0] + 4096 + wave * 1024);
            GLOAD16(Vb + (size_t)R0 * (KVLEN * 2) + (size_t)(kt + 1) * 128 + srcsw,
                    (char*)&Vls[cur ^ 1][0] + wave * 1024);
            GLOAD16(Vb + (size_t)R1 * (KVLEN * 2) + (size_t)(kt + 1) * 128 + srcsw,
                    (char*)&Vls[cur ^ 1][0] + 4096 + wave * 1024);
            const float* mn = mrow + (kt + 1) * 64 + m8g;
            madd_n[0] = *(const f32x4*)(mn);
            madd_n[1] = *(const f32x4*)(mn + 4);
            madd_n[2] = *(const f32x4*)(mn + 32);
            madd_n[3] = *(const f32x4*)(mn + 36);
        }
        const char* Kc = (const char*)&Kls[cur][0];
        const char* Vc = (const char*)&Vls[cur][0];

        // ---- S^T = K Q^T : A = K-frag (LDS perm rows), B = Q-frag
        f32x4 sacc[2][4] = {};
#pragma unroll
        for (int kb = 0; kb < 4; ++kb) {
            const int key = kb * 16 + ql;
            const int rowoff = key * 128;
            const int sw = (key & 7) << 4;
            const int kb0 = g << 4;
            const bf16x8 kf0 = *(const bf16x8*)(Kc + rowoff + ((kb0)      ^ sw));
            const bf16x8 kf1 = *(const bf16x8*)(Kc + rowoff + ((kb0 + 64) ^ sw));
#pragma unroll
            for (int qq = 0; qq < 2; ++qq) {
                sacc[qq][kb] = __builtin_amdgcn_mfma_f32_16x16x32_bf16(kf0, qf[qq][0], sacc[qq][kb], 0, 0, 0);
                sacc[qq][kb] = __builtin_amdgcn_mfma_f32_16x16x32_bf16(kf1, qf[qq][1], sacc[qq][kb], 0, 0, 0);
            }
        }

        // ---- softmax weights in-register + pack to PV A-fragments
        bf16x8 pa[2][2];
#pragma unroll
        for (int qq = 0; qq < 2; ++qq) {
            float pv[4][4];
            float ls = 0.f;
#pragma unroll
            for (int kb = 0; kb < 4; ++kb) {
#pragma unroll
                for (int r = 0; r < 4; ++r) {
                    pv[kb][r] = __builtin_amdgcn_exp2f(
                        __builtin_fmaf(sacc[qq][kb][r], C_SCALE, madd_c[kb][r]));
                    ls += pv[kb][r];
                }
            }
            lsum[qq] += ls;
#pragma unroll
            for (int r = 0; r < 4; ++r) {
                pa[qq][0][r]     = (bf16_t)pv[0][r];
                pa[qq][0][4 + r] = (bf16_t)pv[1][r];
                pa[qq][1][r]     = (bf16_t)pv[2][r];
                pa[qq][1][4 + r] = (bf16_t)pv[3][r];
            }
        }

        // ---- O += P V   (A = pa regs, B = V^T tile, natural key order)
#pragma unroll
        for (int db = 0; db < 4; ++db) {
            const int vrow = db * 16 + ql;
            const int vsw = (vrow & 7) << 4;
            const int kb0 = g << 4;
            const bf16x8 vf0 = *(const bf16x8*)(Vc + vrow * 128 + ((kb0)      ^ vsw));
            const bf16x8 vf1 = *(const bf16x8*)(Vc + vrow * 128 + ((kb0 + 64) ^ vsw));
#pragma unroll
            for (int qq = 0; qq < 2; ++qq) {
                oacc[qq][db] = __builtin_amdgcn_mfma_f32_16x16x32_bf16(pa[qq][0], vf0, oacc[qq][db], 0, 0, 0);
                oacc[qq][db] = __builtin_amdgcn_mfma_f32_16x16x32_bf16(pa[qq][1], vf1, oacc[qq][db], 0, 0, 0);
            }
        }

        __syncthreads();   // drains glds -> next buffer ready
#pragma unroll
        for (int kb = 0; kb < 4; ++kb) madd_c[kb] = madd_n[kb];
    }

    // ---- epilogue: full l per q via 2 shuffles; route l to output lanes
#pragma unroll
    for (int qq = 0; qq < 2; ++qq) {
        float l = lsum[qq];
        l += __shfl_xor(l, 16);
        l += __shfl_xor(l, 32);
        lsum[qq] = l;       // every lane now holds L(q = lane&15)
    }
    const int rbase = g << 2;
#pragma unroll
    for (int qq = 0; qq < 2; ++qq) {
#pragma unroll
        for (int r = 0; r < 4; ++r) {
            const float Lr = __shfl(lsum[qq], rbase + r);   // L(qrow = 4g+r)
            const float inv = 1.0f / Lr;
            const int qrow = qbase + qq * 16 + rbase + r;
            bf16_t* orow = aout + ((size_t)(b * QLEN + qrow)) * HIDDEN + h * HDIM;
#pragma unroll
            for (int db = 0; db < 4; ++db)
                orow[db * 16 + ql] = (bf16_t)(oacc[qq][db][r] * inv);
        }
    }
}

// ---------------------------------------------------------------------------
extern "C" void kernel_launch(void* const* d_in, const int* in_sizes, int n_in,
                              void* d_out, int out_size, void* d_ws, size_t ws_size,
                              hipStream_t stream) {
    (void)in_sizes; (void)n_in; (void)out_size; (void)ws_size;
    const float* q   = (const float*)d_in[0];
    const float* kv  = (const float*)d_in[1];
    const void*  msk = d_in[2];
    const float* Wq  = (const float*)d_in[3];
    const float* bq  = (const float*)d_in[4];
    const float* Wk  = (const float*)d_in[5];
    const float* bk  = (const float*)d_in[6];
    const float* Wv  = (const float*)d_in[7];
    const float* bv  = (const float*)d_in[8];
    const float* Wo  = (const float*)d_in[9];
    const float* bo  = (const float*)d_in[10];

    char* ws = (char*)d_ws;
    const size_t MB = 1024 * 1024;
    float*  maskadd = (float*)ws;                              // 32 KB
    bf16_t* w_bf  = (bf16_t*)(ws + 32 * 1024);                 // 8 MB (4 weights)
    bf16_t* q_bf  = (bf16_t*)(ws + 32 * 1024 + 8  * MB);       // 8 MB (reused as aout)
    bf16_t* kv_bf = (bf16_t*)(ws + 32 * 1024 + 16 * MB);       // 16 MB
    bf16_t* qh    = (bf16_t*)(ws + 32 * 1024 + 32 * MB);       // 8 MB
    bf16_t* kh    = (bf16_t*)(ws + 32 * 1024 + 40 * MB);       // 16 MB
    bf16_t* vt    = (bf16_t*)(ws + 32 * 1024 + 56 * MB);       // 16 MB -> end 72 MB
    bf16_t* aout  = q_bf;    // q_bf dead after q-GEMM

    bf16_t* wq_bf = w_bf;
    bf16_t* wk_bf = w_bf + (size_t)HIDDEN * HIDDEN;
    bf16_t* wv_bf = w_bf + (size_t)2 * HIDDEN * HIDDEN;
    bf16_t* wo_bf = w_bf + (size_t)3 * HIDDEN * HIDDEN;

    mask_prep_kernel<<<dim3(16), 256, 0, stream>>>(msk, maskadd);
    cvt_all_kernel<<<dim3((NQ4 + NKV4 + 4 * NW4) / 256), 256, 0, stream>>>(
        q, kv, Wq, Wk, Wv, Wo, q_bf, kv_bf, w_bf);

    gemm_bt_kernel<0, 64><<<dim3(16, 32), 256, 0, stream>>>(q_bf, wq_bf, bq, qh, 10);
    gemm_kv_fused<<<dim3(16, 64), 256, 0, stream>>>(kv_bf, wk_bf, wv_bf, bk, bv, kh, vt);

    attn_fwd_kernel<<<dim3(512), 256, 0, stream>>>(qh, kh, vt, maskadd, aout);

    gemm_bt_kernel<1, 64><<<dim3(16, 32), 256, 0, stream>>>(aout, wo_bf, bo, d_out, 10);
}

// Round 7
// 155.743 us; speedup vs baseline: 1.3403x; 1.0722x over previous
//
#include <hip/hip_runtime.h>
#include <hip/hip_bf16.h>
#include <stdint.h>
#include <math.h>

#define HIDDEN 1024
#define NHEADS 16
#define HDIM   64
#define BSZ    4
#define QLEN   1024
#define KVLEN  2048

typedef __bf16 bf16_t;
typedef __bf16 bf16x8 __attribute__((ext_vector_type(8)));
typedef __bf16 bf16x4 __attribute__((ext_vector_type(4)));
typedef float  f32x4  __attribute__((ext_vector_type(4)));

// fixed-max softmax: p = exp2( s_raw*C_SCALE + madd ).
#define C_SCALE 0.18033688f     /* 0.125 * log2(e) */
#define C_FMADD (-43.2808512f)  /* -30 * log2(e) */

#define GLOAD16(g, l) \
    __builtin_amdgcn_global_load_lds((const __attribute__((address_space(1))) void*)(g), \
                                     (__attribute__((address_space(3))) void*)(l), 16, 0, 0)

__device__ __forceinline__ float clamp50(float v) {
    return fminf(fmaxf(v, -50.f), 50.f);
}

// ---------------------------------------------------------------------------
// One launch converts q, kv, 4 weights (fp32 -> bf16, clamp50) AND the mask
// (dtype auto-detect -> additive exp2-domain constant). Mask = 4 tail blocks.
// ---------------------------------------------------------------------------
#define NQ4  ((BSZ * QLEN  * HIDDEN) / 4)   /* 1048576 */
#define NKV4 ((BSZ * KVLEN * HIDDEN) / 4)   /* 2097152 */
#define NW4  ((HIDDEN * HIDDEN) / 4)        /* 262144  */
#define NCVT ((NQ4 + NKV4 + 4 * NW4) / 256) /* 16384 blocks */

__global__ void cvt_all_kernel(const float* __restrict__ q, const float* __restrict__ kv,
                               const float* __restrict__ W0, const float* __restrict__ W1,
                               const float* __restrict__ W2, const float* __restrict__ W3,
                               bf16_t* __restrict__ q_bf, bf16_t* __restrict__ kv_bf,
                               bf16_t* __restrict__ w_bf,
                               const void* __restrict__ msk, float* __restrict__ maskadd) {
    if (blockIdx.x >= NCVT) {
        // ---- mask conversion: 4 blocks x 2048 entries, redundant detection
        __shared__ int s_float, s_multi;
        const int t = threadIdx.x;
        if (t == 0) { s_float = 0; s_multi = 0; }
        __syncthreads();
        const uint32_t* w = (const uint32_t*)msk;
        int cf = 0, cm = 0;
        for (int i = t; i < 2048; i += 256) {
            uint32_t v = w[i];
            if (v == 0x3F800000u) cf++;
            else if (v & 0xFFFFFF00u) cm++;
        }
        if (cf) atomicAdd(&s_float, cf);
        if (cm) atomicAdd(&s_multi, cm);
        __syncthreads();
        const int mode = (s_float > 0) ? 2 : ((s_multi > 0) ? 0 : 1);
        const int base = (blockIdx.x - NCVT) * 2048;
        for (int i = base + t; i < base + 2048; i += 256) {
            bool m;
            if (mode == 2)      m = ((const float*)msk)[i] != 0.0f;
            else if (mode == 1) m = ((const int*)msk)[i] != 0;
            else                m = ((const unsigned char*)msk)[i] != 0;
            maskadd[i] = m ? (-100000.0f + C_FMADD) : C_FMADD;
        }
        return;
    }
    const int i = blockIdx.x * blockDim.x + threadIdx.x;
    const float4* src;
    bf16x4* dst;
    if (i < NQ4) {
        src = (const float4*)q + i;            dst = (bf16x4*)q_bf + i;
    } else if (i < NQ4 + NKV4) {
        const int j = i - NQ4;
        src = (const float4*)kv + j;           dst = (bf16x4*)kv_bf + j;
    } else {
        const int j = i - (NQ4 + NKV4);
        const int ws = j >> 18, off = j & (NW4 - 1);
        const float* W = (ws == 0) ? W0 : (ws == 1) ? W1 : (ws == 2) ? W2 : W3;
        src = (const float4*)W + off;          dst = (bf16x4*)w_bf + (size_t)ws * NW4 + off;
    }
    const float4 v = *src;
    bf16x4 o;
    o[0] = (bf16_t)clamp50(v.x); o[1] = (bf16_t)clamp50(v.y);
    o[2] = (bf16_t)clamp50(v.z); o[3] = (bf16_t)clamp50(v.w);
    *dst = o;
}

// ---------------------------------------------------------------------------
// Shared GEMM core: 128xNT tile, BK=64, 4 waves (2x2), glds staging with
// source-side swizzle so LDS[row][c] = G[row][c^(row&7)]. K = 1024.
// ---------------------------------------------------------------------------
template <int NT>
__device__ __forceinline__ void gemm_core(const char* __restrict__ Ab, const char* __restrict__ Bb,
                                          bf16_t* Als, bf16_t* Bls,
                                          f32x4 (&acc)[4][NT / 32],
                                          int wave, int lane, int wm, int wn)
{
    constexpr int NF = NT / 32;
    const int srcsw = ((lane & 7) ^ (lane >> 3)) << 4;
    const int rowl = lane >> 3;

    for (int kt = 0; kt < HIDDEN / 64; ++kt) {
#pragma unroll
        for (int i = 0; i < 4; ++i) {
            const int row = i * 32 + wave * 8 + rowl;
            GLOAD16(Ab + (size_t)row * (HIDDEN * 2) + kt * 128 + srcsw,
                    (char*)Als + i * 4096 + wave * 1024);
        }
#pragma unroll
        for (int i = 0; i < NF; ++i) {
            const int row = i * 32 + wave * 8 + rowl;
            GLOAD16(Bb + (size_t)row * (HIDDEN * 2) + kt * 128 + srcsw,
                    (char*)Bls + i * 4096 + wave * 1024);
        }
        __syncthreads();
#pragma unroll
        for (int kc = 0; kc < 2; ++kc) {
            const int kbyte = kc * 64 + ((lane >> 4) << 4);
            bf16x8 af[4], bfr[NF];
#pragma unroll
            for (int f2 = 0; f2 < 4; ++f2) {
                const int arow = wm * 64 + f2 * 16 + (lane & 15);
                af[f2] = *(const bf16x8*)((const char*)Als + arow * 128 + (kbyte ^ ((arow & 7) << 4)));
            }
#pragma unroll
            for (int f2 = 0; f2 < NF; ++f2) {
                const int brow = wn * (NT / 2) + f2 * 16 + (lane & 15);
                bfr[f2] = *(const bf16x8*)((const char*)Bls + brow * 128 + (kbyte ^ ((brow & 7) << 4)));
            }
#pragma unroll
            for (int mf = 0; mf < 4; ++mf)
#pragma unroll
                for (int nf = 0; nf < NF; ++nf)
                    acc[mf][nf] = __builtin_amdgcn_mfma_f32_16x16x32_bf16(af[mf], bfr[nf], acc[mf][nf], 0, 0, 0);
        }
        __syncthreads();
    }
}

// EPI 0 epilogue: bf16 out in per-head layout [(b*16+h)][s][d], seqlen 1<<slog
template <int NF>
__device__ __forceinline__ void epi_head(f32x4 (&acc)[4][NF], const float* bias,
                                         bf16_t* out, int m0, int n0, int slog,
                                         int wm, int wn, int lane)
{
#pragma unroll
    for (int mf = 0; mf < 4; ++mf) {
#pragma unroll
        for (int nf = 0; nf < NF; ++nf) {
            const int gn = n0 + wn * (NF * 16) + nf * 16 + (lane & 15);
            const float bv = bias[gn];
#pragma unroll
            for (int r = 0; r < 4; ++r) {
                const int gm = m0 + wm * 64 + mf * 16 + ((lane >> 4) << 2) + r;
                const float v = clamp50(acc[mf][nf][r] + bv);
                const int b = gm >> slog;
                const int s = gm & ((1 << slog) - 1);
                const int h = gn >> 6, d = gn & 63;
                out[((((size_t)(b * NHEADS + h)) << slog) + s) * HDIM + d] = (bf16_t)v;
            }
        }
    }
}

// ---------------------------------------------------------------------------
// Generic GEMM kernel. EPI 0: bf16 per-head. EPI 1: fp32 [M][1024].
// ---------------------------------------------------------------------------
template <int EPI, int NT>
__global__ __launch_bounds__(256)
void gemm_bt_kernel(const bf16_t* __restrict__ A, const bf16_t* __restrict__ B,
                    const float* __restrict__ bias, void* __restrict__ out, int slog)
{
    constexpr int NF = NT / 32;
    __shared__ __align__(16) bf16_t Smem[(128 + NT) * 64];
    bf16_t* Als = Smem;
    bf16_t* Bls = Smem + 128 * 64;

    const int m0 = blockIdx.y * 128;
    const int n0 = blockIdx.x * NT;
    const int t = threadIdx.x;
    const int wave = t >> 6, lane = t & 63;
    const int wm = wave >> 1, wn = wave & 1;

    f32x4 acc[4][NF] = {};
    gemm_core<NT>((const char*)A + (size_t)m0 * (HIDDEN * 2),
                  (const char*)B + (size_t)n0 * (HIDDEN * 2),
                  Als, Bls, acc, wave, lane, wm, wn);

    if (EPI == 0) {
        epi_head<NF>(acc, bias, (bf16_t*)out, m0, n0, slog, wm, wn, lane);
    } else {
#pragma unroll
        for (int mf = 0; mf < 4; ++mf) {
#pragma unroll
            for (int nf = 0; nf < NF; ++nf) {
                const int gn = n0 + wn * (NF * 16) + nf * 16 + (lane & 15);
                const float bv = bias[gn];
#pragma unroll
                for (int r = 0; r < 4; ++r) {
                    const int gm = m0 + wm * 64 + mf * 16 + ((lane >> 4) << 2) + r;
                    ((float*)out)[(size_t)gm * HIDDEN + gn] = clamp50(acc[mf][nf][r] + bv);
                }
            }
        }
    }
}

// ---------------------------------------------------------------------------
// Fused K/V projection GEMM. Grid (16, 64): bx<8 -> Wk -> kh (per-head),
// bx>=8 -> Wv -> vt (per-head TRANSPOSED [bh][d][s], s = KVLEN).
// ---------------------------------------------------------------------------
__global__ __launch_bounds__(256)
void gemm_kv_fused(const bf16_t* __restrict__ A, const bf16_t* __restrict__ Bk,
                   const bf16_t* __restrict__ Bv, const float* __restrict__ bk,
                   const float* __restrict__ bv, bf16_t* __restrict__ kh,
                   bf16_t* __restrict__ vt)
{
    __shared__ __align__(16) bf16_t Smem[2 * 128 * 64];
    bf16_t* Als = Smem;
    bf16_t* Bls = Smem + 128 * 64;

    const int isV = blockIdx.x >> 3;
    const int n0 = (blockIdx.x & 7) * 128;
    const int m0 = blockIdx.y * 128;
    const int t = threadIdx.x;
    const int wave = t >> 6, lane = t & 63;
    const int wm = wave >> 1, wn = wave & 1;
    const bf16_t* B = isV ? Bv : Bk;
    const float* bias = isV ? bv : bk;

    f32x4 acc[4][4] = {};
    gemm_core<128>((const char*)A + (size_t)m0 * (HIDDEN * 2),
                   (const char*)B + (size_t)n0 * (HIDDEN * 2),
                   Als, Bls, acc, wave, lane, wm, wn);

    if (!isV) {
        epi_head<4>(acc, bias, kh, m0, n0, 11, wm, wn, lane);
        return;
    }

    // transpose epilogue via LDS (reuse Smem), 2 phases of 64 s-rows.
    bf16_t* Cls = Smem;                  // [64][130]
    const int dl = t >> 1;               // 0..127
    const int sh = (t & 1) << 5;         // 0 or 32
    const int gn = n0 + dl;
    const int h = gn >> 6, d = gn & 63;
    const int bb = m0 >> 11;
    bf16_t* dst = vt + ((size_t)((bb * NHEADS + h) * HDIM + d)) * KVLEN
                + (m0 & (KVLEN - 1)) + sh;
#pragma unroll
    for (int ph = 0; ph < 2; ++ph) {
        if (wm == ph) {
#pragma unroll
            for (int mf = 0; mf < 4; ++mf) {
#pragma unroll
                for (int nf = 0; nf < 4; ++nf) {
                    const int dcol = wn * 64 + nf * 16 + (lane & 15);
                    const float bv2 = bias[n0 + dcol];
#pragma unroll
                    for (int r = 0; r < 4; ++r) {
                        const int srow = mf * 16 + ((lane >> 4) << 2) + r;
                        Cls[srow * 130 + dcol] = (bf16_t)clamp50(acc[mf][nf][r] + bv2);
                    }
                }
            }
        }
        __syncthreads();
#pragma unroll
        for (int j0 = 0; j0 < 32; j0 += 8) {
            bf16x8 v;
#pragma unroll
            for (int j = 0; j < 8; ++j) v[j] = Cls[(sh + j0 + j) * 130 + dl];
            *(bf16x8*)(dst + ph * 64 + j0) = v;
        }
        __syncthreads();
    }
}

// ---------------------------------------------------------------------------
// Flash attention v3: fixed-max softmax, swapped QK^T (P in registers),
// KEY-HALF SPLIT across wave pairs. 8 waves / 512 threads per block.
// Waves wq=0..3 x wg=0..1: wave owns q-rows [qbase+32*wq, +32) and global
// keys [32*wg, 32*wg+32) of each 64-key tile. Partial (O,l) are ADDITIVE
// (fixed max) -> combined once at the end via LDS. Grid 512, XCD-grouped.
//
// K LDS row i holds global key kap(i) = 32*(i>>5) + 8*((i>>2)&3)
//   + 4*((i>>4)&1) + (i&3)  [R6-verified mapping]: lane (g,ql) of wave wg
//   then holds P[q=ql][keys 32*wg + 8g..8g+7] = exactly its PV A-fragment.
// ---------------------------------------------------------------------------
__global__ __launch_bounds__(512)
void attn_fwd_kernel(const bf16_t* __restrict__ Qh, const bf16_t* __restrict__ Kh,
                     const bf16_t* __restrict__ Vt, const float* __restrict__ maskadd,
                     bf16_t* __restrict__ aout)
{
    __shared__ __align__(16) bf16_t Kls[2][64 * 64];   // 16 KB
    __shared__ __align__(16) bf16_t Vls[2][64 * 64];   // 16 KB
    __shared__ __align__(16) float Cbuf[4][32 * 64];   // 32 KB combine
    __shared__ float Lbuf[4][2][16];

    // XCD-grouped swizzle (512 = 8 XCDs x 64): xcd c -> bh in [8c, 8c+8)
    const int f = blockIdx.x;
    const int o = (f & 7) * 64 + (f >> 3);
    const int qt = o & 7;          // 8 q-tiles of 128
    const int bh = o >> 3;
    const int b = bh >> 4, h = bh & 15;
    const int t = threadIdx.x, wave = t >> 6, lane = t & 63;
    const int wq = wave & 3;       // q-row group
    const int wg = wave >> 2;      // key-half group
    const int g = lane >> 4, ql = lane & 15;

    const int qbase = qt * 128 + wq * 32;
    bf16x8 qf[2][2];
#pragma unroll
    for (int qq = 0; qq < 2; ++qq) {
        const bf16_t* qp = Qh + ((size_t)bh * QLEN + qbase + qq * 16 + ql) * HDIM + (g << 3);
        qf[qq][0] = *(const bf16x8*)qp;
        qf[qq][1] = *(const bf16x8*)(qp + 32);
    }

    f32x4 oacc[2][4] = {};
    float lsum[2] = {0.f, 0.f};

    const int srcsw = ((lane & 7) ^ (lane >> 3)) << 4;
    const int R = wave * 8 + (lane >> 3);    // LDS row this lane stages (0..63)
    const int kap = 32 * (R >> 5) + 8 * ((R >> 2) & 3) + 4 * ((R >> 4) & 1) + (R & 3);

    const char* Kb = (const char*)(Kh + (size_t)bh * KVLEN * HDIM);
    const char* Vb = (const char*)(Vt + (size_t)bh * HDIM * KVLEN);
    const float* mrow = maskadd + b * KVLEN + wg * 32 + g * 8;  // this wave's 8-key base
    const int kb0 = g << 4;
    const int vcol = wg * 64 + kb0;          // V^T byte col for this wave's key half

    // prologue: stage tile 0 (one glds instr each for K and V), preload mask
    GLOAD16(Kb + (size_t)kap * 128 + srcsw, (char*)&Kls[0][0] + wave * 1024);
    GLOAD16(Vb + (size_t)R * (KVLEN * 2) + srcsw, (char*)&Vls[0][0] + wave * 1024);
    f32x4 madd_c[2], madd_n[2];
    madd_c[0] = *(const f32x4*)(mrow);
    madd_c[1] = *(const f32x4*)(mrow + 4);
    __syncthreads();

    for (int kt = 0; kt < KVLEN / 64; ++kt) {
        const int cur = kt & 1;
        if (kt < KVLEN / 64 - 1) {
            const size_t ko = (size_t)(kt + 1) * 8192;
            GLOAD16(Kb + ko + (size_t)kap * 128 + srcsw,
                    (char*)&Kls[cur ^ 1][0] + wave * 1024);
            GLOAD16(Vb + (size_t)R * (KVLEN * 2) + (size_t)(kt + 1) * 128 + srcsw,
                    (char*)&Vls[cur ^ 1][0] + wave * 1024);
            madd_n[0] = *(const f32x4*)(mrow + (kt + 1) * 64);
            madd_n[1] = *(const f32x4*)(mrow + (kt + 1) * 64 + 4);
        }
        const char* Kc = (const char*)&Kls[cur][0];
        const char* Vc = (const char*)&Vls[cur][0];

        // ---- S^T = K Q^T over this wave's 32-key half (2 key-blocks)
        f32x4 sacc[2][2] = {};
#pragma unroll
        for (int kb = 0; kb < 2; ++kb) {
            const int key = wg * 32 + kb * 16 + ql;
            const int rowoff = key * 128;
            const int sw = (key & 7) << 4;
            const bf16x8 kf0 = *(const bf16x8*)(Kc + rowoff + ((kb0)      ^ sw));
            const bf16x8 kf1 = *(const bf16x8*)(Kc + rowoff + ((kb0 + 64) ^ sw));
#pragma unroll
            for (int qq = 0; qq < 2; ++qq) {
                sacc[qq][kb] = __builtin_amdgcn_mfma_f32_16x16x32_bf16(kf0, qf[qq][0], sacc[qq][kb], 0, 0, 0);
                sacc[qq][kb] = __builtin_amdgcn_mfma_f32_16x16x32_bf16(kf1, qf[qq][1], sacc[qq][kb], 0, 0, 0);
            }
        }

        // ---- softmax weights in-register + pack to PV A-fragment
        bf16x8 pa[2];
#pragma unroll
        for (int qq = 0; qq < 2; ++qq) {
            float pv[2][4];
            float ls = 0.f;
#pragma unroll
            for (int kb = 0; kb < 2; ++kb) {
#pragma unroll
                for (int r = 0; r < 4; ++r) {
                    pv[kb][r] = __builtin_amdgcn_exp2f(
                        __builtin_fmaf(sacc[qq][kb][r], C_SCALE, madd_c[kb][r]));
                    ls += pv[kb][r];
                }
            }
            lsum[qq] += ls;
#pragma unroll
            for (int r = 0; r < 4; ++r) {
                pa[qq][r]     = (bf16_t)pv[0][r];
                pa[qq][4 + r] = (bf16_t)pv[1][r];
            }
        }

        // ---- O += P V over this key half
#pragma unroll
        for (int db = 0; db < 4; ++db) {
            const int vrow = db * 16 + ql;
            const int vsw = (vrow & 7) << 4;
            const bf16x8 vf = *(const bf16x8*)(Vc + vrow * 128 + (vcol ^ vsw));
#pragma unroll
            for (int qq = 0; qq < 2; ++qq)
                oacc[qq][db] = __builtin_amdgcn_mfma_f32_16x16x32_bf16(pa[qq], vf, oacc[qq][db], 0, 0, 0);
        }

        __syncthreads();   // drains glds -> next buffer ready
#pragma unroll
        for (int kb = 0; kb < 2; ++kb) madd_c[kb] = madd_n[kb];
    }

    // ---- combine key-halves: wg=1 publishes partials, wg=0 merges+stores
#pragma unroll
    for (int qq = 0; qq < 2; ++qq) {
        float l = lsum[qq];
        l += __shfl_xor(l, 16);
        l += __shfl_xor(l, 32);
        lsum[qq] = l;       // every lane holds this half's L(q = ql)
    }
    const int rbase = g << 2;
    if (wg == 1) {
#pragma unroll
        for (int qq = 0; qq < 2; ++qq) {
#pragma unroll
            for (int db = 0; db < 4; ++db)
#pragma unroll
                for (int r = 0; r < 4; ++r)
                    Cbuf[wq][(qq * 16 + rbase + r) * 64 + db * 16 + ql] = oacc[qq][db][r];
            if (lane < 16) Lbuf[wq][qq][lane] = lsum[qq];
        }
    }
    __syncthreads();
    if (wg == 0) {
#pragma unroll
        for (int qq = 0; qq < 2; ++qq) {
            const float Lq = lsum[qq] + Lbuf[wq][qq][ql];   // total L(q = ql)
#pragma unroll
            for (int r = 0; r < 4; ++r) {
                const float Lr = __shfl(Lq, rbase + r);
                const float inv = 1.0f / Lr;
                const int qrow = qbase + qq * 16 + rbase + r;
                bf16_t* orow = aout + ((size_t)(b * QLEN + qrow)) * HIDDEN + h * HDIM;
#pragma unroll
                for (int db = 0; db < 4; ++db) {
                    const float add = Cbuf[wq][(qq * 16 + rbase + r) * 64 + db * 16 + ql];
                    orow[db * 16 + ql] = (bf16_t)((oacc[qq][db][r] + add) * inv);
                }
            }
        }
    }
}

// ---------------------------------------------------------------------------
extern "C" void kernel_launch(void* const* d_in, const int* in_sizes, int n_in,
                              void* d_out, int out_size, void* d_ws, size_t ws_size,
                              hipStream_t stream) {
    (void)in_sizes; (void)n_in; (void)out_size; (void)ws_size;
    const float* q   = (const float*)d_in[0];
    const float* kv  = (const float*)d_in[1];
    const void*  msk = d_in[2];
    const float* Wq  = (const float*)d_in[3];
    const float* bq  = (const float*)d_in[4];
    const float* Wk  = (const float*)d_in[5];
    const float* bk  = (const float*)d_in[6];
    const float* Wv  = (const float*)d_in[7];
    const float* bv  = (const float*)d_in[8];
    const float* Wo  = (const float*)d_in[9];
    const float* bo  = (const float*)d_in[10];

    char* ws = (char*)d_ws;
    const size_t MB = 1024 * 1024;
    float*  maskadd = (float*)ws;                              // 32 KB
    bf16_t* w_bf  = (bf16_t*)(ws + 32 * 1024);                 // 8 MB (4 weights)
    bf16_t* q_bf  = (bf16_t*)(ws + 32 * 1024 + 8  * MB);       // 8 MB (reused as aout)
    bf16_t* kv_bf = (bf16_t*)(ws + 32 * 1024 + 16 * MB);       // 16 MB
    bf16_t* qh    = (bf16_t*)(ws + 32 * 1024 + 32 * MB);       // 8 MB
    bf16_t* kh    = (bf16_t*)(ws + 32 * 1024 + 40 * MB);       // 16 MB
    bf16_t* vt    = (bf16_t*)(ws + 32 * 1024 + 56 * MB);       // 16 MB -> end 72 MB
    bf16_t* aout  = q_bf;    // q_bf dead after q-GEMM

    bf16_t* wq_bf = w_bf;
    bf16_t* wk_bf = w_bf + (size_t)HIDDEN * HIDDEN;
    bf16_t* wv_bf = w_bf + (size_t)2 * HIDDEN * HIDDEN;
    bf16_t* wo_bf = w_bf + (size_t)3 * HIDDEN * HIDDEN;

    cvt_all_kernel<<<dim3(NCVT + 4), 256, 0, stream>>>(
        q, kv, Wq, Wk, Wv, Wo, q_bf, kv_bf, w_bf, msk, maskadd);

    gemm_bt_kernel<0, 64><<<dim3(16, 32), 256, 0, stream>>>(q_bf, wq_bf, bq, qh, 10);
    gemm_kv_fused<<<dim3(16, 64), 256, 0, stream>>>(kv_bf, wk_bf, wv_bf, bk, bv, kh, vt);

    attn_fwd_kernel<<<dim3(512), 512, 0, stream>>>(qh, kh, vt, maskadd, aout);

    gemm_bt_kernel<1, 64><<<dim3(16, 32), 256, 0, stream>>>(aout, wo_bf, bo, d_out, 10);
}

// Round 8
// 153.900 us; speedup vs baseline: 1.3563x; 1.0120x over previous
//
#include <hip/hip_runtime.h>
#include <hip/hip_bf16.h>
#include <stdint.h>
#include <math.h>

#define HIDDEN 1024
#define NHEADS 16
#define HDIM   64
#define BSZ    4
#define QLEN   1024
#define KVLEN  2048

typedef __bf16 bf16_t;
typedef __bf16 bf16x8 __attribute__((ext_vector_type(8)));
typedef __bf16 bf16x4 __attribute__((ext_vector_type(4)));
typedef float  f32x4  __attribute__((ext_vector_type(4)));

// fixed-max softmax: p = exp2( s_raw*C_SCALE + madd ).
#define C_SCALE 0.18033688f     /* 0.125 * log2(e) */
#define C_FMADD (-43.2808512f)  /* -30 * log2(e) */

#define GLOAD16(g, l) \
    __builtin_amdgcn_global_load_lds((const __attribute__((address_space(1))) void*)(g), \
                                     (__attribute__((address_space(3))) void*)(l), 16, 0, 0)

__device__ __forceinline__ float clamp50(float v) {
    return fminf(fmaxf(v, -50.f), 50.f);
}

// ---------------------------------------------------------------------------
// One launch converts q, kv, 4 weights (fp32 -> bf16, clamp50) AND the mask
// (dtype auto-detect -> additive exp2-domain constant). Mask = 4 tail blocks.
// ---------------------------------------------------------------------------
#define NQ4  ((BSZ * QLEN  * HIDDEN) / 4)   /* 1048576 */
#define NKV4 ((BSZ * KVLEN * HIDDEN) / 4)   /* 2097152 */
#define NW4  ((HIDDEN * HIDDEN) / 4)        /* 262144  */
#define NCVT ((NQ4 + NKV4 + 4 * NW4) / 256) /* 16384 blocks */

__global__ void cvt_all_kernel(const float* __restrict__ q, const float* __restrict__ kv,
                               const float* __restrict__ W0, const float* __restrict__ W1,
                               const float* __restrict__ W2, const float* __restrict__ W3,
                               bf16_t* __restrict__ q_bf, bf16_t* __restrict__ kv_bf,
                               bf16_t* __restrict__ w_bf,
                               const void* __restrict__ msk, float* __restrict__ maskadd) {
    if (blockIdx.x >= NCVT) {
        __shared__ int s_float, s_multi;
        const int t = threadIdx.x;
        if (t == 0) { s_float = 0; s_multi = 0; }
        __syncthreads();
        const uint32_t* w = (const uint32_t*)msk;
        int cf = 0, cm = 0;
        for (int i = t; i < 2048; i += 256) {
            uint32_t v = w[i];
            if (v == 0x3F800000u) cf++;
            else if (v & 0xFFFFFF00u) cm++;
        }
        if (cf) atomicAdd(&s_float, cf);
        if (cm) atomicAdd(&s_multi, cm);
        __syncthreads();
        const int mode = (s_float > 0) ? 2 : ((s_multi > 0) ? 0 : 1);
        const int base = (blockIdx.x - NCVT) * 2048;
        for (int i = base + t; i < base + 2048; i += 256) {
            bool m;
            if (mode == 2)      m = ((const float*)msk)[i] != 0.0f;
            else if (mode == 1) m = ((const int*)msk)[i] != 0;
            else                m = ((const unsigned char*)msk)[i] != 0;
            maskadd[i] = m ? (-100000.0f + C_FMADD) : C_FMADD;
        }
        return;
    }
    const int i = blockIdx.x * blockDim.x + threadIdx.x;
    const float4* src;
    bf16x4* dst;
    if (i < NQ4) {
        src = (const float4*)q + i;            dst = (bf16x4*)q_bf + i;
    } else if (i < NQ4 + NKV4) {
        const int j = i - NQ4;
        src = (const float4*)kv + j;           dst = (bf16x4*)kv_bf + j;
    } else {
        const int j = i - (NQ4 + NKV4);
        const int ws = j >> 18, off = j & (NW4 - 1);
        const float* W = (ws == 0) ? W0 : (ws == 1) ? W1 : (ws == 2) ? W2 : W3;
        src = (const float4*)W + off;          dst = (bf16x4*)w_bf + (size_t)ws * NW4 + off;
    }
    const float4 v = *src;
    bf16x4 o;
    o[0] = (bf16_t)clamp50(v.x); o[1] = (bf16_t)clamp50(v.y);
    o[2] = (bf16_t)clamp50(v.z); o[3] = (bf16_t)clamp50(v.w);
    *dst = o;
}

// ---------------------------------------------------------------------------
// Shared GEMM core: 128xNT tile, BK=64, 4 waves (2x2), glds staging with
// source-side swizzle so LDS[row][c] = G[row][c^(row&7)]. K = 1024.
// ---------------------------------------------------------------------------
template <int NT>
__device__ __forceinline__ void gemm_core(const char* __restrict__ Ab, const char* __restrict__ Bb,
                                          bf16_t* Als, bf16_t* Bls,
                                          f32x4 (&acc)[4][NT / 32],
                                          int wave, int lane, int wm, int wn)
{
    constexpr int NF = NT / 32;
    const int srcsw = ((lane & 7) ^ (lane >> 3)) << 4;
    const int rowl = lane >> 3;

    for (int kt = 0; kt < HIDDEN / 64; ++kt) {
#pragma unroll
        for (int i = 0; i < 4; ++i) {
            const int row = i * 32 + wave * 8 + rowl;
            GLOAD16(Ab + (size_t)row * (HIDDEN * 2) + kt * 128 + srcsw,
                    (char*)Als + i * 4096 + wave * 1024);
        }
#pragma unroll
        for (int i = 0; i < NF; ++i) {
            const int row = i * 32 + wave * 8 + rowl;
            GLOAD16(Bb + (size_t)row * (HIDDEN * 2) + kt * 128 + srcsw,
                    (char*)Bls + i * 4096 + wave * 1024);
        }
        __syncthreads();
#pragma unroll
        for (int kc = 0; kc < 2; ++kc) {
            const int kbyte = kc * 64 + ((lane >> 4) << 4);
            bf16x8 af[4], bfr[NF];
#pragma unroll
            for (int f2 = 0; f2 < 4; ++f2) {
                const int arow = wm * 64 + f2 * 16 + (lane & 15);
                af[f2] = *(const bf16x8*)((const char*)Als + arow * 128 + (kbyte ^ ((arow & 7) << 4)));
            }
#pragma unroll
            for (int f2 = 0; f2 < NF; ++f2) {
                const int brow = wn * (NT / 2) + f2 * 16 + (lane & 15);
                bfr[f2] = *(const bf16x8*)((const char*)Bls + brow * 128 + (kbyte ^ ((brow & 7) << 4)));
            }
#pragma unroll
            for (int mf = 0; mf < 4; ++mf)
#pragma unroll
                for (int nf = 0; nf < NF; ++nf)
                    acc[mf][nf] = __builtin_amdgcn_mfma_f32_16x16x32_bf16(af[mf], bfr[nf], acc[mf][nf], 0, 0, 0);
        }
        __syncthreads();
    }
}

// EPI 0 epilogue: bf16 out in per-head layout [(b*16+h)][s][d], seqlen 1<<slog
template <int NF>
__device__ __forceinline__ void epi_head(f32x4 (&acc)[4][NF], const float* bias,
                                         bf16_t* out, int m0, int n0, int slog,
                                         int wm, int wn, int lane)
{
#pragma unroll
    for (int mf = 0; mf < 4; ++mf) {
#pragma unroll
        for (int nf = 0; nf < NF; ++nf) {
            const int gn = n0 + wn * (NF * 16) + nf * 16 + (lane & 15);
            const float bv = bias[gn];
#pragma unroll
            for (int r = 0; r < 4; ++r) {
                const int gm = m0 + wm * 64 + mf * 16 + ((lane >> 4) << 2) + r;
                const float v = clamp50(acc[mf][nf][r] + bv);
                const int b = gm >> slog;
                const int s = gm & ((1 << slog) - 1);
                const int h = gn >> 6, d = gn & 63;
                out[((((size_t)(b * NHEADS + h)) << slog) + s) * HDIM + d] = (bf16_t)v;
            }
        }
    }
}

// ---------------------------------------------------------------------------
// MERGED projection GEMM: q, K, V in one launch. Grid 1280 (1D):
//   lid <  256 : q-proj  (m-panel lid>>3 of 32,  n (lid&7)) -> qh  (slog 10)
//   lid <  768 : K-proj  (m-panel (lid-256)>>3 of 64)       -> kh  (slog 11)
//   else       : V-proj  (m-panel (lid-768)>>3 of 64)       -> vt  (transposed)
// Bijective XCD swizzle lid = (bid&7)*160 + (bid>>3): the 8 consecutive lids
// sharing an A m-panel run on ONE XCD -> panel stays L2-resident.
// ---------------------------------------------------------------------------
__global__ __launch_bounds__(256)
void gemm_proj_all(const bf16_t* __restrict__ q_bf, const bf16_t* __restrict__ kv_bf,
                   const bf16_t* __restrict__ w_bf,
                   const float* __restrict__ bq, const float* __restrict__ bk,
                   const float* __restrict__ bv,
                   bf16_t* __restrict__ qh, bf16_t* __restrict__ kh,
                   bf16_t* __restrict__ vt)
{
    __shared__ __align__(16) bf16_t Smem[2 * 128 * 64];
    bf16_t* Als = Smem;
    bf16_t* Bls = Smem + 128 * 64;

    const int bid = blockIdx.x;
    const int lid = (bid & 7) * 160 + (bid >> 3);

    int seg, j;
    if (lid < 256)      { seg = 0; j = lid; }
    else if (lid < 768) { seg = 1; j = lid - 256; }
    else                { seg = 2; j = lid - 768; }
    const int m0 = (j >> 3) * 128;
    const int n0 = (j & 7) * 128;
    const bf16_t* A    = (seg == 0) ? q_bf : kv_bf;
    const bf16_t* B    = w_bf + (size_t)seg * (HIDDEN * HIDDEN);   // Wq, Wk, Wv
    const float*  bias = (seg == 0) ? bq : (seg == 1) ? bk : bv;

    const int t = threadIdx.x;
    const int wave = t >> 6, lane = t & 63;
    const int wm = wave >> 1, wn = wave & 1;

    f32x4 acc[4][4] = {};
    gemm_core<128>((const char*)A + (size_t)m0 * (HIDDEN * 2),
                   (const char*)B + (size_t)n0 * (HIDDEN * 2),
                   Als, Bls, acc, wave, lane, wm, wn);

    if (seg == 0) {
        epi_head<4>(acc, bias, qh, m0, n0, 10, wm, wn, lane);
        return;
    }
    if (seg == 1) {
        epi_head<4>(acc, bias, kh, m0, n0, 11, wm, wn, lane);
        return;
    }

    // V: transpose epilogue via LDS (reuse Smem), 2 phases of 64 s-rows.
    bf16_t* Cls = Smem;                  // [64][130]
    const int dl = t >> 1;               // 0..127
    const int sh = (t & 1) << 5;         // 0 or 32
    const int gn = n0 + dl;
    const int h = gn >> 6, d = gn & 63;
    const int bb = m0 >> 11;
    bf16_t* dst = vt + ((size_t)((bb * NHEADS + h) * HDIM + d)) * KVLEN
                + (m0 & (KVLEN - 1)) + sh;
#pragma unroll
    for (int ph = 0; ph < 2; ++ph) {
        if (wm == ph) {
#pragma unroll
            for (int mf = 0; mf < 4; ++mf) {
#pragma unroll
                for (int nf = 0; nf < 4; ++nf) {
                    const int dcol = wn * 64 + nf * 16 + (lane & 15);
                    const float bv2 = bias[n0 + dcol];
#pragma unroll
                    for (int r = 0; r < 4; ++r) {
                        const int srow = mf * 16 + ((lane >> 4) << 2) + r;
                        Cls[srow * 130 + dcol] = (bf16_t)clamp50(acc[mf][nf][r] + bv2);
                    }
                }
            }
        }
        __syncthreads();
#pragma unroll
        for (int j0 = 0; j0 < 32; j0 += 8) {
            bf16x8 v;
#pragma unroll
            for (int jj = 0; jj < 8; ++jj) v[jj] = Cls[(sh + j0 + jj) * 130 + dl];
            *(bf16x8*)(dst + ph * 64 + j0) = v;
        }
        __syncthreads();
    }
}

// ---------------------------------------------------------------------------
// Output-projection GEMM (fp32 out [M][1024]), 128x64 tiles for occupancy.
// ---------------------------------------------------------------------------
template <int NT>
__global__ __launch_bounds__(256)
void gemm_out_kernel(const bf16_t* __restrict__ A, const bf16_t* __restrict__ B,
                     const float* __restrict__ bias, float* __restrict__ out)
{
    constexpr int NF = NT / 32;
    __shared__ __align__(16) bf16_t Smem[(128 + NT) * 64];
    bf16_t* Als = Smem;
    bf16_t* Bls = Smem + 128 * 64;

    const int m0 = blockIdx.y * 128;
    const int n0 = blockIdx.x * NT;
    const int t = threadIdx.x;
    const int wave = t >> 6, lane = t & 63;
    const int wm = wave >> 1, wn = wave & 1;

    f32x4 acc[4][NF] = {};
    gemm_core<NT>((const char*)A + (size_t)m0 * (HIDDEN * 2),
                  (const char*)B + (size_t)n0 * (HIDDEN * 2),
                  Als, Bls, acc, wave, lane, wm, wn);

#pragma unroll
    for (int mf = 0; mf < 4; ++mf) {
#pragma unroll
        for (int nf = 0; nf < NF; ++nf) {
            const int gn = n0 + wn * (NF * 16) + nf * 16 + (lane & 15);
            const float bv = bias[gn];
#pragma unroll
            for (int r = 0; r < 4; ++r) {
                const int gm = m0 + wm * 64 + mf * 16 + ((lane >> 4) << 2) + r;
                out[(size_t)gm * HIDDEN + gn] = clamp50(acc[mf][nf][r] + bv);
            }
        }
    }
}

// ---------------------------------------------------------------------------
// Flash attention v3: fixed-max softmax, swapped QK^T (P in registers),
// key-half split across wave pairs, 8 waves / 512 threads, XCD-grouped.
// + T5 setprio around MFMA clusters.
// ---------------------------------------------------------------------------
__global__ __launch_bounds__(512)
void attn_fwd_kernel(const bf16_t* __restrict__ Qh, const bf16_t* __restrict__ Kh,
                     const bf16_t* __restrict__ Vt, const float* __restrict__ maskadd,
                     bf16_t* __restrict__ aout)
{
    __shared__ __align__(16) bf16_t Kls[2][64 * 64];   // 16 KB
    __shared__ __align__(16) bf16_t Vls[2][64 * 64];   // 16 KB
    __shared__ __align__(16) float Cbuf[4][32 * 64];   // 32 KB combine
    __shared__ float Lbuf[4][2][16];

    const int f = blockIdx.x;
    const int o = (f & 7) * 64 + (f >> 3);
    const int qt = o & 7;
    const int bh = o >> 3;
    const int b = bh >> 4, h = bh & 15;
    const int t = threadIdx.x, wave = t >> 6, lane = t & 63;
    const int wq = wave & 3;
    const int wg = wave >> 2;
    const int g = lane >> 4, ql = lane & 15;

    const int qbase = qt * 128 + wq * 32;
    bf16x8 qf[2][2];
#pragma unroll
    for (int qq = 0; qq < 2; ++qq) {
        const bf16_t* qp = Qh + ((size_t)bh * QLEN + qbase + qq * 16 + ql) * HDIM + (g << 3);
        qf[qq][0] = *(const bf16x8*)qp;
        qf[qq][1] = *(const bf16x8*)(qp + 32);
    }

    f32x4 oacc[2][4] = {};
    float lsum[2] = {0.f, 0.f};

    const int srcsw = ((lane & 7) ^ (lane >> 3)) << 4;
    const int R = wave * 8 + (lane >> 3);
    const int kap = 32 * (R >> 5) + 8 * ((R >> 2) & 3) + 4 * ((R >> 4) & 1) + (R & 3);

    const char* Kb = (const char*)(Kh + (size_t)bh * KVLEN * HDIM);
    const char* Vb = (const char*)(Vt + (size_t)bh * HDIM * KVLEN);
    const float* mrow = maskadd + b * KVLEN + wg * 32 + g * 8;
    const int kb0 = g << 4;
    const int vcol = wg * 64 + kb0;

    GLOAD16(Kb + (size_t)kap * 128 + srcsw, (char*)&Kls[0][0] + wave * 1024);
    GLOAD16(Vb + (size_t)R * (KVLEN * 2) + srcsw, (char*)&Vls[0][0] + wave * 1024);
    f32x4 madd_c[2], madd_n[2];
    madd_c[0] = *(const f32x4*)(mrow);
    madd_c[1] = *(const f32x4*)(mrow + 4);
    __syncthreads();

    for (int kt = 0; kt < KVLEN / 64; ++kt) {
        const int cur = kt & 1;
        if (kt < KVLEN / 64 - 1) {
            const size_t ko = (size_t)(kt + 1) * 8192;
            GLOAD16(Kb + ko + (size_t)kap * 128 + srcsw,
                    (char*)&Kls[cur ^ 1][0] + wave * 1024);
            GLOAD16(Vb + (size_t)R * (KVLEN * 2) + (size_t)(kt + 1) * 128 + srcsw,
                    (char*)&Vls[cur ^ 1][0] + wave * 1024);
            madd_n[0] = *(const f32x4*)(mrow + (kt + 1) * 64);
            madd_n[1] = *(const f32x4*)(mrow + (kt + 1) * 64 + 4);
        }
        const char* Kc = (const char*)&Kls[cur][0];
        const char* Vc = (const char*)&Vls[cur][0];

        // ---- S^T = K Q^T over this wave's 32-key half
        f32x4 sacc[2][2] = {};
        __builtin_amdgcn_s_setprio(1);
#pragma unroll
        for (int kb = 0; kb < 2; ++kb) {
            const int key = wg * 32 + kb * 16 + ql;
            const int rowoff = key * 128;
            const int sw = (key & 7) << 4;
            const bf16x8 kf0 = *(const bf16x8*)(Kc + rowoff + ((kb0)      ^ sw));
            const bf16x8 kf1 = *(const bf16x8*)(Kc + rowoff + ((kb0 + 64) ^ sw));
#pragma unroll
            for (int qq = 0; qq < 2; ++qq) {
                sacc[qq][kb] = __builtin_amdgcn_mfma_f32_16x16x32_bf16(kf0, qf[qq][0], sacc[qq][kb], 0, 0, 0);
                sacc[qq][kb] = __builtin_amdgcn_mfma_f32_16x16x32_bf16(kf1, qf[qq][1], sacc[qq][kb], 0, 0, 0);
            }
        }
        __builtin_amdgcn_s_setprio(0);

        // ---- softmax weights in-register + pack to PV A-fragment
        bf16x8 pa[2];
#pragma unroll
        for (int qq = 0; qq < 2; ++qq) {
            float pv[2][4];
            float ls = 0.f;
#pragma unroll
            for (int kb = 0; kb < 2; ++kb) {
#pragma unroll
                for (int r = 0; r < 4; ++r) {
                    pv[kb][r] = __builtin_amdgcn_exp2f(
                        __builtin_fmaf(sacc[qq][kb][r], C_SCALE, madd_c[kb][r]));
                    ls += pv[kb][r];
                }
            }
            lsum[qq] += ls;
#pragma unroll
            for (int r = 0; r < 4; ++r) {
                pa[qq][r]     = (bf16_t)pv[0][r];
                pa[qq][4 + r] = (bf16_t)pv[1][r];
            }
        }

        // ---- O += P V over this key half
        __builtin_amdgcn_s_setprio(1);
#pragma unroll
        for (int db = 0; db < 4; ++db) {
            const int vrow = db * 16 + ql;
            const int vsw = (vrow & 7) << 4;
            const bf16x8 vf = *(const bf16x8*)(Vc + vrow * 128 + (vcol ^ vsw));
#pragma unroll
            for (int qq = 0; qq < 2; ++qq)
                oacc[qq][db] = __builtin_amdgcn_mfma_f32_16x16x32_bf16(pa[qq], vf, oacc[qq][db], 0, 0, 0);
        }
        __builtin_amdgcn_s_setprio(0);

        __syncthreads();
#pragma unroll
        for (int kb = 0; kb < 2; ++kb) madd_c[kb] = madd_n[kb];
    }

    // ---- combine key-halves: wg=1 publishes partials, wg=0 merges+stores
#pragma unroll
    for (int qq = 0; qq < 2; ++qq) {
        float l = lsum[qq];
        l += __shfl_xor(l, 16);
        l += __shfl_xor(l, 32);
        lsum[qq] = l;
    }
    const int rbase = g << 2;
    if (wg == 1) {
#pragma unroll
        for (int qq = 0; qq < 2; ++qq) {
#pragma unroll
            for (int db = 0; db < 4; ++db)
#pragma unroll
                for (int r = 0; r < 4; ++r)
                    Cbuf[wq][(qq * 16 + rbase + r) * 64 + db * 16 + ql] = oacc[qq][db][r];
            if (lane < 16) Lbuf[wq][qq][lane] = lsum[qq];
        }
    }
    __syncthreads();
    if (wg == 0) {
#pragma unroll
        for (int qq = 0; qq < 2; ++qq) {
            const float Lq = lsum[qq] + Lbuf[wq][qq][ql];
#pragma unroll
            for (int r = 0; r < 4; ++r) {
                const float Lr = __shfl(Lq, rbase + r);
                const float inv = 1.0f / Lr;
                const int qrow = qbase + qq * 16 + rbase + r;
                bf16_t* orow = aout + ((size_t)(b * QLEN + qrow)) * HIDDEN + h * HDIM;
#pragma unroll
                for (int db = 0; db < 4; ++db) {
                    const float add = Cbuf[wq][(qq * 16 + rbase + r) * 64 + db * 16 + ql];
                    orow[db * 16 + ql] = (bf16_t)((oacc[qq][db][r] + add) * inv);
                }
            }
        }
    }
}

// ---------------------------------------------------------------------------
extern "C" void kernel_launch(void* const* d_in, const int* in_sizes, int n_in,
                              void* d_out, int out_size, void* d_ws, size_t ws_size,
                              hipStream_t stream) {
    (void)in_sizes; (void)n_in; (void)out_size; (void)ws_size;
    const float* q   = (const float*)d_in[0];
    const float* kv  = (const float*)d_in[1];
    const void*  msk = d_in[2];
    const float* Wq  = (const float*)d_in[3];
    const float* bq  = (const float*)d_in[4];
    const float* Wk  = (const float*)d_in[5];
    const float* bk  = (const float*)d_in[6];
    const float* Wv  = (const float*)d_in[7];
    const float* bv  = (const float*)d_in[8];
    const float* Wo  = (const float*)d_in[9];
    const float* bo  = (const float*)d_in[10];

    char* ws = (char*)d_ws;
    const size_t MB = 1024 * 1024;
    float*  maskadd = (float*)ws;                              // 32 KB
    bf16_t* w_bf  = (bf16_t*)(ws + 32 * 1024);                 // 8 MB (4 weights)
    bf16_t* q_bf  = (bf16_t*)(ws + 32 * 1024 + 8  * MB);       // 8 MB (reused as aout)
    bf16_t* kv_bf = (bf16_t*)(ws + 32 * 1024 + 16 * MB);       // 16 MB
    bf16_t* qh    = (bf16_t*)(ws + 32 * 1024 + 32 * MB);       // 8 MB
    bf16_t* kh    = (bf16_t*)(ws + 32 * 1024 + 40 * MB);       // 16 MB
    bf16_t* vt    = (bf16_t*)(ws + 32 * 1024 + 56 * MB);       // 16 MB -> end 72 MB
    bf16_t* aout  = q_bf;    // q_bf dead after projection kernel

    bf16_t* wo_bf = w_bf + (size_t)3 * HIDDEN * HIDDEN;

    cvt_all_kernel<<<dim3(NCVT + 4), 256, 0, stream>>>(
        q, kv, Wq, Wk, Wv, Wo, q_bf, kv_bf, w_bf, msk, maskadd);

    gemm_proj_all<<<dim3(1280), 256, 0, stream>>>(
        q_bf, kv_bf, w_bf, bq, bk, bv, qh, kh, vt);

    attn_fwd_kernel<<<dim3(512), 512, 0, stream>>>(qh, kh, vt, maskadd, aout);

    gemm_out_kernel<64><<<dim3(16, 32), 256, 0, stream>>>(aout, wo_bf, bo, (float*)d_out);
}

// Round 9
// 146.618 us; speedup vs baseline: 1.4237x; 1.0497x over previous
//
#include <hip/hip_runtime.h>
#include <hip/hip_bf16.h>
#include <stdint.h>
#include <math.h>

#define HIDDEN 1024
#define NHEADS 16
#define HDIM   64
#define BSZ    4
#define QLEN   1024
#define KVLEN  2048

typedef __bf16 bf16_t;
typedef __bf16 bf16x8 __attribute__((ext_vector_type(8)));
typedef __bf16 bf16x4 __attribute__((ext_vector_type(4)));
typedef float  f32x4  __attribute__((ext_vector_type(4)));

// fixed-max softmax: p = exp2( s_raw*C_SCALE + madd ).
#define C_SCALE 0.18033688f     /* 0.125 * log2(e) */
#define C_FMADD (-43.2808512f)  /* -30 * log2(e) */

#define GLOAD16(g, l) \
    __builtin_amdgcn_global_load_lds((const __attribute__((address_space(1))) void*)(g), \
                                     (__attribute__((address_space(3))) void*)(l), 16, 0, 0)

__device__ __forceinline__ float clamp50(float v) {
    return fminf(fmaxf(v, -50.f), 50.f);
}

// ---------------------------------------------------------------------------
// One launch converts q, kv, 4 weights (fp32 -> bf16, clamp50) AND the mask
// (dtype auto-detect -> additive exp2-domain constant). Mask = 4 tail blocks.
// ---------------------------------------------------------------------------
#define NQ4  ((BSZ * QLEN  * HIDDEN) / 4)   /* 1048576 */
#define NKV4 ((BSZ * KVLEN * HIDDEN) / 4)   /* 2097152 */
#define NW4  ((HIDDEN * HIDDEN) / 4)        /* 262144  */
#define NCVT ((NQ4 + NKV4 + 4 * NW4) / 256) /* 16384 blocks */

__global__ void cvt_all_kernel(const float* __restrict__ q, const float* __restrict__ kv,
                               const float* __restrict__ W0, const float* __restrict__ W1,
                               const float* __restrict__ W2, const float* __restrict__ W3,
                               bf16_t* __restrict__ q_bf, bf16_t* __restrict__ kv_bf,
                               bf16_t* __restrict__ w_bf,
                               const void* __restrict__ msk, float* __restrict__ maskadd) {
    if (blockIdx.x >= NCVT) {
        __shared__ int s_float, s_multi;
        const int t = threadIdx.x;
        if (t == 0) { s_float = 0; s_multi = 0; }
        __syncthreads();
        const uint32_t* w = (const uint32_t*)msk;
        int cf = 0, cm = 0;
        for (int i = t; i < 2048; i += 256) {
            uint32_t v = w[i];
            if (v == 0x3F800000u) cf++;
            else if (v & 0xFFFFFF00u) cm++;
        }
        if (cf) atomicAdd(&s_float, cf);
        if (cm) atomicAdd(&s_multi, cm);
        __syncthreads();
        const int mode = (s_float > 0) ? 2 : ((s_multi > 0) ? 0 : 1);
        const int base = (blockIdx.x - NCVT) * 2048;
        for (int i = base + t; i < base + 2048; i += 256) {
            bool m;
            if (mode == 2)      m = ((const float*)msk)[i] != 0.0f;
            else if (mode == 1) m = ((const int*)msk)[i] != 0;
            else                m = ((const unsigned char*)msk)[i] != 0;
            maskadd[i] = m ? (-100000.0f + C_FMADD) : C_FMADD;
        }
        return;
    }
    const int i = blockIdx.x * blockDim.x + threadIdx.x;
    const float4* src;
    bf16x4* dst;
    if (i < NQ4) {
        src = (const float4*)q + i;            dst = (bf16x4*)q_bf + i;
    } else if (i < NQ4 + NKV4) {
        const int j = i - NQ4;
        src = (const float4*)kv + j;           dst = (bf16x4*)kv_bf + j;
    } else {
        const int j = i - (NQ4 + NKV4);
        const int ws = j >> 18, off = j & (NW4 - 1);
        const float* W = (ws == 0) ? W0 : (ws == 1) ? W1 : (ws == 2) ? W2 : W3;
        src = (const float4*)W + off;          dst = (bf16x4*)w_bf + (size_t)ws * NW4 + off;
    }
    const float4 v = *src;
    bf16x4 o;
    o[0] = (bf16_t)clamp50(v.x); o[1] = (bf16_t)clamp50(v.y);
    o[2] = (bf16_t)clamp50(v.z); o[3] = (bf16_t)clamp50(v.w);
    *dst = o;
}

// ---------------------------------------------------------------------------
// Staging helper: one K-tile (A 128 rows + B NT rows of 128B) via glds.
// ---------------------------------------------------------------------------
template <int NT>
__device__ __forceinline__ void stage_tile(const char* __restrict__ Ab,
                                           const char* __restrict__ Bb,
                                           char* base, int kt, int wave, int rowl, int srcsw)
{
    constexpr int NF = NT / 32;
#pragma unroll
    for (int i = 0; i < 4; ++i) {
        const int row = i * 32 + wave * 8 + rowl;
        GLOAD16(Ab + (size_t)row * (HIDDEN * 2) + kt * 128 + srcsw,
                base + i * 4096 + wave * 1024);
    }
#pragma unroll
    for (int i = 0; i < NF; ++i) {
        const int row = i * 32 + wave * 8 + rowl;
        GLOAD16(Bb + (size_t)row * (HIDDEN * 2) + kt * 128 + srcsw,
                base + 16384 + i * 4096 + wave * 1024);
    }
}

// ---------------------------------------------------------------------------
// GEMM core v2: 128xNT tile, BK=64, 4 waves (2x2), DOUBLE-BUFFERED LDS with
// early glds issue (attn-style): stage(k+1) -> compute(k) -> one barrier.
// The barrier's vmcnt(0) drain lands after compute has covered load latency.
// LDS = 2 * (128+NT) rows * 128B. K = 1024.
// ---------------------------------------------------------------------------
template <int NT>
__device__ __forceinline__ void gemm_core_db(const char* __restrict__ Ab,
                                             const char* __restrict__ Bb,
                                             char* Ls,
                                             f32x4 (&acc)[4][NT / 32],
                                             int wave, int lane, int wm, int wn)
{
    constexpr int NF = NT / 32;
    constexpr int BUF = (128 + NT) * 128;   // bytes per buffer
    const int srcsw = ((lane & 7) ^ (lane >> 3)) << 4;
    const int rowl = lane >> 3;

    stage_tile<NT>(Ab, Bb, Ls, 0, wave, rowl, srcsw);
    __syncthreads();

    for (int kt = 0; kt < HIDDEN / 64; ++kt) {
        const int cur = kt & 1;
        if (kt < HIDDEN / 64 - 1)
            stage_tile<NT>(Ab, Bb, Ls + (cur ^ 1) * BUF, kt + 1, wave, rowl, srcsw);
        const char* Abase = Ls + cur * BUF;
        const char* Bbase = Abase + 16384;
#pragma unroll
        for (int kc = 0; kc < 2; ++kc) {
            const int kbyte = kc * 64 + ((lane >> 4) << 4);
            bf16x8 af[4], bfr[NF];
#pragma unroll
            for (int f2 = 0; f2 < 4; ++f2) {
                const int arow = wm * 64 + f2 * 16 + (lane & 15);
                af[f2] = *(const bf16x8*)(Abase + arow * 128 + (kbyte ^ ((arow & 7) << 4)));
            }
#pragma unroll
            for (int f2 = 0; f2 < NF; ++f2) {
                const int brow = wn * (NT / 2) + f2 * 16 + (lane & 15);
                bfr[f2] = *(const bf16x8*)(Bbase + brow * 128 + (kbyte ^ ((brow & 7) << 4)));
            }
#pragma unroll
            for (int mf = 0; mf < 4; ++mf)
#pragma unroll
                for (int nf = 0; nf < NF; ++nf)
                    acc[mf][nf] = __builtin_amdgcn_mfma_f32_16x16x32_bf16(af[mf], bfr[nf], acc[mf][nf], 0, 0, 0);
        }
        __syncthreads();   // drains this iter's glds -> other buffer ready
    }
}

// EPI 0 epilogue: bf16 out in per-head layout [(b*16+h)][s][d], seqlen 1<<slog
template <int NF>
__device__ __forceinline__ void epi_head(f32x4 (&acc)[4][NF], const float* bias,
                                         bf16_t* out, int m0, int n0, int slog,
                                         int wm, int wn, int lane)
{
#pragma unroll
    for (int mf = 0; mf < 4; ++mf) {
#pragma unroll
        for (int nf = 0; nf < NF; ++nf) {
            const int gn = n0 + wn * (NF * 16) + nf * 16 + (lane & 15);
            const float bv = bias[gn];
#pragma unroll
            for (int r = 0; r < 4; ++r) {
                const int gm = m0 + wm * 64 + mf * 16 + ((lane >> 4) << 2) + r;
                const float v = clamp50(acc[mf][nf][r] + bv);
                const int b = gm >> slog;
                const int s = gm & ((1 << slog) - 1);
                const int h = gn >> 6, d = gn & 63;
                out[((((size_t)(b * NHEADS + h)) << slog) + s) * HDIM + d] = (bf16_t)v;
            }
        }
    }
}

// ---------------------------------------------------------------------------
// MERGED projection GEMM: q, K, V in one launch. Grid 1280 (1D), dbuf core.
// Bijective XCD swizzle lid = (bid&7)*160 + (bid>>3): the 8 consecutive lids
// sharing an A m-panel run on ONE XCD -> panel stays L2-resident.
// ---------------------------------------------------------------------------
__global__ __launch_bounds__(256)
void gemm_proj_all(const bf16_t* __restrict__ q_bf, const bf16_t* __restrict__ kv_bf,
                   const bf16_t* __restrict__ w_bf,
                   const float* __restrict__ bq, const float* __restrict__ bk,
                   const float* __restrict__ bv,
                   bf16_t* __restrict__ qh, bf16_t* __restrict__ kh,
                   bf16_t* __restrict__ vt)
{
    __shared__ __align__(16) bf16_t Smem[2 * 256 * 64];   // 64 KB (2 buffers)

    const int bid = blockIdx.x;
    const int lid = (bid & 7) * 160 + (bid >> 3);

    int seg, j;
    if (lid < 256)      { seg = 0; j = lid; }
    else if (lid < 768) { seg = 1; j = lid - 256; }
    else                { seg = 2; j = lid - 768; }
    const int m0 = (j >> 3) * 128;
    const int n0 = (j & 7) * 128;
    const bf16_t* A    = (seg == 0) ? q_bf : kv_bf;
    const bf16_t* B    = w_bf + (size_t)seg * (HIDDEN * HIDDEN);   // Wq, Wk, Wv
    const float*  bias = (seg == 0) ? bq : (seg == 1) ? bk : bv;

    const int t = threadIdx.x;
    const int wave = t >> 6, lane = t & 63;
    const int wm = wave >> 1, wn = wave & 1;

    f32x4 acc[4][4] = {};
    gemm_core_db<128>((const char*)A + (size_t)m0 * (HIDDEN * 2),
                      (const char*)B + (size_t)n0 * (HIDDEN * 2),
                      (char*)Smem, acc, wave, lane, wm, wn);

    if (seg == 0) {
        epi_head<4>(acc, bias, qh, m0, n0, 10, wm, wn, lane);
        return;
    }
    if (seg == 1) {
        epi_head<4>(acc, bias, kh, m0, n0, 11, wm, wn, lane);
        return;
    }

    // V: transpose epilogue via LDS (reuse Smem), 2 phases of 64 s-rows.
    bf16_t* Cls = Smem;                  // [64][130]
    const int dl = t >> 1;               // 0..127
    const int sh = (t & 1) << 5;         // 0 or 32
    const int gn = n0 + dl;
    const int h = gn >> 6, d = gn & 63;
    const int bb = m0 >> 11;
    bf16_t* dst = vt + ((size_t)((bb * NHEADS + h) * HDIM + d)) * KVLEN
                + (m0 & (KVLEN - 1)) + sh;
    __syncthreads();
#pragma unroll
    for (int ph = 0; ph < 2; ++ph) {
        if (wm == ph) {
#pragma unroll
            for (int mf = 0; mf < 4; ++mf) {
#pragma unroll
                for (int nf = 0; nf < 4; ++nf) {
                    const int dcol = wn * 64 + nf * 16 + (lane & 15);
                    const float bv2 = bias[n0 + dcol];
#pragma unroll
                    for (int r = 0; r < 4; ++r) {
                        const int srow = mf * 16 + ((lane >> 4) << 2) + r;
                        Cls[srow * 130 + dcol] = (bf16_t)clamp50(acc[mf][nf][r] + bv2);
                    }
                }
            }
        }
        __syncthreads();
#pragma unroll
        for (int j0 = 0; j0 < 32; j0 += 8) {
            bf16x8 v;
#pragma unroll
            for (int jj = 0; jj < 8; ++jj) v[jj] = Cls[(sh + j0 + jj) * 130 + dl];
            *(bf16x8*)(dst + ph * 64 + j0) = v;
        }
        __syncthreads();
    }
}

// ---------------------------------------------------------------------------
// Output-projection GEMM (fp32 out [M][1024]), 128x64 tiles, dbuf core,
// 1D grid 512 with panel-per-XCD swizzle (8 n-blocks... 16 per panel).
// ---------------------------------------------------------------------------
__global__ __launch_bounds__(256)
void gemm_out_kernel(const bf16_t* __restrict__ A, const bf16_t* __restrict__ B,
                     const float* __restrict__ bias, float* __restrict__ out)
{
    constexpr int NT = 64;
    constexpr int NF = NT / 32;
    __shared__ __align__(16) bf16_t Smem[2 * (128 + NT) * 64];   // 48 KB

    const int bid = blockIdx.x;
    const int lid = (bid & 7) * 64 + (bid >> 3);   // 512 = 8 x 64, bijective
    const int m0 = (lid >> 4) * 128;
    const int n0 = (lid & 15) * NT;
    const int t = threadIdx.x;
    const int wave = t >> 6, lane = t & 63;
    const int wm = wave >> 1, wn = wave & 1;

    f32x4 acc[4][NF] = {};
    gemm_core_db<NT>((const char*)A + (size_t)m0 * (HIDDEN * 2),
                     (const char*)B + (size_t)n0 * (HIDDEN * 2),
                     (char*)Smem, acc, wave, lane, wm, wn);

#pragma unroll
    for (int mf = 0; mf < 4; ++mf) {
#pragma unroll
        for (int nf = 0; nf < NF; ++nf) {
            const int gn = n0 + wn * (NF * 16) + nf * 16 + (lane & 15);
            const float bv = bias[gn];
#pragma unroll
            for (int r = 0; r < 4; ++r) {
                const int gm = m0 + wm * 64 + mf * 16 + ((lane >> 4) << 2) + r;
                out[(size_t)gm * HIDDEN + gn] = clamp50(acc[mf][nf][r] + bv);
            }
        }
    }
}

// ---------------------------------------------------------------------------
// Flash attention v3: fixed-max softmax, swapped QK^T (P in registers),
// key-half split across wave pairs, 8 waves / 512 threads, XCD-grouped.
// ---------------------------------------------------------------------------
__global__ __launch_bounds__(512)
void attn_fwd_kernel(const bf16_t* __restrict__ Qh, const bf16_t* __restrict__ Kh,
                     const bf16_t* __restrict__ Vt, const float* __restrict__ maskadd,
                     bf16_t* __restrict__ aout)
{
    __shared__ __align__(16) bf16_t Kls[2][64 * 64];   // 16 KB
    __shared__ __align__(16) bf16_t Vls[2][64 * 64];   // 16 KB
    __shared__ __align__(16) float Cbuf[4][32 * 64];   // 32 KB combine
    __shared__ float Lbuf[4][2][16];

    const int f = blockIdx.x;
    const int o = (f & 7) * 64 + (f >> 3);
    const int qt = o & 7;
    const int bh = o >> 3;
    const int b = bh >> 4, h = bh & 15;
    const int t = threadIdx.x, wave = t >> 6, lane = t & 63;
    const int wq = wave & 3;
    const int wg = wave >> 2;
    const int g = lane >> 4, ql = lane & 15;

    const int qbase = qt * 128 + wq * 32;
    bf16x8 qf[2][2];
#pragma unroll
    for (int qq = 0; qq < 2; ++qq) {
        const bf16_t* qp = Qh + ((size_t)bh * QLEN + qbase + qq * 16 + ql) * HDIM + (g << 3);
        qf[qq][0] = *(const bf16x8*)qp;
        qf[qq][1] = *(const bf16x8*)(qp + 32);
    }

    f32x4 oacc[2][4] = {};
    float lsum[2] = {0.f, 0.f};

    const int srcsw = ((lane & 7) ^ (lane >> 3)) << 4;
    const int R = wave * 8 + (lane >> 3);
    const int kap = 32 * (R >> 5) + 8 * ((R >> 2) & 3) + 4 * ((R >> 4) & 1) + (R & 3);

    const char* Kb = (const char*)(Kh + (size_t)bh * KVLEN * HDIM);
    const char* Vb = (const char*)(Vt + (size_t)bh * HDIM * KVLEN);
    const float* mrow = maskadd + b * KVLEN + wg * 32 + g * 8;
    const int kb0 = g << 4;
    const int vcol = wg * 64 + kb0;

    GLOAD16(Kb + (size_t)kap * 128 + srcsw, (char*)&Kls[0][0] + wave * 1024);
    GLOAD16(Vb + (size_t)R * (KVLEN * 2) + srcsw, (char*)&Vls[0][0] + wave * 1024);
    f32x4 madd_c[2], madd_n[2];
    madd_c[0] = *(const f32x4*)(mrow);
    madd_c[1] = *(const f32x4*)(mrow + 4);
    __syncthreads();

    for (int kt = 0; kt < KVLEN / 64; ++kt) {
        const int cur = kt & 1;
        if (kt < KVLEN / 64 - 1) {
            const size_t ko = (size_t)(kt + 1) * 8192;
            GLOAD16(Kb + ko + (size_t)kap * 128 + srcsw,
                    (char*)&Kls[cur ^ 1][0] + wave * 1024);
            GLOAD16(Vb + (size_t)R * (KVLEN * 2) + (size_t)(kt + 1) * 128 + srcsw,
                    (char*)&Vls[cur ^ 1][0] + wave * 1024);
            madd_n[0] = *(const f32x4*)(mrow + (kt + 1) * 64);
            madd_n[1] = *(const f32x4*)(mrow + (kt + 1) * 64 + 4);
        }
        const char* Kc = (const char*)&Kls[cur][0];
        const char* Vc = (const char*)&Vls[cur][0];

        // ---- S^T = K Q^T over this wave's 32-key half
        f32x4 sacc[2][2] = {};
        __builtin_amdgcn_s_setprio(1);
#pragma unroll
        for (int kb = 0; kb < 2; ++kb) {
            const int key = wg * 32 + kb * 16 + ql;
            const int rowoff = key * 128;
            const int sw = (key & 7) << 4;
            const bf16x8 kf0 = *(const bf16x8*)(Kc + rowoff + ((kb0)      ^ sw));
            const bf16x8 kf1 = *(const bf16x8*)(Kc + rowoff + ((kb0 + 64) ^ sw));
#pragma unroll
            for (int qq = 0; qq < 2; ++qq) {
                sacc[qq][kb] = __builtin_amdgcn_mfma_f32_16x16x32_bf16(kf0, qf[qq][0], sacc[qq][kb], 0, 0, 0);
                sacc[qq][kb] = __builtin_amdgcn_mfma_f32_16x16x32_bf16(kf1, qf[qq][1], sacc[qq][kb], 0, 0, 0);
            }
        }
        __builtin_amdgcn_s_setprio(0);

        // ---- softmax weights in-register + pack to PV A-fragment
        bf16x8 pa[2];
#pragma unroll
        for (int qq = 0; qq < 2; ++qq) {
            float pv[2][4];
            float ls = 0.f;
#pragma unroll
            for (int kb = 0; kb < 2; ++kb) {
#pragma unroll
                for (int r = 0; r < 4; ++r) {
                    pv[kb][r] = __builtin_amdgcn_exp2f(
                        __builtin_fmaf(sacc[qq][kb][r], C_SCALE, madd_c[kb][r]));
                    ls += pv[kb][r];
                }
            }
            lsum[qq] += ls;
#pragma unroll
            for (int r = 0; r < 4; ++r) {
                pa[qq][r]     = (bf16_t)pv[0][r];
                pa[qq][4 + r] = (bf16_t)pv[1][r];
            }
        }

        // ---- O += P V over this key half
        __builtin_amdgcn_s_setprio(1);
#pragma unroll
        for (int db = 0; db < 4; ++db) {
            const int vrow = db * 16 + ql;
            const int vsw = (vrow & 7) << 4;
            const bf16x8 vf = *(const bf16x8*)(Vc + vrow * 128 + (vcol ^ vsw));
#pragma unroll
            for (int qq = 0; qq < 2; ++qq)
                oacc[qq][db] = __builtin_amdgcn_mfma_f32_16x16x32_bf16(pa[qq], vf, oacc[qq][db], 0, 0, 0);
        }
        __builtin_amdgcn_s_setprio(0);

        __syncthreads();
#pragma unroll
        for (int kb = 0; kb < 2; ++kb) madd_c[kb] = madd_n[kb];
    }

    // ---- combine key-halves: wg=1 publishes partials, wg=0 merges+stores
#pragma unroll
    for (int qq = 0; qq < 2; ++qq) {
        float l = lsum[qq];
        l += __shfl_xor(l, 16);
        l += __shfl_xor(l, 32);
        lsum[qq] = l;
    }
    const int rbase = g << 2;
    if (wg == 1) {
#pragma unroll
        for (int qq = 0; qq < 2; ++qq) {
#pragma unroll
            for (int db = 0; db < 4; ++db)
#pragma unroll
                for (int r = 0; r < 4; ++r)
                    Cbuf[wq][(qq * 16 + rbase + r) * 64 + db * 16 + ql] = oacc[qq][db][r];
            if (lane < 16) Lbuf[wq][qq][lane] = lsum[qq];
        }
    }
    __syncthreads();
    if (wg == 0) {
#pragma unroll
        for (int qq = 0; qq < 2; ++qq) {
            const float Lq = lsum[qq] + Lbuf[wq][qq][ql];
#pragma unroll
            for (int r = 0; r < 4; ++r) {
                const float Lr = __shfl(Lq, rbase + r);
                const float inv = 1.0f / Lr;
                const int qrow = qbase + qq * 16 + rbase + r;
                bf16_t* orow = aout + ((size_t)(b * QLEN + qrow)) * HIDDEN + h * HDIM;
#pragma unroll
                for (int db = 0; db < 4; ++db) {
                    const float add = Cbuf[wq][(qq * 16 + rbase + r) * 64 + db * 16 + ql];
                    orow[db * 16 + ql] = (bf16_t)((oacc[qq][db][r] + add) * inv);
                }
            }
        }
    }
}

// ---------------------------------------------------------------------------
extern "C" void kernel_launch(void* const* d_in, const int* in_sizes, int n_in,
                              void* d_out, int out_size, void* d_ws, size_t ws_size,
                              hipStream_t stream) {
    (void)in_sizes; (void)n_in; (void)out_size; (void)ws_size;
    const float* q   = (const float*)d_in[0];
    const float* kv  = (const float*)d_in[1];
    const void*  msk = d_in[2];
    const float* Wq  = (const float*)d_in[3];
    const float* bq  = (const float*)d_in[4];
    const float* Wk  = (const float*)d_in[5];
    const float* bk  = (const float*)d_in[6];
    const float* Wv  = (const float*)d_in[7];
    const float* bv  = (const float*)d_in[8];
    const float* Wo  = (const float*)d_in[9];
    const float* bo  = (const float*)d_in[10];

    char* ws = (char*)d_ws;
    const size_t MB = 1024 * 1024;
    float*  maskadd = (float*)ws;                              // 32 KB
    bf16_t* w_bf  = (bf16_t*)(ws + 32 * 1024);                 // 8 MB (4 weights)
    bf16_t* q_bf  = (bf16_t*)(ws + 32 * 1024 + 8  * MB);       // 8 MB (reused as aout)
    bf16_t* kv_bf = (bf16_t*)(ws + 32 * 1024 + 16 * MB);       // 16 MB
    bf16_t* qh    = (bf16_t*)(ws + 32 * 1024 + 32 * MB);       // 8 MB
    bf16_t* kh    = (bf16_t*)(ws + 32 * 1024 + 40 * MB);       // 16 MB
    bf16_t* vt    = (bf16_t*)(ws + 32 * 1024 + 56 * MB);       // 16 MB -> end 72 MB
    bf16_t* aout  = q_bf;    // q_bf dead after projection kernel

    bf16_t* wo_bf = w_bf + (size_t)3 * HIDDEN * HIDDEN;

    cvt_all_kernel<<<dim3(NCVT + 4), 256, 0, stream>>>(
        q, kv, Wq, Wk, Wv, Wo, q_bf, kv_bf, w_bf, msk, maskadd);

    gemm_proj_all<<<dim3(1280), 256, 0, stream>>>(
        q_bf, kv_bf, w_bf, bq, bk, bv, qh, kh, vt);

    attn_fwd_kernel<<<dim3(512), 512, 0, stream>>>(qh, kh, vt, maskadd, aout);

    gemm_out_kernel<<<dim3(512), 256, 0, stream>>>(aout, wo_bf, bo, (float*)d_out);
}

// Round 10
// 140.109 us; speedup vs baseline: 1.4898x; 1.0465x over previous
//
#include <hip/hip_runtime.h>
#include <hip/hip_bf16.h>
#include <stdint.h>
#include <math.h>

#define HIDDEN 1024
#define NHEADS 16
#define HDIM   64
#define BSZ    4
#define QLEN   1024
#define KVLEN  2048

typedef __bf16 bf16_t;
typedef __bf16 bf16x8 __attribute__((ext_vector_type(8)));
typedef __bf16 bf16x4 __attribute__((ext_vector_type(4)));
typedef float  f32x4  __attribute__((ext_vector_type(4)));

// fixed-max softmax: p = exp2( s_raw*C_SCALE + madd ).
#define C_SCALE 0.18033688f     /* 0.125 * log2(e) */
#define C_FMADD (-43.2808512f)  /* -30 * log2(e) */

#define GLOAD16(g, l) \
    __builtin_amdgcn_global_load_lds((const __attribute__((address_space(1))) void*)(g), \
                                     (__attribute__((address_space(3))) void*)(l), 16, 0, 0)

__device__ __forceinline__ float clamp50(float v) {
    return fminf(fmaxf(v, -50.f), 50.f);
}

// ---------------------------------------------------------------------------
// One launch converts q, kv, 4 weights (fp32 -> bf16, clamp50) AND the mask
// (dtype auto-detect -> additive exp2-domain constant). Mask = 4 tail blocks.
// ---------------------------------------------------------------------------
#define NQ4  ((BSZ * QLEN  * HIDDEN) / 4)   /* 1048576 */
#define NKV4 ((BSZ * KVLEN * HIDDEN) / 4)   /* 2097152 */
#define NW4  ((HIDDEN * HIDDEN) / 4)        /* 262144  */
#define NCVT ((NQ4 + NKV4 + 4 * NW4) / 256) /* 16384 blocks */

__global__ void cvt_all_kernel(const float* __restrict__ q, const float* __restrict__ kv,
                               const float* __restrict__ W0, const float* __restrict__ W1,
                               const float* __restrict__ W2, const float* __restrict__ W3,
                               bf16_t* __restrict__ q_bf, bf16_t* __restrict__ kv_bf,
                               bf16_t* __restrict__ w_bf,
                               const void* __restrict__ msk, float* __restrict__ maskadd) {
    if (blockIdx.x >= NCVT) {
        __shared__ int s_float, s_multi;
        const int t = threadIdx.x;
        if (t == 0) { s_float = 0; s_multi = 0; }
        __syncthreads();
        const uint32_t* w = (const uint32_t*)msk;
        int cf = 0, cm = 0;
        for (int i = t; i < 2048; i += 256) {
            uint32_t v = w[i];
            if (v == 0x3F800000u) cf++;
            else if (v & 0xFFFFFF00u) cm++;
        }
        if (cf) atomicAdd(&s_float, cf);
        if (cm) atomicAdd(&s_multi, cm);
        __syncthreads();
        const int mode = (s_float > 0) ? 2 : ((s_multi > 0) ? 0 : 1);
        const int base = (blockIdx.x - NCVT) * 2048;
        for (int i = base + t; i < base + 2048; i += 256) {
            bool m;
            if (mode == 2)      m = ((const float*)msk)[i] != 0.0f;
            else if (mode == 1) m = ((const int*)msk)[i] != 0;
            else                m = ((const unsigned char*)msk)[i] != 0;
            maskadd[i] = m ? (-100000.0f + C_FMADD) : C_FMADD;
        }
        return;
    }
    const int i = blockIdx.x * blockDim.x + threadIdx.x;
    const float4* src;
    bf16x4* dst;
    if (i < NQ4) {
        src = (const float4*)q + i;            dst = (bf16x4*)q_bf + i;
    } else if (i < NQ4 + NKV4) {
        const int j = i - NQ4;
        src = (const float4*)kv + j;           dst = (bf16x4*)kv_bf + j;
    } else {
        const int j = i - (NQ4 + NKV4);
        const int ws = j >> 18, off = j & (NW4 - 1);
        const float* W = (ws == 0) ? W0 : (ws == 1) ? W1 : (ws == 2) ? W2 : W3;
        src = (const float4*)W + off;          dst = (bf16x4*)w_bf + (size_t)ws * NW4 + off;
    }
    const float4 v = *src;
    bf16x4 o;
    o[0] = (bf16_t)clamp50(v.x); o[1] = (bf16_t)clamp50(v.y);
    o[2] = (bf16_t)clamp50(v.z); o[3] = (bf16_t)clamp50(v.w);
    *dst = o;
}

// ---------------------------------------------------------------------------
// 8-WAVE GEMM core: 128xNT tile, BK=64, 8 waves (2m x 4n), double-buffered
// LDS with early glds issue. Per-wave output 64 x NT/4. LDS layout:
// A tile 128 rows x 128B, then B tile NT rows x 128B. Source-side swizzle:
// LDS[row][c] = G[row][c ^ (row&7)].
// ---------------------------------------------------------------------------
template <int NT>
__device__ __forceinline__ void stage_tile8(const char* __restrict__ Ab,
                                            const char* __restrict__ Bb,
                                            char* base, int kt, int wave, int rowl, int srcsw)
{
#pragma unroll
    for (int i = 0; i < 2; ++i) {
        const int row = i * 64 + wave * 8 + rowl;
        GLOAD16(Ab + (size_t)row * (HIDDEN * 2) + kt * 128 + srcsw,
                base + i * 8192 + wave * 1024);
    }
#pragma unroll
    for (int i = 0; i < NT / 64; ++i) {
        const int row = i * 64 + wave * 8 + rowl;
        GLOAD16(Bb + (size_t)row * (HIDDEN * 2) + kt * 128 + srcsw,
                base + 16384 + i * 8192 + wave * 1024);
    }
}

template <int NT>
__device__ __forceinline__ void gemm_core_db8(const char* __restrict__ Ab,
                                              const char* __restrict__ Bb,
                                              char* Ls,
                                              f32x4 (&acc)[4][NT / 64],
                                              int wave, int lane, int wm, int wn)
{
    constexpr int NFB = NT / 64;
    constexpr int BUF = (128 + NT) * 128;   // bytes per buffer
    const int srcsw = ((lane & 7) ^ (lane >> 3)) << 4;
    const int rowl = lane >> 3;
    const int ql = lane & 15;

    stage_tile8<NT>(Ab, Bb, Ls, 0, wave, rowl, srcsw);
    __syncthreads();

    for (int kt = 0; kt < HIDDEN / 64; ++kt) {
        const int cur = kt & 1;
        if (kt < HIDDEN / 64 - 1)
            stage_tile8<NT>(Ab, Bb, Ls + (cur ^ 1) * BUF, kt + 1, wave, rowl, srcsw);
        const char* Abase = Ls + cur * BUF;
        const char* Bbase = Abase + 16384;
#pragma unroll
        for (int kc = 0; kc < 2; ++kc) {
            const int kbyte = kc * 64 + ((lane >> 4) << 4);
            bf16x8 af[4], bfr[NFB];
#pragma unroll
            for (int f2 = 0; f2 < 4; ++f2) {
                const int arow = wm * 64 + f2 * 16 + ql;
                af[f2] = *(const bf16x8*)(Abase + arow * 128 + (kbyte ^ ((arow & 7) << 4)));
            }
#pragma unroll
            for (int f2 = 0; f2 < NFB; ++f2) {
                const int brow = wn * (NT / 4) + f2 * 16 + ql;
                bfr[f2] = *(const bf16x8*)(Bbase + brow * 128 + (kbyte ^ ((brow & 7) << 4)));
            }
#pragma unroll
            for (int mf = 0; mf < 4; ++mf)
#pragma unroll
                for (int nf = 0; nf < NFB; ++nf)
                    acc[mf][nf] = __builtin_amdgcn_mfma_f32_16x16x32_bf16(af[mf], bfr[nf], acc[mf][nf], 0, 0, 0);
        }
        __syncthreads();   // drains this iter's glds -> other buffer ready
    }
}

// EPI epilogue: bf16 out in per-head layout [(b*16+h)][s][d], seqlen 1<<slog
template <int NF>
__device__ __forceinline__ void epi_head(f32x4 (&acc)[4][NF], const float* bias,
                                         bf16_t* out, int m0, int n0, int slog,
                                         int wm, int wn, int lane)
{
#pragma unroll
    for (int mf = 0; mf < 4; ++mf) {
#pragma unroll
        for (int nf = 0; nf < NF; ++nf) {
            const int gn = n0 + wn * (NF * 16) + nf * 16 + (lane & 15);
            const float bv = bias[gn];
#pragma unroll
            for (int r = 0; r < 4; ++r) {
                const int gm = m0 + wm * 64 + mf * 16 + ((lane >> 4) << 2) + r;
                const float v = clamp50(acc[mf][nf][r] + bv);
                const int b = gm >> slog;
                const int s = gm & ((1 << slog) - 1);
                const int h = gn >> 6, d = gn & 63;
                out[((((size_t)(b * NHEADS + h)) << slog) + s) * HDIM + d] = (bf16_t)v;
            }
        }
    }
}

// ---------------------------------------------------------------------------
// MERGED projection GEMM: q, K, V in one launch. Grid 1280, 512 thr (8 waves).
// Bijective XCD swizzle lid = (bid&7)*160 + (bid>>3): the 8 consecutive lids
// sharing an A m-panel run on ONE XCD -> panel stays L2-resident.
// ---------------------------------------------------------------------------
__global__ __launch_bounds__(512)
void gemm_proj_all(const bf16_t* __restrict__ q_bf, const bf16_t* __restrict__ kv_bf,
                   const bf16_t* __restrict__ w_bf,
                   const float* __restrict__ bq, const float* __restrict__ bk,
                   const float* __restrict__ bv,
                   bf16_t* __restrict__ qh, bf16_t* __restrict__ kh,
                   bf16_t* __restrict__ vt)
{
    __shared__ __align__(16) bf16_t Smem[2 * 256 * 64];   // 64 KB (2 buffers)

    const int bid = blockIdx.x;
    const int lid = (bid & 7) * 160 + (bid >> 3);

    int seg, j;
    if (lid < 256)      { seg = 0; j = lid; }
    else if (lid < 768) { seg = 1; j = lid - 256; }
    else                { seg = 2; j = lid - 768; }
    const int m0 = (j >> 3) * 128;
    const int n0 = (j & 7) * 128;
    const bf16_t* A    = (seg == 0) ? q_bf : kv_bf;
    const bf16_t* B    = w_bf + (size_t)seg * (HIDDEN * HIDDEN);   // Wq, Wk, Wv
    const float*  bias = (seg == 0) ? bq : (seg == 1) ? bk : bv;

    const int t = threadIdx.x;
    const int wave = t >> 6, lane = t & 63;
    const int wm = wave >> 2, wn = wave & 3;

    f32x4 acc[4][2] = {};
    gemm_core_db8<128>((const char*)A + (size_t)m0 * (HIDDEN * 2),
                       (const char*)B + (size_t)n0 * (HIDDEN * 2),
                       (char*)Smem, acc, wave, lane, wm, wn);

    if (seg == 0) {
        epi_head<2>(acc, bias, qh, m0, n0, 10, wm, wn, lane);
        return;
    }
    if (seg == 1) {
        epi_head<2>(acc, bias, kh, m0, n0, 11, wm, wn, lane);
        return;
    }

    // V: transpose epilogue via LDS (reuse Smem), 2 phases of 64 s-rows.
    bf16_t* Cls = Smem;                  // [64][130]
    const int dl = t >> 2;               // 0..127
    const int sh = (t & 3) << 4;         // 0,16,32,48
    const int gn = n0 + dl;
    const int h = gn >> 6, d = gn & 63;
    const int bb = m0 >> 11;
    bf16_t* dst = vt + ((size_t)((bb * NHEADS + h) * HDIM + d)) * KVLEN
                + (m0 & (KVLEN - 1)) + sh;
    __syncthreads();
#pragma unroll
    for (int ph = 0; ph < 2; ++ph) {
        if (wm == ph) {
#pragma unroll
            for (int mf = 0; mf < 4; ++mf) {
#pragma unroll
                for (int nf = 0; nf < 2; ++nf) {
                    const int dcol = wn * 32 + nf * 16 + (lane & 15);
                    const float bv2 = bias[n0 + dcol];
#pragma unroll
                    for (int r = 0; r < 4; ++r) {
                        const int srow = mf * 16 + ((lane >> 4) << 2) + r;
                        Cls[srow * 130 + dcol] = (bf16_t)clamp50(acc[mf][nf][r] + bv2);
                    }
                }
            }
        }
        __syncthreads();
#pragma unroll
        for (int j0 = 0; j0 < 16; j0 += 8) {
            bf16x8 v;
#pragma unroll
            for (int jj = 0; jj < 8; ++jj) v[jj] = Cls[(sh + j0 + jj) * 130 + dl];
            *(bf16x8*)(dst + ph * 64 + j0) = v;
        }
        __syncthreads();
    }
}

// ---------------------------------------------------------------------------
// Output-projection GEMM (fp32 out [M][1024]), 128x64 tiles, 8 waves,
// dbuf core, 1D grid 512 with panel-per-XCD swizzle.
// ---------------------------------------------------------------------------
__global__ __launch_bounds__(512)
void gemm_out_kernel(const bf16_t* __restrict__ A, const bf16_t* __restrict__ B,
                     const float* __restrict__ bias, float* __restrict__ out)
{
    constexpr int NT = 64;
    __shared__ __align__(16) bf16_t Smem[2 * (128 + NT) * 64];   // 48 KB

    const int bid = blockIdx.x;
    const int lid = (bid & 7) * 64 + (bid >> 3);   // 512 = 8 x 64, bijective
    const int m0 = (lid >> 4) * 128;
    const int n0 = (lid & 15) * NT;
    const int t = threadIdx.x;
    const int wave = t >> 6, lane = t & 63;
    const int wm = wave >> 2, wn = wave & 3;

    f32x4 acc[4][1] = {};
    gemm_core_db8<NT>((const char*)A + (size_t)m0 * (HIDDEN * 2),
                      (const char*)B + (size_t)n0 * (HIDDEN * 2),
                      (char*)Smem, acc, wave, lane, wm, wn);

#pragma unroll
    for (int mf = 0; mf < 4; ++mf) {
        const int gn = n0 + wn * 16 + (lane & 15);
        const float bv = bias[gn];
#pragma unroll
        for (int r = 0; r < 4; ++r) {
            const int gm = m0 + wm * 64 + mf * 16 + ((lane >> 4) << 2) + r;
            out[(size_t)gm * HIDDEN + gn] = clamp50(acc[mf][0][r] + bv);
        }
    }
}

// ---------------------------------------------------------------------------
// Flash attention v3: fixed-max softmax, swapped QK^T (P in registers),
// key-half split across wave pairs, 8 waves / 512 threads, XCD-grouped.
// ---------------------------------------------------------------------------
__global__ __launch_bounds__(512)
void attn_fwd_kernel(const bf16_t* __restrict__ Qh, const bf16_t* __restrict__ Kh,
                     const bf16_t* __restrict__ Vt, const float* __restrict__ maskadd,
                     bf16_t* __restrict__ aout)
{
    __shared__ __align__(16) bf16_t Kls[2][64 * 64];   // 16 KB
    __shared__ __align__(16) bf16_t Vls[2][64 * 64];   // 16 KB
    __shared__ __align__(16) float Cbuf[4][32 * 64];   // 32 KB combine
    __shared__ float Lbuf[4][2][16];

    const int f = blockIdx.x;
    const int o = (f & 7) * 64 + (f >> 3);
    const int qt = o & 7;
    const int bh = o >> 3;
    const int b = bh >> 4, h = bh & 15;
    const int t = threadIdx.x, wave = t >> 6, lane = t & 63;
    const int wq = wave & 3;
    const int wg = wave >> 2;
    const int g = lane >> 4, ql = lane & 15;

    const int qbase = qt * 128 + wq * 32;
    bf16x8 qf[2][2];
#pragma unroll
    for (int qq = 0; qq < 2; ++qq) {
        const bf16_t* qp = Qh + ((size_t)bh * QLEN + qbase + qq * 16 + ql) * HDIM + (g << 3);
        qf[qq][0] = *(const bf16x8*)qp;
        qf[qq][1] = *(const bf16x8*)(qp + 32);
    }

    f32x4 oacc[2][4] = {};
    float lsum[2] = {0.f, 0.f};

    const int srcsw = ((lane & 7) ^ (lane >> 3)) << 4;
    const int R = wave * 8 + (lane >> 3);
    const int kap = 32 * (R >> 5) + 8 * ((R >> 2) & 3) + 4 * ((R >> 4) & 1) + (R & 3);

    const char* Kb = (const char*)(Kh + (size_t)bh * KVLEN * HDIM);
    const char* Vb = (const char*)(Vt + (size_t)bh * HDIM * KVLEN);
    const float* mrow = maskadd + b * KVLEN + wg * 32 + g * 8;
    const int kb0 = g << 4;
    const int vcol = wg * 64 + kb0;

    GLOAD16(Kb + (size_t)kap * 128 + srcsw, (char*)&Kls[0][0] + wave * 1024);
    GLOAD16(Vb + (size_t)R * (KVLEN * 2) + srcsw, (char*)&Vls[0][0] + wave * 1024);
    f32x4 madd_c[2], madd_n[2];
    madd_c[0] = *(const f32x4*)(mrow);
    madd_c[1] = *(const f32x4*)(mrow + 4);
    __syncthreads();

    for (int kt = 0; kt < KVLEN / 64; ++kt) {
        const int cur = kt & 1;
        if (kt < KVLEN / 64 - 1) {
            const size_t ko = (size_t)(kt + 1) * 8192;
            GLOAD16(Kb + ko + (size_t)kap * 128 + srcsw,
                    (char*)&Kls[cur ^ 1][0] + wave * 1024);
            GLOAD16(Vb + (size_t)R * (KVLEN * 2) + (size_t)(kt + 1) * 128 + srcsw,
                    (char*)&Vls[cur ^ 1][0] + wave * 1024);
            madd_n[0] = *(const f32x4*)(mrow + (kt + 1) * 64);
            madd_n[1] = *(const f32x4*)(mrow + (kt + 1) * 64 + 4);
        }
        const char* Kc = (const char*)&Kls[cur][0];
        const char* Vc = (const char*)&Vls[cur][0];

        // ---- S^T = K Q^T over this wave's 32-key half
        f32x4 sacc[2][2] = {};
        __builtin_amdgcn_s_setprio(1);
#pragma unroll
        for (int kb = 0; kb < 2; ++kb) {
            const int key = wg * 32 + kb * 16 + ql;
            const int rowoff = key * 128;
            const int sw = (key & 7) << 4;
            const bf16x8 kf0 = *(const bf16x8*)(Kc + rowoff + ((kb0)      ^ sw));
            const bf16x8 kf1 = *(const bf16x8*)(Kc + rowoff + ((kb0 + 64) ^ sw));
#pragma unroll
            for (int qq = 0; qq < 2; ++qq) {
                sacc[qq][kb] = __builtin_amdgcn_mfma_f32_16x16x32_bf16(kf0, qf[qq][0], sacc[qq][kb], 0, 0, 0);
                sacc[qq][kb] = __builtin_amdgcn_mfma_f32_16x16x32_bf16(kf1, qf[qq][1], sacc[qq][kb], 0, 0, 0);
            }
        }
        __builtin_amdgcn_s_setprio(0);

        // ---- softmax weights in-register + pack to PV A-fragment
        bf16x8 pa[2];
#pragma unroll
        for (int qq = 0; qq < 2; ++qq) {
            float pv[2][4];
            float ls = 0.f;
#pragma unroll
            for (int kb = 0; kb < 2; ++kb) {
#pragma unroll
                for (int r = 0; r < 4; ++r) {
                    pv[kb][r] = __builtin_amdgcn_exp2f(
                        __builtin_fmaf(sacc[qq][kb][r], C_SCALE, madd_c[kb][r]));
                    ls += pv[kb][r];
                }
            }
            lsum[qq] += ls;
#pragma unroll
            for (int r = 0; r < 4; ++r) {
                pa[qq][r]     = (bf16_t)pv[0][r];
                pa[qq][4 + r] = (bf16_t)pv[1][r];
            }
        }

        // ---- O += P V over this key half
        __builtin_amdgcn_s_setprio(1);
#pragma unroll
        for (int db = 0; db < 4; ++db) {
            const int vrow = db * 16 + ql;
            const int vsw = (vrow & 7) << 4;
            const bf16x8 vf = *(const bf16x8*)(Vc + vrow * 128 + (vcol ^ vsw));
#pragma unroll
            for (int qq = 0; qq < 2; ++qq)
                oacc[qq][db] = __builtin_amdgcn_mfma_f32_16x16x32_bf16(pa[qq], vf, oacc[qq][db], 0, 0, 0);
        }
        __builtin_amdgcn_s_setprio(0);

        __syncthreads();
#pragma unroll
        for (int kb = 0; kb < 2; ++kb) madd_c[kb] = madd_n[kb];
    }

    // ---- combine key-halves: wg=1 publishes partials, wg=0 merges+stores
#pragma unroll
    for (int qq = 0; qq < 2; ++qq) {
        float l = lsum[qq];
        l += __shfl_xor(l, 16);
        l += __shfl_xor(l, 32);
        lsum[qq] = l;
    }
    const int rbase = g << 2;
    if (wg == 1) {
#pragma unroll
        for (int qq = 0; qq < 2; ++qq) {
#pragma unroll
            for (int db = 0; db < 4; ++db)
#pragma unroll
                for (int r = 0; r < 4; ++r)
                    Cbuf[wq][(qq * 16 + rbase + r) * 64 + db * 16 + ql] = oacc[qq][db][r];
            if (lane < 16) Lbuf[wq][qq][lane] = lsum[qq];
        }
    }
    __syncthreads();
    if (wg == 0) {
#pragma unroll
        for (int qq = 0; qq < 2; ++qq) {
            const float Lq = lsum[qq] + Lbuf[wq][qq][ql];
#pragma unroll
            for (int r = 0; r < 4; ++r) {
                const float Lr = __shfl(Lq, rbase + r);
                const float inv = 1.0f / Lr;
                const int qrow = qbase + qq * 16 + rbase + r;
                bf16_t* orow = aout + ((size_t)(b * QLEN + qrow)) * HIDDEN + h * HDIM;
#pragma unroll
                for (int db = 0; db < 4; ++db) {
                    const float add = Cbuf[wq][(qq * 16 + rbase + r) * 64 + db * 16 + ql];
                    orow[db * 16 + ql] = (bf16_t)((oacc[qq][db][r] + add) * inv);
                }
            }
        }
    }
}

// ---------------------------------------------------------------------------
extern "C" void kernel_launch(void* const* d_in, const int* in_sizes, int n_in,
                              void* d_out, int out_size, void* d_ws, size_t ws_size,
                              hipStream_t stream) {
    (void)in_sizes; (void)n_in; (void)out_size; (void)ws_size;
    const float* q   = (const float*)d_in[0];
    const float* kv  = (const float*)d_in[1];
    const void*  msk = d_in[2];
    const float* Wq  = (const float*)d_in[3];
    const float* bq  = (const float*)d_in[4];
    const float* Wk  = (const float*)d_in[5];
    const float* bk  = (const float*)d_in[6];
    const float* Wv  = (const float*)d_in[7];
    const float* bv  = (const float*)d_in[8];
    const float* Wo  = (const float*)d_in[9];
    const float* bo  = (const float*)d_in[10];

    char* ws = (char*)d_ws;
    const size_t MB = 1024 * 1024;
    float*  maskadd = (float*)ws;                              // 32 KB
    bf16_t* w_bf  = (bf16_t*)(ws + 32 * 1024);                 // 8 MB (4 weights)
    bf16_t* q_bf  = (bf16_t*)(ws + 32 * 1024 + 8  * MB);       // 8 MB (reused as aout)
    bf16_t* kv_bf = (bf16_t*)(ws + 32 * 1024 + 16 * MB);       // 16 MB
    bf16_t* qh    = (bf16_t*)(ws + 32 * 1024 + 32 * MB);       // 8 MB
    bf16_t* kh    = (bf16_t*)(ws + 32 * 1024 + 40 * MB);       // 16 MB
    bf16_t* vt    = (bf16_t*)(ws + 32 * 1024 + 56 * MB);       // 16 MB -> end 72 MB
    bf16_t* aout  = q_bf;    // q_bf dead after projection kernel

    bf16_t* wo_bf = w_bf + (size_t)3 * HIDDEN * HIDDEN;

    cvt_all_kernel<<<dim3(NCVT + 4), 256, 0, stream>>>(
        q, kv, Wq, Wk, Wv, Wo, q_bf, kv_bf, w_bf, msk, maskadd);

    gemm_proj_all<<<dim3(1280), 512, 0, stream>>>(
        q_bf, kv_bf, w_bf, bq, bk, bv, qh, kh, vt);

    attn_fwd_kernel<<<dim3(512), 512, 0, stream>>>(qh, kh, vt, maskadd, aout);

    gemm_out_kernel<<<dim3(512), 512, 0, stream>>>(aout, wo_bf, bo, (float*)d_out);
}

// Round 11
// 140.036 us; speedup vs baseline: 1.4906x; 1.0005x over previous
//
#include <hip/hip_runtime.h>
#include <hip/hip_bf16.h>
#include <stdint.h>
#include <math.h>

#define HIDDEN 1024
#define NHEADS 16
#define HDIM   64
#define BSZ    4
#define QLEN   1024
#define KVLEN  2048

typedef __bf16 bf16_t;
typedef __bf16 bf16x8 __attribute__((ext_vector_type(8)));
typedef __bf16 bf16x4 __attribute__((ext_vector_type(4)));
typedef float  f32x4  __attribute__((ext_vector_type(4)));

// fixed-max softmax: p = exp2( s_raw*C_SCALE + madd ).
#define C_SCALE 0.18033688f     /* 0.125 * log2(e) */
#define C_FMADD (-43.2808512f)  /* -30 * log2(e) */

#define GLOAD16(g, l) \
    __builtin_amdgcn_global_load_lds((const __attribute__((address_space(1))) void*)(g), \
                                     (__attribute__((address_space(3))) void*)(l), 16, 0, 0)

__device__ __forceinline__ float clamp50(float v) {
    return fminf(fmaxf(v, -50.f), 50.f);
}

// ---------------------------------------------------------------------------
// Converts the 4 weights (fp32 -> bf16; clamp50 is a no-op for |W|<=1/32 but
// kept for exactness) AND the mask (dtype auto-detect -> additive exp2-domain
// constant). q/kv conversion is now FUSED into the projection GEMM staging.
// Grid: 4096 weight blocks + 4 mask blocks.
// ---------------------------------------------------------------------------
#define NW4  ((HIDDEN * HIDDEN) / 4)        /* 262144 */
#define NWCVT (4 * NW4 / 256)               /* 4096 blocks */

__global__ void cvt_w_mask_kernel(const float* __restrict__ W0, const float* __restrict__ W1,
                                  const float* __restrict__ W2, const float* __restrict__ W3,
                                  bf16_t* __restrict__ w_bf,
                                  const void* __restrict__ msk, float* __restrict__ maskadd) {
    if (blockIdx.x >= NWCVT) {
        __shared__ int s_float, s_multi;
        const int t = threadIdx.x;
        if (t == 0) { s_float = 0; s_multi = 0; }
        __syncthreads();
        const uint32_t* w = (const uint32_t*)msk;
        int cf = 0, cm = 0;
        for (int i = t; i < 2048; i += 256) {
            uint32_t v = w[i];
            if (v == 0x3F800000u) cf++;
            else if (v & 0xFFFFFF00u) cm++;
        }
        if (cf) atomicAdd(&s_float, cf);
        if (cm) atomicAdd(&s_multi, cm);
        __syncthreads();
        const int mode = (s_float > 0) ? 2 : ((s_multi > 0) ? 0 : 1);
        const int base = (blockIdx.x - NWCVT) * 2048;
        for (int i = base + t; i < base + 2048; i += 256) {
            bool m;
            if (mode == 2)      m = ((const float*)msk)[i] != 0.0f;
            else if (mode == 1) m = ((const int*)msk)[i] != 0;
            else                m = ((const unsigned char*)msk)[i] != 0;
            maskadd[i] = m ? (-100000.0f + C_FMADD) : C_FMADD;
        }
        return;
    }
    const int i = blockIdx.x * blockDim.x + threadIdx.x;
    const int ws = i >> 18, off = i & (NW4 - 1);
    const float* W = (ws == 0) ? W0 : (ws == 1) ? W1 : (ws == 2) ? W2 : W3;
    const float4 v = ((const float4*)W)[off];
    bf16x4 o;
    o[0] = (bf16_t)clamp50(v.x); o[1] = (bf16_t)clamp50(v.y);
    o[2] = (bf16_t)clamp50(v.z); o[3] = (bf16_t)clamp50(v.w);
    ((bf16x4*)w_bf)[(size_t)ws * NW4 + off] = o;
}

// ---------------------------------------------------------------------------
// Projection GEMM core, 8 waves, 128x128 tile, BK=64, double-buffered.
// A is FP32 in global: reg-staged with fused clamp50+cvt (T14 split: loads
// issued BEFORE compute, converted+ds_written AFTER compute, before barrier).
// B is bf16 weights staged via global_load_lds. Source-side swizzle on both:
// LDS[row][c] = G[row][c^(row&7)] (fp32 source chunk = 32B, bf16 = 16B).
// ---------------------------------------------------------------------------
__device__ __forceinline__ void proj_core(const char* __restrict__ Ab,   // fp32
                                          const char* __restrict__ Bb,   // bf16
                                          char* Ls, f32x4 (&acc)[4][2],
                                          int wave, int lane, int wm, int wn)
{
    constexpr int BUF = 256 * 128;   // 32 KB per buffer (A 16K + B 16K)
    const int srcsw = ((lane & 7) ^ (lane >> 3)) << 4;
    const int rowl = lane >> 3;
    const int ql = lane & 15;

    float4 a0[2], a1[2];
    // ---- prologue: A loads (fp32), B glds, convert+write A, barrier
#pragma unroll
    for (int i = 0; i < 2; ++i) {
        const int row = i * 64 + wave * 8 + rowl;
        const float4* p = (const float4*)(Ab + (size_t)row * (HIDDEN * 4) + (srcsw << 1));
        a0[i] = p[0]; a1[i] = p[1];
    }
#pragma unroll
    for (int i = 0; i < 2; ++i) {
        const int row = i * 64 + wave * 8 + rowl;
        GLOAD16(Bb + (size_t)row * (HIDDEN * 2) + srcsw,
                Ls + 16384 + i * 8192 + wave * 1024);
    }
#pragma unroll
    for (int i = 0; i < 2; ++i) {
        bf16x8 o;
        o[0] = (bf16_t)clamp50(a0[i].x); o[1] = (bf16_t)clamp50(a0[i].y);
        o[2] = (bf16_t)clamp50(a0[i].z); o[3] = (bf16_t)clamp50(a0[i].w);
        o[4] = (bf16_t)clamp50(a1[i].x); o[5] = (bf16_t)clamp50(a1[i].y);
        o[6] = (bf16_t)clamp50(a1[i].z); o[7] = (bf16_t)clamp50(a1[i].w);
        *(bf16x8*)(Ls + i * 8192 + wave * 1024 + lane * 16) = o;
    }
    __syncthreads();

    for (int kt = 0; kt < HIDDEN / 64; ++kt) {
        const int cur = kt & 1;
        // ---- issue next tile: A fp32 loads to regs, B glds direct
        if (kt < HIDDEN / 64 - 1) {
#pragma unroll
            for (int i = 0; i < 2; ++i) {
                const int row = i * 64 + wave * 8 + rowl;
                const float4* p = (const float4*)(Ab + (size_t)row * (HIDDEN * 4)
                                                  + (kt + 1) * 256 + (srcsw << 1));
                a0[i] = p[0]; a1[i] = p[1];
            }
#pragma unroll
            for (int i = 0; i < 2; ++i) {
                const int row = i * 64 + wave * 8 + rowl;
                GLOAD16(Bb + (size_t)row * (HIDDEN * 2) + (kt + 1) * 128 + srcsw,
                        Ls + (cur ^ 1) * BUF + 16384 + i * 8192 + wave * 1024);
            }
        }
        // ---- compute current tile
        const char* Abase = Ls + cur * BUF;
        const char* Bbase = Abase + 16384;
#pragma unroll
        for (int kc = 0; kc < 2; ++kc) {
            const int kbyte = kc * 64 + ((lane >> 4) << 4);
            bf16x8 af[4], bfr[2];
#pragma unroll
            for (int f2 = 0; f2 < 4; ++f2) {
                const int arow = wm * 64 + f2 * 16 + ql;
                af[f2] = *(const bf16x8*)(Abase + arow * 128 + (kbyte ^ ((arow & 7) << 4)));
            }
#pragma unroll
            for (int f2 = 0; f2 < 2; ++f2) {
                const int brow = wn * 32 + f2 * 16 + ql;
                bfr[f2] = *(const bf16x8*)(Bbase + brow * 128 + (kbyte ^ ((brow & 7) << 4)));
            }
#pragma unroll
            for (int mf = 0; mf < 4; ++mf)
#pragma unroll
                for (int nf = 0; nf < 2; ++nf)
                    acc[mf][nf] = __builtin_amdgcn_mfma_f32_16x16x32_bf16(af[mf], bfr[nf], acc[mf][nf], 0, 0, 0);
        }
        // ---- write-late: convert A regs -> other buffer
        if (kt < HIDDEN / 64 - 1) {
#pragma unroll
            for (int i = 0; i < 2; ++i) {
                bf16x8 o;
                o[0] = (bf16_t)clamp50(a0[i].x); o[1] = (bf16_t)clamp50(a0[i].y);
                o[2] = (bf16_t)clamp50(a0[i].z); o[3] = (bf16_t)clamp50(a0[i].w);
                o[4] = (bf16_t)clamp50(a1[i].x); o[5] = (bf16_t)clamp50(a1[i].y);
                o[6] = (bf16_t)clamp50(a1[i].z); o[7] = (bf16_t)clamp50(a1[i].w);
                *(bf16x8*)(Ls + (cur ^ 1) * BUF + i * 8192 + wave * 1024 + lane * 16) = o;
            }
        }
        __syncthreads();   // drains B glds + makes A ds_writes visible
    }
}

// EPI epilogue: bf16 out in per-head layout [(b*16+h)][s][d], seqlen 1<<slog
template <int NF>
__device__ __forceinline__ void epi_head(f32x4 (&acc)[4][NF], const float* bias,
                                         bf16_t* out, int m0, int n0, int slog,
                                         int wm, int wn, int lane)
{
#pragma unroll
    for (int mf = 0; mf < 4; ++mf) {
#pragma unroll
        for (int nf = 0; nf < NF; ++nf) {
            const int gn = n0 + wn * (NF * 16) + nf * 16 + (lane & 15);
            const float bv = bias[gn];
#pragma unroll
            for (int r = 0; r < 4; ++r) {
                const int gm = m0 + wm * 64 + mf * 16 + ((lane >> 4) << 2) + r;
                const float v = clamp50(acc[mf][nf][r] + bv);
                const int b = gm >> slog;
                const int s = gm & ((1 << slog) - 1);
                const int h = gn >> 6, d = gn & 63;
                out[((((size_t)(b * NHEADS + h)) << slog) + s) * HDIM + d] = (bf16_t)v;
            }
        }
    }
}

// ---------------------------------------------------------------------------
// MERGED projection GEMM, fused A-conversion. Grid 1280, 512 thr (8 waves).
// A = q (fp32) for seg 0, kv (fp32) for segs 1/2. Bijective XCD swizzle
// lid = (bid&7)*160 + (bid>>3): 8 consecutive lids share an A m-panel on one
// XCD -> fp32 panel fetched once per XCD, L2-resident for the other 7.
// ---------------------------------------------------------------------------
__global__ __launch_bounds__(512)
void gemm_proj_all(const float* __restrict__ qf32, const float* __restrict__ kvf32,
                   const bf16_t* __restrict__ w_bf,
                   const float* __restrict__ bq, const float* __restrict__ bk,
                   const float* __restrict__ bv,
                   bf16_t* __restrict__ qh, bf16_t* __restrict__ kh,
                   bf16_t* __restrict__ vt)
{
    __shared__ __align__(16) bf16_t Smem[2 * 256 * 64];   // 64 KB (2 buffers)

    const int bid = blockIdx.x;
    const int lid = (bid & 7) * 160 + (bid >> 3);

    int seg, j;
    if (lid < 256)      { seg = 0; j = lid; }
    else if (lid < 768) { seg = 1; j = lid - 256; }
    else                { seg = 2; j = lid - 768; }
    const int m0 = (j >> 3) * 128;
    const int n0 = (j & 7) * 128;
    const float*  A    = (seg == 0) ? qf32 : kvf32;
    const bf16_t* B    = w_bf + (size_t)seg * (HIDDEN * HIDDEN);   // Wq, Wk, Wv
    const float*  bias = (seg == 0) ? bq : (seg == 1) ? bk : bv;

    const int t = threadIdx.x;
    const int wave = t >> 6, lane = t & 63;
    const int wm = wave >> 2, wn = wave & 3;

    f32x4 acc[4][2] = {};
    proj_core((const char*)A + (size_t)m0 * (HIDDEN * 4),
              (const char*)B + (size_t)n0 * (HIDDEN * 2),
              (char*)Smem, acc, wave, lane, wm, wn);

    if (seg == 0) {
        epi_head<2>(acc, bias, qh, m0, n0, 10, wm, wn, lane);
        return;
    }
    if (seg == 1) {
        epi_head<2>(acc, bias, kh, m0, n0, 11, wm, wn, lane);
        return;
    }

    // V: transpose epilogue via LDS (reuse Smem), 2 phases of 64 s-rows.
    bf16_t* Cls = Smem;                  // [64][130]
    const int dl = t >> 2;               // 0..127
    const int sh = (t & 3) << 4;         // 0,16,32,48
    const int gn = n0 + dl;
    const int h = gn >> 6, d = gn & 63;
    const int bb = m0 >> 11;
    bf16_t* dst = vt + ((size_t)((bb * NHEADS + h) * HDIM + d)) * KVLEN
                + (m0 & (KVLEN - 1)) + sh;
    __syncthreads();
#pragma unroll
    for (int ph = 0; ph < 2; ++ph) {
        if (wm == ph) {
#pragma unroll
            for (int mf = 0; mf < 4; ++mf) {
#pragma unroll
                for (int nf = 0; nf < 2; ++nf) {
                    const int dcol = wn * 32 + nf * 16 + (lane & 15);
                    const float bv2 = bias[n0 + dcol];
#pragma unroll
                    for (int r = 0; r < 4; ++r) {
                        const int srow = mf * 16 + ((lane >> 4) << 2) + r;
                        Cls[srow * 130 + dcol] = (bf16_t)clamp50(acc[mf][nf][r] + bv2);
                    }
                }
            }
        }
        __syncthreads();
#pragma unroll
        for (int j0 = 0; j0 < 16; j0 += 8) {
            bf16x8 v;
#pragma unroll
            for (int jj = 0; jj < 8; ++jj) v[jj] = Cls[(sh + j0 + jj) * 130 + dl];
            *(bf16x8*)(dst + ph * 64 + j0) = v;
        }
        __syncthreads();
    }
}

// ---------------------------------------------------------------------------
// 8-WAVE all-bf16 GEMM core (for the output projection), 128xNT, dbuf glds.
// ---------------------------------------------------------------------------
template <int NT>
__device__ __forceinline__ void stage_tile8(const char* __restrict__ Ab,
                                            const char* __restrict__ Bb,
                                            char* base, int kt, int wave, int rowl, int srcsw)
{
#pragma unroll
    for (int i = 0; i < 2; ++i) {
        const int row = i * 64 + wave * 8 + rowl;
        GLOAD16(Ab + (size_t)row * (HIDDEN * 2) + kt * 128 + srcsw,
                base + i * 8192 + wave * 1024);
    }
#pragma unroll
    for (int i = 0; i < NT / 64; ++i) {
        const int row = i * 64 + wave * 8 + rowl;
        GLOAD16(Bb + (size_t)row * (HIDDEN * 2) + kt * 128 + srcsw,
                base + 16384 + i * 8192 + wave * 1024);
    }
}

template <int NT>
__device__ __forceinline__ void gemm_core_db8(const char* __restrict__ Ab,
                                              const char* __restrict__ Bb,
                                              char* Ls,
                                              f32x4 (&acc)[4][NT / 64],
                                              int wave, int lane, int wm, int wn)
{
    constexpr int NFB = NT / 64;
    constexpr int BUF = (128 + NT) * 128;
    const int srcsw = ((lane & 7) ^ (lane >> 3)) << 4;
    const int rowl = lane >> 3;
    const int ql = lane & 15;

    stage_tile8<NT>(Ab, Bb, Ls, 0, wave, rowl, srcsw);
    __syncthreads();

    for (int kt = 0; kt < HIDDEN / 64; ++kt) {
        const int cur = kt & 1;
        if (kt < HIDDEN / 64 - 1)
            stage_tile8<NT>(Ab, Bb, Ls + (cur ^ 1) * BUF, kt + 1, wave, rowl, srcsw);
        const char* Abase = Ls + cur * BUF;
        const char* Bbase = Abase + 16384;
#pragma unroll
        for (int kc = 0; kc < 2; ++kc) {
            const int kbyte = kc * 64 + ((lane >> 4) << 4);
            bf16x8 af[4], bfr[NFB];
#pragma unroll
            for (int f2 = 0; f2 < 4; ++f2) {
                const int arow = wm * 64 + f2 * 16 + ql;
                af[f2] = *(const bf16x8*)(Abase + arow * 128 + (kbyte ^ ((arow & 7) << 4)));
            }
#pragma unroll
            for (int f2 = 0; f2 < NFB; ++f2) {
                const int brow = wn * (NT / 4) + f2 * 16 + ql;
                bfr[f2] = *(const bf16x8*)(Bbase + brow * 128 + (kbyte ^ ((brow & 7) << 4)));
            }
#pragma unroll
            for (int mf = 0; mf < 4; ++mf)
#pragma unroll
                for (int nf = 0; nf < NFB; ++nf)
                    acc[mf][nf] = __builtin_amdgcn_mfma_f32_16x16x32_bf16(af[mf], bfr[nf], acc[mf][nf], 0, 0, 0);
        }
        __syncthreads();
    }
}

// ---------------------------------------------------------------------------
// Output-projection GEMM (fp32 out [M][1024]), 128x64 tiles, 8 waves,
// dbuf core, 1D grid 512 with panel-per-XCD swizzle.
// ---------------------------------------------------------------------------
__global__ __launch_bounds__(512)
void gemm_out_kernel(const bf16_t* __restrict__ A, const bf16_t* __restrict__ B,
                     const float* __restrict__ bias, float* __restrict__ out)
{
    constexpr int NT = 64;
    __shared__ __align__(16) bf16_t Smem[2 * (128 + NT) * 64];   // 48 KB

    const int bid = blockIdx.x;
    const int lid = (bid & 7) * 64 + (bid >> 3);   // 512 = 8 x 64, bijective
    const int m0 = (lid >> 4) * 128;
    const int n0 = (lid & 15) * NT;
    const int t = threadIdx.x;
    const int wave = t >> 6, lane = t & 63;
    const int wm = wave >> 2, wn = wave & 3;

    f32x4 acc[4][1] = {};
    gemm_core_db8<NT>((const char*)A + (size_t)m0 * (HIDDEN * 2),
                      (const char*)B + (size_t)n0 * (HIDDEN * 2),
                      (char*)Smem, acc, wave, lane, wm, wn);

#pragma unroll
    for (int mf = 0; mf < 4; ++mf) {
        const int gn = n0 + wn * 16 + (lane & 15);
        const float bv = bias[gn];
#pragma unroll
        for (int r = 0; r < 4; ++r) {
            const int gm = m0 + wm * 64 + mf * 16 + ((lane >> 4) << 2) + r;
            out[(size_t)gm * HIDDEN + gn] = clamp50(acc[mf][0][r] + bv);
        }
    }
}

// ---------------------------------------------------------------------------
// Flash attention v3: fixed-max softmax, swapped QK^T (P in registers),
// key-half split across wave pairs, 8 waves / 512 threads, XCD-grouped.
// ---------------------------------------------------------------------------
__global__ __launch_bounds__(512)
void attn_fwd_kernel(const bf16_t* __restrict__ Qh, const bf16_t* __restrict__ Kh,
                     const bf16_t* __restrict__ Vt, const float* __restrict__ maskadd,
                     bf16_t* __restrict__ aout)
{
    __shared__ __align__(16) bf16_t Kls[2][64 * 64];   // 16 KB
    __shared__ __align__(16) bf16_t Vls[2][64 * 64];   // 16 KB
    __shared__ __align__(16) float Cbuf[4][32 * 64];   // 32 KB combine
    __shared__ float Lbuf[4][2][16];

    const int f = blockIdx.x;
    const int o = (f & 7) * 64 + (f >> 3);
    const int qt = o & 7;
    const int bh = o >> 3;
    const int b = bh >> 4, h = bh & 15;
    const int t = threadIdx.x, wave = t >> 6, lane = t & 63;
    const int wq = wave & 3;
    const int wg = wave >> 2;
    const int g = lane >> 4, ql = lane & 15;

    const int qbase = qt * 128 + wq * 32;
    bf16x8 qf[2][2];
#pragma unroll
    for (int qq = 0; qq < 2; ++qq) {
        const bf16_t* qp = Qh + ((size_t)bh * QLEN + qbase + qq * 16 + ql) * HDIM + (g << 3);
        qf[qq][0] = *(const bf16x8*)qp;
        qf[qq][1] = *(const bf16x8*)(qp + 32);
    }

    f32x4 oacc[2][4] = {};
    float lsum[2] = {0.f, 0.f};

    const int srcsw = ((lane & 7) ^ (lane >> 3)) << 4;
    const int R = wave * 8 + (lane >> 3);
    const int kap = 32 * (R >> 5) + 8 * ((R >> 2) & 3) + 4 * ((R >> 4) & 1) + (R & 3);

    const char* Kb = (const char*)(Kh + (size_t)bh * KVLEN * HDIM);
    const char* Vb = (const char*)(Vt + (size_t)bh * HDIM * KVLEN);
    const float* mrow = maskadd + b * KVLEN + wg * 32 + g * 8;
    const int kb0 = g << 4;
    const int vcol = wg * 64 + kb0;

    GLOAD16(Kb + (size_t)kap * 128 + srcsw, (char*)&Kls[0][0] + wave * 1024);
    GLOAD16(Vb + (size_t)R * (KVLEN * 2) + srcsw, (char*)&Vls[0][0] + wave * 1024);
    f32x4 madd_c[2], madd_n[2];
    madd_c[0] = *(const f32x4*)(mrow);
    madd_c[1] = *(const f32x4*)(mrow + 4);
    __syncthreads();

    for (int kt = 0; kt < KVLEN / 64; ++kt) {
        const int cur = kt & 1;
        if (kt < KVLEN / 64 - 1) {
            const size_t ko = (size_t)(kt + 1) * 8192;
            GLOAD16(Kb + ko + (size_t)kap * 128 + srcsw,
                    (char*)&Kls[cur ^ 1][0] + wave * 1024);
            GLOAD16(Vb + (size_t)R * (KVLEN * 2) + (size_t)(kt + 1) * 128 + srcsw,
                    (char*)&Vls[cur ^ 1][0] + wave * 1024);
            madd_n[0] = *(const f32x4*)(mrow + (kt + 1) * 64);
            madd_n[1] = *(const f32x4*)(mrow + (kt + 1) * 64 + 4);
        }
        const char* Kc = (const char*)&Kls[cur][0];
        const char* Vc = (const char*)&Vls[cur][0];

        // ---- S^T = K Q^T over this wave's 32-key half
        f32x4 sacc[2][2] = {};
        __builtin_amdgcn_s_setprio(1);
#pragma unroll
        for (int kb = 0; kb < 2; ++kb) {
            const int key = wg * 32 + kb * 16 + ql;
            const int rowoff = key * 128;
            const int sw = (key & 7) << 4;
            const bf16x8 kf0 = *(const bf16x8*)(Kc + rowoff + ((kb0)      ^ sw));
            const bf16x8 kf1 = *(const bf16x8*)(Kc + rowoff + ((kb0 + 64) ^ sw));
#pragma unroll
            for (int qq = 0; qq < 2; ++qq) {
                sacc[qq][kb] = __builtin_amdgcn_mfma_f32_16x16x32_bf16(kf0, qf[qq][0], sacc[qq][kb], 0, 0, 0);
                sacc[qq][kb] = __builtin_amdgcn_mfma_f32_16x16x32_bf16(kf1, qf[qq][1], sacc[qq][kb], 0, 0, 0);
            }
        }
        __builtin_amdgcn_s_setprio(0);

        // ---- softmax weights in-register + pack to PV A-fragment
        bf16x8 pa[2];
#pragma unroll
        for (int qq = 0; qq < 2; ++qq) {
            float pv[2][4];
            float ls = 0.f;
#pragma unroll
            for (int kb = 0; kb < 2; ++kb) {
#pragma unroll
                for (int r = 0; r < 4; ++r) {
                    pv[kb][r] = __builtin_amdgcn_exp2f(
                        __builtin_fmaf(sacc[qq][kb][r], C_SCALE, madd_c[kb][r]));
                    ls += pv[kb][r];
                }
            }
            lsum[qq] += ls;
#pragma unroll
            for (int r = 0; r < 4; ++r) {
                pa[qq][r]     = (bf16_t)pv[0][r];
                pa[qq][4 + r] = (bf16_t)pv[1][r];
            }
        }

        // ---- O += P V over this key half
        __builtin_amdgcn_s_setprio(1);
#pragma unroll
        for (int db = 0; db < 4; ++db) {
            const int vrow = db * 16 + ql;
            const int vsw = (vrow & 7) << 4;
            const bf16x8 vf = *(const bf16x8*)(Vc + vrow * 128 + (vcol ^ vsw));
#pragma unroll
            for (int qq = 0; qq < 2; ++qq)
                oacc[qq][db] = __builtin_amdgcn_mfma_f32_16x16x32_bf16(pa[qq], vf, oacc[qq][db], 0, 0, 0);
        }
        __builtin_amdgcn_s_setprio(0);

        __syncthreads();
#pragma unroll
        for (int kb = 0; kb < 2; ++kb) madd_c[kb] = madd_n[kb];
    }

    // ---- combine key-halves: wg=1 publishes partials, wg=0 merges+stores
#pragma unroll
    for (int qq = 0; qq < 2; ++qq) {
        float l = lsum[qq];
        l += __shfl_xor(l, 16);
        l += __shfl_xor(l, 32);
        lsum[qq] = l;
    }
    const int rbase = g << 2;
    if (wg == 1) {
#pragma unroll
        for (int qq = 0; qq < 2; ++qq) {
#pragma unroll
            for (int db = 0; db < 4; ++db)
#pragma unroll
                for (int r = 0; r < 4; ++r)
                    Cbuf[wq][(qq * 16 + rbase + r) * 64 + db * 16 + ql] = oacc[qq][db][r];
            if (lane < 16) Lbuf[wq][qq][lane] = lsum[qq];
        }
    }
    __syncthreads();
    if (wg == 0) {
#pragma unroll
        for (int qq = 0; qq < 2; ++qq) {
            const float Lq = lsum[qq] + Lbuf[wq][qq][ql];
#pragma unroll
            for (int r = 0; r < 4; ++r) {
                const float Lr = __shfl(Lq, rbase + r);
                const float inv = 1.0f / Lr;
                const int qrow = qbase + qq * 16 + rbase + r;
                bf16_t* orow = aout + ((size_t)(b * QLEN + qrow)) * HIDDEN + h * HDIM;
#pragma unroll
                for (int db = 0; db < 4; ++db) {
                    const float add = Cbuf[wq][(qq * 16 + rbase + r) * 64 + db * 16 + ql];
                    orow[db * 16 + ql] = (bf16_t)((oacc[qq][db][r] + add) * inv);
                }
            }
        }
    }
}

// ---------------------------------------------------------------------------
extern "C" void kernel_launch(void* const* d_in, const int* in_sizes, int n_in,
                              void* d_out, int out_size, void* d_ws, size_t ws_size,
                              hipStream_t stream) {
    (void)in_sizes; (void)n_in; (void)out_size; (void)ws_size;
    const float* q   = (const float*)d_in[0];
    const float* kv  = (const float*)d_in[1];
    const void*  msk = d_in[2];
    const float* Wq  = (const float*)d_in[3];
    const float* bq  = (const float*)d_in[4];
    const float* Wk  = (const float*)d_in[5];
    const float* bk  = (const float*)d_in[6];
    const float* Wv  = (const float*)d_in[7];
    const float* bv  = (const float*)d_in[8];
    const float* Wo  = (const float*)d_in[9];
    const float* bo  = (const float*)d_in[10];

    char* ws = (char*)d_ws;
    const size_t MB = 1024 * 1024;
    float*  maskadd = (float*)ws;                              // 32 KB
    bf16_t* w_bf  = (bf16_t*)(ws + 32 * 1024);                 // 8 MB (4 weights)
    bf16_t* aout  = (bf16_t*)(ws + 32 * 1024 + 8  * MB);       // 8 MB
    bf16_t* qh    = (bf16_t*)(ws + 32 * 1024 + 32 * MB);       // 8 MB
    bf16_t* kh    = (bf16_t*)(ws + 32 * 1024 + 40 * MB);       // 16 MB
    bf16_t* vt    = (bf16_t*)(ws + 32 * 1024 + 56 * MB);       // 16 MB -> end 72 MB

    bf16_t* wo_bf = w_bf + (size_t)3 * HIDDEN * HIDDEN;

    cvt_w_mask_kernel<<<dim3(NWCVT + 4), 256, 0, stream>>>(
        Wq, Wk, Wv, Wo, w_bf, msk, maskadd);

    gemm_proj_all<<<dim3(1280), 512, 0, stream>>>(
        q, kv, w_bf, bq, bk, bv, qh, kh, vt);

    attn_fwd_kernel<<<dim3(512), 512, 0, stream>>>(qh, kh, vt, maskadd, aout);

    gemm_out_kernel<<<dim3(512), 512, 0, stream>>>(aout, wo_bf, bo, (float*)d_out);
}

// Round 12
// 136.924 us; speedup vs baseline: 1.5245x; 1.0227x over previous
//
#include <hip/hip_runtime.h>
#include <hip/hip_bf16.h>
#include <stdint.h>
#include <math.h>

#define HIDDEN 1024
#define NHEADS 16
#define HDIM   64
#define BSZ    4
#define QLEN   1024
#define KVLEN  2048

typedef __bf16 bf16_t;
typedef __bf16 bf16x8 __attribute__((ext_vector_type(8)));
typedef __bf16 bf16x4 __attribute__((ext_vector_type(4)));
typedef float  f32x4  __attribute__((ext_vector_type(4)));

// fixed-max softmax: p = exp2( s_raw*C_SCALE + madd ).
#define C_SCALE 0.18033688f     /* 0.125 * log2(e) */
#define C_FMADD (-43.2808512f)  /* -30 * log2(e) */

#define GLOAD16(g, l) \
    __builtin_amdgcn_global_load_lds((const __attribute__((address_space(1))) void*)(g), \
                                     (__attribute__((address_space(3))) void*)(l), 16, 0, 0)

__device__ __forceinline__ float clamp50(float v) {
    return fminf(fmaxf(v, -50.f), 50.f);
}

// ---------------------------------------------------------------------------
// Converts the 4 weights (fp32 -> bf16) AND the mask (dtype auto-detect ->
// additive exp2-domain constant). q/kv conversion is fused into proj staging.
// ---------------------------------------------------------------------------
#define NW4  ((HIDDEN * HIDDEN) / 4)        /* 262144 */
#define NWCVT (4 * NW4 / 256)               /* 4096 blocks */

__global__ void cvt_w_mask_kernel(const float* __restrict__ W0, const float* __restrict__ W1,
                                  const float* __restrict__ W2, const float* __restrict__ W3,
                                  bf16_t* __restrict__ w_bf,
                                  const void* __restrict__ msk, float* __restrict__ maskadd) {
    if (blockIdx.x >= NWCVT) {
        __shared__ int s_float, s_multi;
        const int t = threadIdx.x;
        if (t == 0) { s_float = 0; s_multi = 0; }
        __syncthreads();
        const uint32_t* w = (const uint32_t*)msk;
        int cf = 0, cm = 0;
        for (int i = t; i < 2048; i += 256) {
            uint32_t v = w[i];
            if (v == 0x3F800000u) cf++;
            else if (v & 0xFFFFFF00u) cm++;
        }
        if (cf) atomicAdd(&s_float, cf);
        if (cm) atomicAdd(&s_multi, cm);
        __syncthreads();
        const int mode = (s_float > 0) ? 2 : ((s_multi > 0) ? 0 : 1);
        const int base = (blockIdx.x - NWCVT) * 2048;
        for (int i = base + t; i < base + 2048; i += 256) {
            bool m;
            if (mode == 2)      m = ((const float*)msk)[i] != 0.0f;
            else if (mode == 1) m = ((const int*)msk)[i] != 0;
            else                m = ((const unsigned char*)msk)[i] != 0;
            maskadd[i] = m ? (-100000.0f + C_FMADD) : C_FMADD;
        }
        return;
    }
    const int i = blockIdx.x * blockDim.x + threadIdx.x;
    const int ws = i >> 18, off = i & (NW4 - 1);
    const float* W = (ws == 0) ? W0 : (ws == 1) ? W1 : (ws == 2) ? W2 : W3;
    const float4 v = ((const float4*)W)[off];
    bf16x4 o;
    o[0] = (bf16_t)clamp50(v.x); o[1] = (bf16_t)clamp50(v.y);
    o[2] = (bf16_t)clamp50(v.z); o[3] = (bf16_t)clamp50(v.w);
    ((bf16x4*)w_bf)[(size_t)ws * NW4 + off] = o;
}

// ---------------------------------------------------------------------------
// Projection GEMM core, 8 waves, 128x128, BK=64, dbuf LDS, 2-DEEP A-pipeline:
//   iter k: ds_write A(k+1) from regs loaded at iter k-1 (already drained by
//   the previous barrier -> ZERO vmcnt wait), issue B glds (k+1), issue A
//   fp32 loads (k+2) into the other named reg set, compute tile k, barrier.
// Role swap is compile-time (two macro bodies per unrolled step).
// Source-side swizzle: LDS[row][c] = G[row][c^(row&7)] (fp32 chunk = 32B).
// ---------------------------------------------------------------------------
#define PROJ_CVT_WRITE(dstbuf, wr0, wr1) \
    _Pragma("unroll") for (int i_ = 0; i_ < 2; ++i_) { \
        bf16x8 o_; \
        o_[0] = (bf16_t)clamp50(wr0[i_].x); o_[1] = (bf16_t)clamp50(wr0[i_].y); \
        o_[2] = (bf16_t)clamp50(wr0[i_].z); o_[3] = (bf16_t)clamp50(wr0[i_].w); \
        o_[4] = (bf16_t)clamp50(wr1[i_].x); o_[5] = (bf16_t)clamp50(wr1[i_].y); \
        o_[6] = (bf16_t)clamp50(wr1[i_].z); o_[7] = (bf16_t)clamp50(wr1[i_].w); \
        *(bf16x8*)((dstbuf) + i_ * 8192 + wave * 1024 + lane * 16) = o_; \
    }

#define PROJ_BODY(kt, wr0, wr1, ld0, ld1) do { \
    const int cur_ = (kt) & 1; \
    char* nbuf_ = Ls + (cur_ ^ 1) * BUF; \
    if ((kt) < 15) { \
        PROJ_CVT_WRITE(nbuf_, wr0, wr1) \
        _Pragma("unroll") for (int i_ = 0; i_ < 2; ++i_) { \
            const int row_ = i_ * 64 + wave * 8 + rowl; \
            GLOAD16(Bb + (size_t)row_ * (HIDDEN * 2) + ((kt) + 1) * 128 + srcsw, \
                    nbuf_ + 16384 + i_ * 8192 + wave * 1024); \
        } \
    } \
    if ((kt) < 14) { \
        _Pragma("unroll") for (int i_ = 0; i_ < 2; ++i_) { \
            const int row_ = i_ * 64 + wave * 8 + rowl; \
            const float4* p_ = (const float4*)(Ab + (size_t)row_ * (HIDDEN * 4) \
                                               + ((kt) + 2) * 256 + (srcsw << 1)); \
            ld0[i_] = p_[0]; ld1[i_] = p_[1]; \
        } \
    } \
    const char* Abase_ = Ls + cur_ * BUF; \
    const char* Bbase_ = Abase_ + 16384; \
    _Pragma("unroll") for (int kc_ = 0; kc_ < 2; ++kc_) { \
        const int kbyte_ = kc_ * 64 + ((lane >> 4) << 4); \
        bf16x8 af_[4], bfr_[2]; \
        _Pragma("unroll") for (int f_ = 0; f_ < 4; ++f_) { \
            const int arow_ = wm * 64 + f_ * 16 + ql; \
            af_[f_] = *(const bf16x8*)(Abase_ + arow_ * 128 + (kbyte_ ^ ((arow_ & 7) << 4))); \
        } \
        _Pragma("unroll") for (int f_ = 0; f_ < 2; ++f_) { \
            const int brow_ = wn * 32 + f_ * 16 + ql; \
            bfr_[f_] = *(const bf16x8*)(Bbase_ + brow_ * 128 + (kbyte_ ^ ((brow_ & 7) << 4))); \
        } \
        _Pragma("unroll") for (int mf_ = 0; mf_ < 4; ++mf_) \
            _Pragma("unroll") for (int nf_ = 0; nf_ < 2; ++nf_) \
                acc[mf_][nf_] = __builtin_amdgcn_mfma_f32_16x16x32_bf16(af_[mf_], bfr_[nf_], acc[mf_][nf_], 0, 0, 0); \
    } \
    __syncthreads(); \
} while (0)

__device__ __forceinline__ void proj_core(const char* __restrict__ Ab,   // fp32
                                          const char* __restrict__ Bb,   // bf16
                                          char* Ls, f32x4 (&acc)[4][2],
                                          int wave, int lane, int wm, int wn)
{
    constexpr int BUF = 256 * 128;   // 32 KB per buffer (A 16K + B 16K)
    const int srcsw = ((lane & 7) ^ (lane >> 3)) << 4;
    const int rowl = lane >> 3;
    const int ql = lane & 15;

    float4 e0[2], e1[2], f0[2], f1[2];

    // ---- prologue: tile0 A -> regs -> buf0; tile0 B glds; tile1 A -> e-regs
#pragma unroll
    for (int i = 0; i < 2; ++i) {
        const int row = i * 64 + wave * 8 + rowl;
        const float4* p = (const float4*)(Ab + (size_t)row * (HIDDEN * 4) + (srcsw << 1));
        e0[i] = p[0]; e1[i] = p[1];
        GLOAD16(Bb + (size_t)row * (HIDDEN * 2) + srcsw,
                Ls + 16384 + i * 8192 + wave * 1024);
    }
    PROJ_CVT_WRITE(Ls, e0, e1)
#pragma unroll
    for (int i = 0; i < 2; ++i) {
        const int row = i * 64 + wave * 8 + rowl;
        const float4* p = (const float4*)(Ab + (size_t)row * (HIDDEN * 4) + 256 + (srcsw << 1));
        e0[i] = p[0]; e1[i] = p[1];
    }
    __syncthreads();

    for (int kt2 = 0; kt2 < 8; ++kt2) {
        PROJ_BODY(2 * kt2,     e0, e1, f0, f1);
        PROJ_BODY(2 * kt2 + 1, f0, f1, e0, e1);
    }
}

// EPI epilogue: bf16 out in per-head layout [(b*16+h)][s][d], seqlen 1<<slog
template <int NF>
__device__ __forceinline__ void epi_head(f32x4 (&acc)[4][NF], const float* bias,
                                         bf16_t* out, int m0, int n0, int slog,
                                         int wm, int wn, int lane)
{
#pragma unroll
    for (int mf = 0; mf < 4; ++mf) {
#pragma unroll
        for (int nf = 0; nf < NF; ++nf) {
            const int gn = n0 + wn * (NF * 16) + nf * 16 + (lane & 15);
            const float bv = bias[gn];
#pragma unroll
            for (int r = 0; r < 4; ++r) {
                const int gm = m0 + wm * 64 + mf * 16 + ((lane >> 4) << 2) + r;
                const float v = clamp50(acc[mf][nf][r] + bv);
                const int b = gm >> slog;
                const int s = gm & ((1 << slog) - 1);
                const int h = gn >> 6, d = gn & 63;
                out[((((size_t)(b * NHEADS + h)) << slog) + s) * HDIM + d] = (bf16_t)v;
            }
        }
    }
}

// ---------------------------------------------------------------------------
// MERGED projection GEMM, fused A-conversion. Grid 1280, 512 thr (8 waves).
// Bijective XCD swizzle lid = (bid&7)*160 + (bid>>3): 8 consecutive lids share
// an A m-panel on one XCD -> fp32 panel L2-resident after first fetch.
// ---------------------------------------------------------------------------
__global__ __launch_bounds__(512)
void gemm_proj_all(const float* __restrict__ qf32, const float* __restrict__ kvf32,
                   const bf16_t* __restrict__ w_bf,
                   const float* __restrict__ bq, const float* __restrict__ bk,
                   const float* __restrict__ bv,
                   bf16_t* __restrict__ qh, bf16_t* __restrict__ kh,
                   bf16_t* __restrict__ vt)
{
    __shared__ __align__(16) bf16_t Smem[2 * 256 * 64];   // 64 KB (2 buffers)

    const int bid = blockIdx.x;
    const int lid = (bid & 7) * 160 + (bid >> 3);

    int seg, j;
    if (lid < 256)      { seg = 0; j = lid; }
    else if (lid < 768) { seg = 1; j = lid - 256; }
    else                { seg = 2; j = lid - 768; }
    const int m0 = (j >> 3) * 128;
    const int n0 = (j & 7) * 128;
    const float*  A    = (seg == 0) ? qf32 : kvf32;
    const bf16_t* B    = w_bf + (size_t)seg * (HIDDEN * HIDDEN);   // Wq, Wk, Wv
    const float*  bias = (seg == 0) ? bq : (seg == 1) ? bk : bv;

    const int t = threadIdx.x;
    const int wave = t >> 6, lane = t & 63;
    const int wm = wave >> 2, wn = wave & 3;

    f32x4 acc[4][2] = {};
    proj_core((const char*)A + (size_t)m0 * (HIDDEN * 4),
              (const char*)B + (size_t)n0 * (HIDDEN * 2),
              (char*)Smem, acc, wave, lane, wm, wn);

    if (seg == 0) {
        epi_head<2>(acc, bias, qh, m0, n0, 10, wm, wn, lane);
        return;
    }
    if (seg == 1) {
        epi_head<2>(acc, bias, kh, m0, n0, 11, wm, wn, lane);
        return;
    }

    // V: transpose epilogue via LDS (reuse Smem), 2 phases of 64 s-rows.
    bf16_t* Cls = Smem;                  // [64][130]
    const int dl = t >> 2;               // 0..127
    const int sh = (t & 3) << 4;         // 0,16,32,48
    const int gn = n0 + dl;
    const int h = gn >> 6, d = gn & 63;
    const int bb = m0 >> 11;
    bf16_t* dst = vt + ((size_t)((bb * NHEADS + h) * HDIM + d)) * KVLEN
                + (m0 & (KVLEN - 1)) + sh;
    __syncthreads();
#pragma unroll
    for (int ph = 0; ph < 2; ++ph) {
        if (wm == ph) {
#pragma unroll
            for (int mf = 0; mf < 4; ++mf) {
#pragma unroll
                for (int nf = 0; nf < 2; ++nf) {
                    const int dcol = wn * 32 + nf * 16 + (lane & 15);
                    const float bv2 = bias[n0 + dcol];
#pragma unroll
                    for (int r = 0; r < 4; ++r) {
                        const int srow = mf * 16 + ((lane >> 4) << 2) + r;
                        Cls[srow * 130 + dcol] = (bf16_t)clamp50(acc[mf][nf][r] + bv2);
                    }
                }
            }
        }
        __syncthreads();
#pragma unroll
        for (int j0 = 0; j0 < 16; j0 += 8) {
            bf16x8 v;
#pragma unroll
            for (int jj = 0; jj < 8; ++jj) v[jj] = Cls[(sh + j0 + jj) * 130 + dl];
            *(bf16x8*)(dst + ph * 64 + j0) = v;
        }
        __syncthreads();
    }
}

// ---------------------------------------------------------------------------
// 8-WAVE all-bf16 GEMM core (output projection), 128xNT, dbuf glds.
// ---------------------------------------------------------------------------
template <int NT>
__device__ __forceinline__ void stage_tile8(const char* __restrict__ Ab,
                                            const char* __restrict__ Bb,
                                            char* base, int kt, int wave, int rowl, int srcsw)
{
#pragma unroll
    for (int i = 0; i < 2; ++i) {
        const int row = i * 64 + wave * 8 + rowl;
        GLOAD16(Ab + (size_t)row * (HIDDEN * 2) + kt * 128 + srcsw,
                base + i * 8192 + wave * 1024);
    }
#pragma unroll
    for (int i = 0; i < NT / 64; ++i) {
        const int row = i * 64 + wave * 8 + rowl;
        GLOAD16(Bb + (size_t)row * (HIDDEN * 2) + kt * 128 + srcsw,
                base + 16384 + i * 8192 + wave * 1024);
    }
}

template <int NT>
__device__ __forceinline__ void gemm_core_db8(const char* __restrict__ Ab,
                                              const char* __restrict__ Bb,
                                              char* Ls,
                                              f32x4 (&acc)[4][NT / 64],
                                              int wave, int lane, int wm, int wn)
{
    constexpr int NFB = NT / 64;
    constexpr int BUF = (128 + NT) * 128;
    const int srcsw = ((lane & 7) ^ (lane >> 3)) << 4;
    const int rowl = lane >> 3;
    const int ql = lane & 15;

    stage_tile8<NT>(Ab, Bb, Ls, 0, wave, rowl, srcsw);
    __syncthreads();

    for (int kt = 0; kt < HIDDEN / 64; ++kt) {
        const int cur = kt & 1;
        if (kt < HIDDEN / 64 - 1)
            stage_tile8<NT>(Ab, Bb, Ls + (cur ^ 1) * BUF, kt + 1, wave, rowl, srcsw);
        const char* Abase = Ls + cur * BUF;
        const char* Bbase = Abase + 16384;
#pragma unroll
        for (int kc = 0; kc < 2; ++kc) {
            const int kbyte = kc * 64 + ((lane >> 4) << 4);
            bf16x8 af[4], bfr[NFB];
#pragma unroll
            for (int f2 = 0; f2 < 4; ++f2) {
                const int arow = wm * 64 + f2 * 16 + ql;
                af[f2] = *(const bf16x8*)(Abase + arow * 128 + (kbyte ^ ((arow & 7) << 4)));
            }
#pragma unroll
            for (int f2 = 0; f2 < NFB; ++f2) {
                const int brow = wn * (NT / 4) + f2 * 16 + ql;
                bfr[f2] = *(const bf16x8*)(Bbase + brow * 128 + (kbyte ^ ((brow & 7) << 4)));
            }
#pragma unroll
            for (int mf = 0; mf < 4; ++mf)
#pragma unroll
                for (int nf = 0; nf < NFB; ++nf)
                    acc[mf][nf] = __builtin_amdgcn_mfma_f32_16x16x32_bf16(af[mf], bfr[nf], acc[mf][nf], 0, 0, 0);
        }
        __syncthreads();
    }
}

// ---------------------------------------------------------------------------
// Output-projection GEMM (fp32 out [M][1024]), 128x64 tiles, 8 waves,
// dbuf core, 1D grid 512 with panel-per-XCD swizzle.
// ---------------------------------------------------------------------------
__global__ __launch_bounds__(512)
void gemm_out_kernel(const bf16_t* __restrict__ A, const bf16_t* __restrict__ B,
                     const float* __restrict__ bias, float* __restrict__ out)
{
    constexpr int NT = 64;
    __shared__ __align__(16) bf16_t Smem[2 * (128 + NT) * 64];   // 48 KB

    const int bid = blockIdx.x;
    const int lid = (bid & 7) * 64 + (bid >> 3);   // 512 = 8 x 64, bijective
    const int m0 = (lid >> 4) * 128;
    const int n0 = (lid & 15) * NT;
    const int t = threadIdx.x;
    const int wave = t >> 6, lane = t & 63;
    const int wm = wave >> 2, wn = wave & 3;

    f32x4 acc[4][1] = {};
    gemm_core_db8<NT>((const char*)A + (size_t)m0 * (HIDDEN * 2),
                      (const char*)B + (size_t)n0 * (HIDDEN * 2),
                      (char*)Smem, acc, wave, lane, wm, wn);

#pragma unroll
    for (int mf = 0; mf < 4; ++mf) {
        const int gn = n0 + wn * 16 + (lane & 15);
        const float bv = bias[gn];
#pragma unroll
        for (int r = 0; r < 4; ++r) {
            const int gm = m0 + wm * 64 + mf * 16 + ((lane >> 4) << 2) + r;
            out[(size_t)gm * HIDDEN + gn] = clamp50(acc[mf][0][r] + bv);
        }
    }
}

// ---------------------------------------------------------------------------
// Flash attention v3: fixed-max softmax, swapped QK^T (P in registers),
// key-half split across wave pairs, 8 waves / 512 threads, XCD-grouped.
// ---------------------------------------------------------------------------
__global__ __launch_bounds__(512)
void attn_fwd_kernel(const bf16_t* __restrict__ Qh, const bf16_t* __restrict__ Kh,
                     const bf16_t* __restrict__ Vt, const float* __restrict__ maskadd,
                     bf16_t* __restrict__ aout)
{
    __shared__ __align__(16) bf16_t Kls[2][64 * 64];   // 16 KB
    __shared__ __align__(16) bf16_t Vls[2][64 * 64];   // 16 KB
    __shared__ __align__(16) float Cbuf[4][32 * 64];   // 32 KB combine
    __shared__ float Lbuf[4][2][16];

    const int f = blockIdx.x;
    const int o = (f & 7) * 64 + (f >> 3);
    const int qt = o & 7;
    const int bh = o >> 3;
    const int b = bh >> 4, h = bh & 15;
    const int t = threadIdx.x, wave = t >> 6, lane = t & 63;
    const int wq = wave & 3;
    const int wg = wave >> 2;
    const int g = lane >> 4, ql = lane & 15;

    const int qbase = qt * 128 + wq * 32;
    bf16x8 qf[2][2];
#pragma unroll
    for (int qq = 0; qq < 2; ++qq) {
        const bf16_t* qp = Qh + ((size_t)bh * QLEN + qbase + qq * 16 + ql) * HDIM + (g << 3);
        qf[qq][0] = *(const bf16x8*)qp;
        qf[qq][1] = *(const bf16x8*)(qp + 32);
    }

    f32x4 oacc[2][4] = {};
    float lsum[2] = {0.f, 0.f};

    const int srcsw = ((lane & 7) ^ (lane >> 3)) << 4;
    const int R = wave * 8 + (lane >> 3);
    const int kap = 32 * (R >> 5) + 8 * ((R >> 2) & 3) + 4 * ((R >> 4) & 1) + (R & 3);

    const char* Kb = (const char*)(Kh + (size_t)bh * KVLEN * HDIM);
    const char* Vb = (const char*)(Vt + (size_t)bh * HDIM * KVLEN);
    const float* mrow = maskadd + b * KVLEN + wg * 32 + g * 8;
    const int kb0 = g << 4;
    const int vcol = wg * 64 + kb0;

    GLOAD16(Kb + (size_t)kap * 128 + srcsw, (char*)&Kls[0][0] + wave * 1024);
    GLOAD16(Vb + (size_t)R * (KVLEN * 2) + srcsw, (char*)&Vls[0][0] + wave * 1024);
    f32x4 madd_c[2], madd_n[2];
    madd_c[0] = *(const f32x4*)(mrow);
    madd_c[1] = *(const f32x4*)(mrow + 4);
    __syncthreads();

    for (int kt = 0; kt < KVLEN / 64; ++kt) {
        const int cur = kt & 1;
        if (kt < KVLEN / 64 - 1) {
            const size_t ko = (size_t)(kt + 1) * 8192;
            GLOAD16(Kb + ko + (size_t)kap * 128 + srcsw,
                    (char*)&Kls[cur ^ 1][0] + wave * 1024);
            GLOAD16(Vb + (size_t)R * (KVLEN * 2) + (size_t)(kt + 1) * 128 + srcsw,
                    (char*)&Vls[cur ^ 1][0] + wave * 1024);
            madd_n[0] = *(const f32x4*)(mrow + (kt + 1) * 64);
            madd_n[1] = *(const f32x4*)(mrow + (kt + 1) * 64 + 4);
        }
        const char* Kc = (const char*)&Kls[cur][0];
        const char* Vc = (const char*)&Vls[cur][0];

        // ---- S^T = K Q^T over this wave's 32-key half
        f32x4 sacc[2][2] = {};
        __builtin_amdgcn_s_setprio(1);
#pragma unroll
        for (int kb = 0; kb < 2; ++kb) {
            const int key = wg * 32 + kb * 16 + ql;
            const int rowoff = key * 128;
            const int sw = (key & 7) << 4;
            const bf16x8 kf0 = *(const bf16x8*)(Kc + rowoff + ((kb0)      ^ sw));
            const bf16x8 kf1 = *(const bf16x8*)(Kc + rowoff + ((kb0 + 64) ^ sw));
#pragma unroll
            for (int qq = 0; qq < 2; ++qq) {
                sacc[qq][kb] = __builtin_amdgcn_mfma_f32_16x16x32_bf16(kf0, qf[qq][0], sacc[qq][kb], 0, 0, 0);
                sacc[qq][kb] = __builtin_amdgcn_mfma_f32_16x16x32_bf16(kf1, qf[qq][1], sacc[qq][kb], 0, 0, 0);
            }
        }
        __builtin_amdgcn_s_setprio(0);

        // ---- softmax weights in-register + pack to PV A-fragment
        bf16x8 pa[2];
#pragma unroll
        for (int qq = 0; qq < 2; ++qq) {
            float pv[2][4];
            float ls = 0.f;
#pragma unroll
            for (int kb = 0; kb < 2; ++kb) {
#pragma unroll
                for (int r = 0; r < 4; ++r) {
                    pv[kb][r] = __builtin_amdgcn_exp2f(
                        __builtin_fmaf(sacc[qq][kb][r], C_SCALE, madd_c[kb][r]));
                    ls += pv[kb][r];
                }
            }
            lsum[qq] += ls;
#pragma unroll
            for (int r = 0; r < 4; ++r) {
                pa[qq][r]     = (bf16_t)pv[0][r];
                pa[qq][4 + r] = (bf16_t)pv[1][r];
            }
        }

        // ---- O += P V over this key half
        __builtin_amdgcn_s_setprio(1);
#pragma unroll
        for (int db = 0; db < 4; ++db) {
            const int vrow = db * 16 + ql;
            const int vsw = (vrow & 7) << 4;
            const bf16x8 vf = *(const bf16x8*)(Vc + vrow * 128 + (vcol ^ vsw));
#pragma unroll
            for (int qq = 0; qq < 2; ++qq)
                oacc[qq][db] = __builtin_amdgcn_mfma_f32_16x16x32_bf16(pa[qq], vf, oacc[qq][db], 0, 0, 0);
        }
        __builtin_amdgcn_s_setprio(0);

        __syncthreads();
#pragma unroll
        for (int kb = 0; kb < 2; ++kb) madd_c[kb] = madd_n[kb];
    }

    // ---- combine key-halves: wg=1 publishes partials, wg=0 merges+stores
#pragma unroll
    for (int qq = 0; qq < 2; ++qq) {
        float l = lsum[qq];
        l += __shfl_xor(l, 16);
        l += __shfl_xor(l, 32);
        lsum[qq] = l;
    }
    const int rbase = g << 2;
    if (wg == 1) {
#pragma unroll
        for (int qq = 0; qq < 2; ++qq) {
#pragma unroll
            for (int db = 0; db < 4; ++db)
#pragma unroll
                for (int r = 0; r < 4; ++r)
                    Cbuf[wq][(qq * 16 + rbase + r) * 64 + db * 16 + ql] = oacc[qq][db][r];
            if (lane < 16) Lbuf[wq][qq][lane] = lsum[qq];
        }
    }
    __syncthreads();
    if (wg == 0) {
#pragma unroll
        for (int qq = 0; qq < 2; ++qq) {
            const float Lq = lsum[qq] + Lbuf[wq][qq][ql];
#pragma unroll
            for (int r = 0; r < 4; ++r) {
                const float Lr = __shfl(Lq, rbase + r);
                const float inv = 1.0f / Lr;
                const int qrow = qbase + qq * 16 + rbase + r;
                bf16_t* orow = aout + ((size_t)(b * QLEN + qrow)) * HIDDEN + h * HDIM;
#pragma unroll
                for (int db = 0; db < 4; ++db) {
                    const float add = Cbuf[wq][(qq * 16 + rbase + r) * 64 + db * 16 + ql];
                    orow[db * 16 + ql] = (bf16_t)((oacc[qq][db][r] + add) * inv);
                }
            }
        }
    }
}

// ---------------------------------------------------------------------------
extern "C" void kernel_launch(void* const* d_in, const int* in_sizes, int n_in,
                              void* d_out, int out_size, void* d_ws, size_t ws_size,
                              hipStream_t stream) {
    (void)in_sizes; (void)n_in; (void)out_size; (void)ws_size;
    const float* q   = (const float*)d_in[0];
    const float* kv  = (const float*)d_in[1];
    const void*  msk = d_in[2];
    const float* Wq  = (const float*)d_in[3];
    const float* bq  = (const float*)d_in[4];
    const float* Wk  = (const float*)d_in[5];
    const float* bk  = (const float*)d_in[6];
    const float* Wv  = (const float*)d_in[7];
    const float* bv  = (const float*)d_in[8];
    const float* Wo  = (const float*)d_in[9];
    const float* bo  = (const float*)d_in[10];

    char* ws = (char*)d_ws;
    const size_t MB = 1024 * 1024;
    float*  maskadd = (float*)ws;                              // 32 KB
    bf16_t* w_bf  = (bf16_t*)(ws + 32 * 1024);                 // 8 MB (4 weights)
    bf16_t* aout  = (bf16_t*)(ws + 32 * 1024 + 8  * MB);       // 8 MB
    bf16_t* qh    = (bf16_t*)(ws + 32 * 1024 + 32 * MB);       // 8 MB
    bf16_t* kh    = (bf16_t*)(ws + 32 * 1024 + 40 * MB);       // 16 MB
    bf16_t* vt    = (bf16_t*)(ws + 32 * 1024 + 56 * MB);       // 16 MB -> end 72 MB

    bf16_t* wo_bf = w_bf + (size_t)3 * HIDDEN * HIDDEN;

    cvt_w_mask_kernel<<<dim3(NWCVT + 4), 256, 0, stream>>>(
        Wq, Wk, Wv, Wo, w_bf, msk, maskadd);

    gemm_proj_all<<<dim3(1280), 512, 0, stream>>>(
        q, kv, w_bf, bq, bk, bv, qh, kh, vt);

    attn_fwd_kernel<<<dim3(512), 512, 0, stream>>>(qh, kh, vt, maskadd, aout);

    gemm_out_kernel<<<dim3(512), 512, 0, stream>>>(aout, wo_bf, bo, (float*)d_out);
}